// Round 1
// baseline (4510.291 us; speedup 1.0000x reference)
//
#include <hip/hip_runtime.h>
#include <hip/hip_bf16.h>

// ---------------------------------------------------------------------------
// Decoder forward, fp32 direct implementation.
// Upsample2 and channel-concat are fused into conv input addressing.
// Workspace layout (floats), with lifetime-based aliasing; peak ~48.7 MB.
// ---------------------------------------------------------------------------

#define DEV __device__ __forceinline__

// ---------------------- generic direct conv -------------------------------
// src = virtual concat([src0 (C0 ch), src1 (C1 ch)]), optionally 2x-upsampled.
// Output (b, outC, outH, outW), outH = srcH*(UP?2:1). pad = (K-1)/2, same conv.
// ACT: 0 = none (bias only), 2 = tanh.
template <int K, bool REFLECT, bool UP, int ACT>
__global__ __launch_bounds__(256) void conv_k(
    const float* __restrict__ src0, int C0,
    const float* __restrict__ src1, int C1,
    int srcH, int srcW,
    const float* __restrict__ w, const float* __restrict__ bias,
    float* __restrict__ out, int outC)
{
    constexpr int P  = (K - 1) / 2;
    constexpr int LT = 16 + K - 1;
    __shared__ float tile[LT * LT];

    const int b     = blockIdx.z;
    const int oc0   = blockIdx.y * 4;
    const int outH  = srcH * (UP ? 2 : 1);
    const int outW  = srcW * (UP ? 2 : 1);
    const int tilesX = outW / 16;
    const int tileY = (blockIdx.x / tilesX) * 16;
    const int tileX = (blockIdx.x % tilesX) * 16;
    const int ty = threadIdx.x / 16, tx = threadIdx.x % 16;
    const int Cin = C0 + C1;
    const int HWs = srcH * srcW;

    // weight base pointers, oc clamped so we never read OOB (store is guarded)
    const float* wbase[4];
#pragma unroll
    for (int o = 0; o < 4; ++o) {
        int oc = oc0 + o; if (oc > outC - 1) oc = outC - 1;
        wbase[o] = w + (size_t)oc * Cin * K * K;
    }

    float acc[4] = {0.f, 0.f, 0.f, 0.f};

    for (int ic = 0; ic < Cin; ++ic) {
        const float* sp = (ic < C0)
            ? src0 + ((size_t)b * C0 + ic) * HWs
            : src1 + ((size_t)b * C1 + (ic - C0)) * HWs;

        for (int l = threadIdx.x; l < LT * LT; l += 256) {
            int gy = tileY - P + l / LT;
            int gx = tileX - P + l % LT;
            float v;
            if (REFLECT) {
                if (gy < 0) gy = -gy;
                if (gy >= outH) gy = 2 * outH - 2 - gy;
                if (gx < 0) gx = -gx;
                if (gx >= outW) gx = 2 * outW - 2 - gx;
                int sy = UP ? (gy >> 1) : gy;
                int sx = UP ? (gx >> 1) : gx;
                v = sp[sy * srcW + sx];
            } else {
                bool ok = (gy >= 0) & (gy < outH) & (gx >= 0) & (gx < outW);
                int sy = UP ? (gy >> 1) : gy;
                int sx = UP ? (gx >> 1) : gx;
                v = ok ? sp[sy * srcW + sx] : 0.f;
            }
            tile[l] = v;
        }
        __syncthreads();

        const int wo = ic * K * K;
#pragma unroll
        for (int ky = 0; ky < K; ++ky) {
#pragma unroll
            for (int kx = 0; kx < K; ++kx) {
                float v = tile[(ty + ky) * LT + tx + kx];
#pragma unroll
                for (int o = 0; o < 4; ++o)
                    acc[o] = fmaf(wbase[o][wo + ky * K + kx], v, acc[o]);
            }
        }
        __syncthreads();
    }

    const size_t HWo = (size_t)outH * outW;
#pragma unroll
    for (int o = 0; o < 4; ++o) {
        int oc = oc0 + o;
        if (oc >= outC) break;
        float r = acc[o] + bias[oc];
        if (ACT == 2) r = tanhf(r);
        out[((size_t)b * outC + oc) * HWo + (size_t)(tileY + ty) * outW + tileX + tx] = r;
    }
}

// ---------------------- instance norm -------------------------------------
__global__ __launch_bounds__(256) void inorm_stats(
    const float* __restrict__ x, float* __restrict__ stats, int HW)
{
    __shared__ float sh[8];
    const int bc = blockIdx.x;
    const float* p = x + (size_t)bc * HW;
    float s = 0.f, ss = 0.f;
    for (int i = threadIdx.x; i < HW; i += 256) {
        float v = p[i];
        s += v; ss = fmaf(v, v, ss);
    }
#pragma unroll
    for (int o = 32; o; o >>= 1) { s += __shfl_down(s, o); ss += __shfl_down(ss, o); }
    if ((threadIdx.x & 63) == 0) {
        sh[(threadIdx.x >> 6) * 2] = s;
        sh[(threadIdx.x >> 6) * 2 + 1] = ss;
    }
    __syncthreads();
    if (threadIdx.x == 0) {
        s  = sh[0] + sh[2] + sh[4] + sh[6];
        ss = sh[1] + sh[3] + sh[5] + sh[7];
        float m   = s / HW;
        float var = ss / HW - m * m;
        stats[2 * bc]     = m;
        stats[2 * bc + 1] = rsqrtf(var + 1e-5f);
    }
}

// MODE: 1 = norm + relu, 2 = norm + residual add
template <int MODE>
__global__ __launch_bounds__(256) void inorm_apply(
    float* __restrict__ x, const float* __restrict__ stats,
    const float* __restrict__ res, int lgHW, size_t total)
{
    size_t i = (size_t)blockIdx.x * 256 + threadIdx.x;
    if (i >= total) return;
    int bc = (int)(i >> lgHW);
    float m = stats[2 * bc], r = stats[2 * bc + 1];
    float v = (x[i] - m) * r;
    if (MODE == 1) v = fmaxf(v, 0.f);
    if (MODE == 2) v += res[i];
    x[i] = v;
}

// ---------------------- deformable conv -----------------------------------
// wt layout [k][c][o]  (pre-transposed)
__global__ __launch_bounds__(256) void transpose_w(
    const float* __restrict__ w, float* __restrict__ wt, int C, int O)
{
    int i = blockIdx.x * 256 + threadIdx.x;
    if (i >= O * C * 9) return;
    int k = i % 9;
    int c = (i / 9) % C;
    int o = i / (9 * C);
    wt[((size_t)k * C + c) * O + o] = w[i];
}

template <int C, int O>
__global__ __launch_bounds__(256) void deform_conv(
    const float* __restrict__ feat, const float* __restrict__ om,
    const float* __restrict__ wt, const float* __restrict__ bias,
    float* __restrict__ out, int H, int W)
{
    constexpr int J = O / 8;
    const int b = blockIdx.y;
    const int pixBase = blockIdx.x * 32;
    const int lane = threadIdx.x >> 5;   // 0..7
    const int pix  = threadIdx.x & 31;
    const int HW = H * W;
    const int pg = pixBase + pix;

    __shared__ int   sY0[32], sX0[32];
    __shared__ float sWt[4][32];
    __shared__ float sVal[8][32];
    __shared__ __align__(16) float sWgt[8 * O];

    float acc[J];
#pragma unroll
    for (int j = 0; j < J; ++j) acc[j] = 0.f;

    const float* ombase = om + (size_t)b * 27 * HW;

    for (int k = 0; k < 9; ++k) {
        if (threadIdx.x < 32) {
            int p2 = pixBase + (int)threadIdx.x;
            int hh = p2 / W, ww = p2 % W;
            float dy = ombase[(size_t)k * HW + p2];
            float dx = ombase[(size_t)(9 + k) * HW + p2];
            float mk = 1.f / (1.f + __expf(-ombase[(size_t)(18 + k) * HW + p2]));
            float py = (float)(hh + (k / 3) - 1) + dy;
            float px = (float)(ww + (k % 3) - 1) + dx;
            float y0f = floorf(py), x0f = floorf(px);
            int y0 = (int)y0f, x0 = (int)x0f;
            float wy = py - y0f, wx = px - x0f;
            float vy0 = ((unsigned)y0       < (unsigned)H) ? 1.f : 0.f;
            float vy1 = ((unsigned)(y0 + 1) < (unsigned)H) ? 1.f : 0.f;
            float vx0 = ((unsigned)x0       < (unsigned)W) ? 1.f : 0.f;
            float vx1 = ((unsigned)(x0 + 1) < (unsigned)W) ? 1.f : 0.f;
            sY0[threadIdx.x] = y0;
            sX0[threadIdx.x] = x0;
            sWt[0][threadIdx.x] = (1.f - wy) * (1.f - wx) * vy0 * vx0 * mk;
            sWt[1][threadIdx.x] = (1.f - wy) * wx         * vy0 * vx1 * mk;
            sWt[2][threadIdx.x] = wy         * (1.f - wx) * vy1 * vx0 * mk;
            sWt[3][threadIdx.x] = wy         * wx         * vy1 * vx1 * mk;
        }
        __syncthreads();

        int y0 = sY0[pix], x0 = sX0[pix];
        int y0c = min(max(y0, 0), H - 1), y1c = min(max(y0 + 1, 0), H - 1);
        int x0c = min(max(x0, 0), W - 1), x1c = min(max(x0 + 1, 0), W - 1);
        float w00 = sWt[0][pix], w01 = sWt[1][pix];
        float w10 = sWt[2][pix], w11 = sWt[3][pix];
        int o00 = y0c * W + x0c, o01 = y0c * W + x1c;
        int o10 = y1c * W + x0c, o11 = y1c * W + x1c;

        const float* wk = wt + (size_t)k * C * O;
        for (int cb = 0; cb < C; cb += 8) {
            const float* fp = feat + ((size_t)b * C + cb + lane) * HW;
            float v = w00 * fp[o00] + w01 * fp[o01] + w10 * fp[o10] + w11 * fp[o11];
            sVal[lane][pix] = v;

            constexpr int CNT4 = 2 * O;  // number of float4 in 8*O floats
            if (threadIdx.x < CNT4) {
                const float4* srcw = reinterpret_cast<const float4*>(wk + (size_t)cb * O)
                                   + threadIdx.x;
                reinterpret_cast<float4*>(sWgt)[threadIdx.x] = *srcw;
            }
            __syncthreads();

#pragma unroll
            for (int cc = 0; cc < 8; ++cc) {
                float vv = sVal[cc][pix];
                const float* wrow = &sWgt[cc * O + lane * J];
#pragma unroll
                for (int j = 0; j < J; ++j)
                    acc[j] = fmaf(wrow[j], vv, acc[j]);
            }
            __syncthreads();
        }
    }

#pragma unroll
    for (int j = 0; j < J; ++j) {
        int oc = lane * J + j;
        out[((size_t)b * O + oc) * HW + pg] = acc[j] + bias[oc];
    }
}

// ---------------------- offset |mean| reductions --------------------------
__global__ __launch_bounds__(256) void absmean_partial(
    const float* __restrict__ om, int HW, float* __restrict__ partial)
{
    const int n18 = 18 * HW;
    const long long total = 4LL * n18;
    float s = 0.f;
    for (long long i = (long long)blockIdx.x * 256 + threadIdx.x; i < total;
         i += (long long)gridDim.x * 256) {
        int b = (int)(i / n18);
        int r = (int)(i % n18);
        s += fabsf(om[(size_t)b * 27 * HW + r]);
    }
    __shared__ float sh[4];
#pragma unroll
    for (int o = 32; o; o >>= 1) s += __shfl_down(s, o);
    if ((threadIdx.x & 63) == 0) sh[threadIdx.x >> 6] = s;
    __syncthreads();
    if (threadIdx.x == 0) partial[blockIdx.x] = sh[0] + sh[1] + sh[2] + sh[3];
}

__global__ __launch_bounds__(256) void finalize_k(
    const float* __restrict__ p1, const float* __restrict__ p2,
    float* __restrict__ outScalar)
{
    __shared__ float sh[8];
    float a = p1[threadIdx.x] + p1[threadIdx.x + 256];
    float b = p2[threadIdx.x] + p2[threadIdx.x + 256];
#pragma unroll
    for (int o = 32; o; o >>= 1) { a += __shfl_down(a, o); b += __shfl_down(b, o); }
    if ((threadIdx.x & 63) == 0) {
        sh[(threadIdx.x >> 6) * 2]     = a;
        sh[(threadIdx.x >> 6) * 2 + 1] = b;
    }
    __syncthreads();
    if (threadIdx.x == 0) {
        a = sh[0] + sh[2] + sh[4] + sh[6];
        b = sh[1] + sh[3] + sh[5] + sh[7];
        // offset1: (4,18,128,128)  offset2: (4,18,64,64)
        *outScalar = 0.5f * (a / (4.f * 18.f * 16384.f) + b / (4.f * 18.f * 4096.f));
    }
}

// ---------------------------------------------------------------------------
extern "C" void kernel_launch(void* const* d_in, const int* in_sizes, int n_in,
                              void* d_out, int out_size, void* d_ws, size_t ws_size,
                              hipStream_t stream)
{
    const float* x      = (const float*)d_in[0];
    const float* skip1  = (const float*)d_in[1];
    const float* skip2  = (const float*)d_in[2];
    const float* rb1_w1 = (const float*)d_in[3];
    const float* rb1_b1 = (const float*)d_in[4];
    const float* rb1_w2 = (const float*)d_in[5];
    const float* rb1_b2 = (const float*)d_in[6];
    const float* rb2_w1 = (const float*)d_in[7];
    const float* rb2_b1 = (const float*)d_in[8];
    const float* rb2_w2 = (const float*)d_in[9];
    const float* rb2_b2 = (const float*)d_in[10];
    const float* c1_w   = (const float*)d_in[11];
    const float* c1_b   = (const float*)d_in[12];
    const float* c2_w   = (const float*)d_in[13];
    const float* c2_b   = (const float*)d_in[14];
    const float* c3_w   = (const float*)d_in[15];
    const float* c3_b   = (const float*)d_in[16];
    const float* off2_w = (const float*)d_in[17];
    const float* off2_b = (const float*)d_in[18];
    const float* d2_w   = (const float*)d_in[19];
    const float* d2_b   = (const float*)d_in[20];
    const float* off1_w = (const float*)d_in[21];
    const float* off1_b = (const float*)d_in[22];
    const float* d1_w   = (const float*)d_in[23];
    const float* d1_b   = (const float*)d_in[24];

    float* ws    = (float*)d_ws;
    float* stats = ws;               // 2048 floats (max 1024 (b,c) pairs)
    float* part2 = ws + 2048;        // 512
    float* part1 = ws + 2560;        // 512
    // buffers (float offsets); aliases are lifetime-safe (see schedule)
    float* A1  = ws + 4096;          // (4,256,32,32) = 1048576
    float* A2  = ws + 1052672;       // 1048576
    float* A3  = ws + 2101248;       // 1048576
    float* R1  = ws + 3149824;       // (4,128,64,64) = 2097152   (outA)
    float* OM2 = ws + 5246976;       // (4,27,64,64)  = 442368
    float* CP2 = ws + 5689344;       // (4,128,64,64) = 2097152
    float* R2  = ws + 7786496;       // (4,64,128,128)= 4194304   (outB)
    float* OM1 = ws + 4096;          // (4,27,128,128)= 1769472  [alias A1/A2]
    float* CP1 = ws + 3149824;       // (4,64,128,128)= 4194304  [alias R1/OM2/CP2]
    float* WT2 = ws + 11980800;      // 9*128*128 = 147456
    float* WT1 = ws + 12128256;      // 9*64*64   = 36864
    float* outp = (float*)d_out;     // 4*3*128*128 + 1

    dim3 blk(256);

    // ---- resblock 1 ----
    conv_k<3, true, false, 0><<<dim3(4, 64, 4), blk, 0, stream>>>(x, 256, nullptr, 0, 32, 32, rb1_w1, rb1_b1, A1, 256);
    inorm_stats<<<1024, blk, 0, stream>>>(A1, stats, 1024);
    inorm_apply<1><<<4096, blk, 0, stream>>>(A1, stats, nullptr, 10, 1048576);
    conv_k<3, true, false, 0><<<dim3(4, 64, 4), blk, 0, stream>>>(A1, 256, nullptr, 0, 32, 32, rb1_w2, rb1_b2, A2, 256);
    inorm_stats<<<1024, blk, 0, stream>>>(A2, stats, 1024);
    inorm_apply<2><<<4096, blk, 0, stream>>>(A2, stats, x, 10, 1048576);
    // ---- resblock 2 ----
    conv_k<3, true, false, 0><<<dim3(4, 64, 4), blk, 0, stream>>>(A2, 256, nullptr, 0, 32, 32, rb2_w1, rb2_b1, A1, 256);
    inorm_stats<<<1024, blk, 0, stream>>>(A1, stats, 1024);
    inorm_apply<1><<<4096, blk, 0, stream>>>(A1, stats, nullptr, 10, 1048576);
    conv_k<3, true, false, 0><<<dim3(4, 64, 4), blk, 0, stream>>>(A1, 256, nullptr, 0, 32, 32, rb2_w2, rb2_b2, A3, 256);
    inorm_stats<<<1024, blk, 0, stream>>>(A3, stats, 1024);
    inorm_apply<2><<<4096, blk, 0, stream>>>(A3, stats, A2, 10, 1048576);
    // ---- c1: upsample2 fused + 5x5 reflect, 256->128 @64x64 ----
    conv_k<5, true, true, 0><<<dim3(16, 32, 4), blk, 0, stream>>>(A3, 256, nullptr, 0, 32, 32, c1_w, c1_b, R1, 128);
    inorm_stats<<<512, blk, 0, stream>>>(R1, stats, 4096);
    inorm_apply<1><<<8192, blk, 0, stream>>>(R1, stats, nullptr, 12, 2097152);
    // ---- offset conv 2: concat([outA, skip2]) -> 27ch, zero pad ----
    conv_k<3, false, false, 0><<<dim3(16, 7, 4), blk, 0, stream>>>(R1, 128, skip2, 128, 64, 64, off2_w, off2_b, OM2, 27);
    absmean_partial<<<512, blk, 0, stream>>>(OM2, 4096, part2);
    // ---- deform conv 2: feat = skip2 ----
    transpose_w<<<(128 * 128 * 9 + 255) / 256, blk, 0, stream>>>(d2_w, WT2, 128, 128);
    deform_conv<128, 128><<<dim3(128, 4), blk, 0, stream>>>(skip2, OM2, WT2, d2_b, CP2, 64, 64);
    // ---- c2: upsample2(concat([cpre2, outA])) fused + 5x5 reflect, 256->64 @128x128 ----
    conv_k<5, true, true, 0><<<dim3(64, 16, 4), blk, 0, stream>>>(CP2, 128, R1, 128, 64, 64, c2_w, c2_b, R2, 64);
    inorm_stats<<<256, blk, 0, stream>>>(R2, stats, 16384);
    inorm_apply<1><<<16384, blk, 0, stream>>>(R2, stats, nullptr, 14, 4194304);
    // ---- offset conv 1: concat([outB, skip1]) -> 27ch, zero pad ----
    conv_k<3, false, false, 0><<<dim3(64, 7, 4), blk, 0, stream>>>(R2, 64, skip1, 64, 128, 128, off1_w, off1_b, OM1, 27);
    absmean_partial<<<512, blk, 0, stream>>>(OM1, 16384, part1);
    // ---- deform conv 1: feat = skip1 ----
    transpose_w<<<(64 * 64 * 9 + 255) / 256, blk, 0, stream>>>(d1_w, WT1, 64, 64);
    deform_conv<64, 64><<<dim3(512, 4), blk, 0, stream>>>(skip1, OM1, WT1, d1_b, CP1, 128, 128);
    // ---- c3: concat([cpre1, outB]) + 7x7 reflect, 128->3, tanh ----
    conv_k<7, true, false, 2><<<dim3(64, 1, 4), blk, 0, stream>>>(CP1, 64, R2, 64, 128, 128, c3_w, c3_b, outp, 3);
    // ---- offset_sum scalar ----
    finalize_k<<<1, blk, 0, stream>>>(part1, part2, outp + 196608);
}

// Round 3
// 1533.744 us; speedup vs baseline: 2.9407x; 2.9407x over previous
//
#include <hip/hip_runtime.h>
#include <hip/hip_bf16.h>

#define DEV __device__ __forceinline__

typedef unsigned short u16;
typedef __attribute__((ext_vector_type(8))) short short8;
typedef __attribute__((ext_vector_type(4))) float float4v;

DEV u16 f2bf(float v) {
    __hip_bfloat16 h = __float2bfloat16(v);
    return *reinterpret_cast<u16*>(&h);
}

DEV float4v mfma16(short8 a, short8 b, float4v c) {
    return __builtin_amdgcn_mfma_f32_16x16x32_bf16(a, b, c, 0, 0, 0);
}

// ---------------------------------------------------------------------------
// MFMA conv. Input: bf16 channels-last-chunked [b][ch][px][32ic] (virtual
// concat X0|X1 at chunk granularity), optional 2x upsample fused, reflect or
// zero pad. Weights pre-packed in A-fragment order. Output fp32 NCHW.
// Block: 4 waves x 64 px = 256 px (TH rows of width W). Wave: MF*16 oc x 64 px.
// ---------------------------------------------------------------------------
template <int K, bool UP, bool REFLECT, int MF>
__global__ __launch_bounds__(256) void mconv(
    const u16* __restrict__ X0, int c0ch,
    const u16* __restrict__ X1, int nch,
    const u16* __restrict__ WT, int NOB,
    const float* __restrict__ bias, float* __restrict__ out,
    int OC, int W, int lgW, int TH, int SW, int H)
{
    constexpr int P  = (K - 1) / 2;
    constexpr int K2 = K * K;
    extern __shared__ char smem[];
    u16* Xs = (u16*)smem;
    const int LW   = W + K - 1;
    const int tid  = threadIdx.x;
    const int wv   = tid >> 6;
    const int lane = tid & 63;
    const int lm   = lane & 15;
    const int lg   = lane >> 4;
    const int rows0  = blockIdx.x * TH;
    const int b      = blockIdx.z;
    const int obBase = blockIdx.y * MF;
    const int SH  = UP ? (H >> 1) : H;
    const int HWs = SW * SH;

    int pbyte[4];
#pragma unroll
    for (int nf = 0; nf < 4; ++nf) {
        int pxo = wv * 64 + nf * 16;
        int ro  = pxo >> lgW;
        int c0  = pxo & (W - 1);
        pbyte[nf] = (ro * LW + c0 + lm) * 64 + lg * 16;
    }

    float4v acc[MF][4];
#pragma unroll
    for (int m = 0; m < MF; ++m)
#pragma unroll
        for (int n = 0; n < 4; ++n) acc[m][n] = (float4v){0.f, 0.f, 0.f, 0.f};

    const int items = (TH + K - 1) * LW * 4;

    for (int ch = 0; ch < nch; ++ch) {
        const u16* src = (ch < c0ch)
            ? X0 + (size_t)(b * c0ch + ch) * HWs * 32
            : X1 + (size_t)(b * (nch - c0ch) + (ch - c0ch)) * HWs * 32;

        for (int it = tid; it < items; it += 256) {
            int icg = it & 3;
            int t   = it >> 2;
            int tr  = t / LW;
            int tc  = t - tr * LW;
            int gy = rows0 - P + tr;
            int gx = tc - P;
            uint4 v = {0u, 0u, 0u, 0u};
            bool ok = true;
            if (REFLECT) {
                gy = gy < 0 ? -gy : (gy >= H ? 2 * H - 2 - gy : gy);
                gx = gx < 0 ? -gx : (gx >= W ? 2 * W - 2 - gx : gx);
            } else {
                ok = (gy >= 0) & (gy < H) & (gx >= 0) & (gx < W);
            }
            if (ok) {
                int sy = UP ? (gy >> 1) : gy;
                int sx = UP ? (gx >> 1) : gx;
                v = *(const uint4*)(src + (size_t)(sy * SW + sx) * 32 + icg * 8);
            }
            *(uint4*)(Xs + (t * 32 + icg * 8)) = v;
        }
        __syncthreads();

        const u16* wch = WT + (size_t)(ch * NOB) * K2 * 512;
#pragma unroll
        for (int ky = 0; ky < K; ++ky) {
#pragma unroll
            for (int kx = 0; kx < K; ++kx) {
                const int toff = (ky * LW + kx) * 64;
                short8 Bf[4];
#pragma unroll
                for (int nf = 0; nf < 4; ++nf)
                    Bf[nf] = *(const short8*)((const char*)Xs + pbyte[nf] + toff);
                const int tap = ky * K + kx;
#pragma unroll
                for (int m = 0; m < MF; ++m) {
                    short8 Af = *(const short8*)(wch + (size_t)((obBase + m) * K2 + tap) * 512 + lane * 8);
#pragma unroll
                    for (int nf = 0; nf < 4; ++nf)
                        acc[m][nf] = mfma16(Af, Bf[nf], acc[m][nf]);
                }
            }
        }
        __syncthreads();
    }

    const size_t HWo = (size_t)H * W;
#pragma unroll
    for (int m = 0; m < MF; ++m) {
        int oc0 = obBase * 16 + m * 16 + lg * 4;
#pragma unroll
        for (int nf = 0; nf < 4; ++nf) {
            int px = rows0 * W + wv * 64 + nf * 16 + lm;
#pragma unroll
            for (int r = 0; r < 4; ++r) {
                int oc = oc0 + r;
                if (oc < OC)
                    out[(size_t)(b * OC + oc) * HWo + px] = acc[m][nf][r] + bias[oc];
            }
        }
    }
}

// ---------------------------------------------------------------------------
// Weight pack: w[OC][IC][K2] fp32 -> wt[ch][ob][tap][lane][8] bf16 (A-frag).
// ---------------------------------------------------------------------------
__global__ __launch_bounds__(256) void wtrans(
    const float* __restrict__ w, u16* __restrict__ wt,
    int OC, int IC, int K2, int NOB, int total)
{
    int i = blockIdx.x * 256 + threadIdx.x;
    if (i >= total) return;
    int e = i & 7;
    int l = (i >> 3) & 63;
    int rest = i >> 9;
    int tap = rest % K2;
    rest /= K2;
    int ob = rest % NOB;
    int ch = rest / NOB;
    int oc = ob * 16 + (l & 15);
    if (oc >= OC) oc = OC - 1;
    int ic = ch * 32 + (l >> 4) * 8 + e;
    wt[i] = f2bf(w[((size_t)oc * IC + ic) * K2 + tap]);
}

// ---------------------------------------------------------------------------
// fp32 NCHW -> bf16 [b][chunk][px][32ic]
// ---------------------------------------------------------------------------
__global__ __launch_bounds__(256) void act2t(
    const float* __restrict__ in, u16* __restrict__ out,
    int lgHW, int lgC, size_t total)
{
    size_t i = (size_t)blockIdx.x * 256 + threadIdx.x;
    if (i >= total) return;
    int px = (int)(i & (((size_t)1 << lgHW) - 1));
    int bc = (int)(i >> lgHW);
    int c = bc & ((1 << lgC) - 1);
    int b = bc >> lgC;
    size_t o = ((((size_t)(b << (lgC - 5)) + (c >> 5)) << lgHW) + px) * 32 + (c & 31);
    out[o] = f2bf(in[i]);
}

// ---------------------- instance norm -------------------------------------
__global__ __launch_bounds__(256) void inorm_stats(
    const float* __restrict__ x, float* __restrict__ stats, int HW)
{
    __shared__ float sh[8];
    const int bc = blockIdx.x;
    const float* p = x + (size_t)bc * HW;
    float s = 0.f, ss = 0.f;
    for (int i = threadIdx.x; i < HW; i += 256) {
        float v = p[i];
        s += v; ss = fmaf(v, v, ss);
    }
#pragma unroll
    for (int o = 32; o; o >>= 1) { s += __shfl_down(s, o); ss += __shfl_down(ss, o); }
    if ((threadIdx.x & 63) == 0) {
        sh[(threadIdx.x >> 6) * 2] = s;
        sh[(threadIdx.x >> 6) * 2 + 1] = ss;
    }
    __syncthreads();
    if (threadIdx.x == 0) {
        s  = sh[0] + sh[2] + sh[4] + sh[6];
        ss = sh[1] + sh[3] + sh[5] + sh[7];
        float m   = s / HW;
        float var = ss / HW - m * m;
        stats[2 * bc]     = m;
        stats[2 * bc + 1] = rsqrtf(var + 1e-5f);
    }
}

// MODE: 1 = norm+relu, 2 = norm+residual. WF32: write fp32 in place.
// WT16: write bf16 transformed.
template <int MODE, bool WF32, bool WT16>
__global__ __launch_bounds__(256) void inorm_apply(
    float* __restrict__ x, const float* __restrict__ stats,
    const float* __restrict__ res, int lgHW, int lgC, size_t total,
    u16* __restrict__ tout)
{
    size_t i = (size_t)blockIdx.x * 256 + threadIdx.x;
    if (i >= total) return;
    int bc = (int)(i >> lgHW);
    float m = stats[2 * bc], r = stats[2 * bc + 1];
    float v = (x[i] - m) * r;
    if (MODE == 1) v = fmaxf(v, 0.f);
    if (MODE == 2) v += res[i];
    if (WF32) x[i] = v;
    if (WT16) {
        int px = (int)(i & (((size_t)1 << lgHW) - 1));
        int c = bc & ((1 << lgC) - 1);
        int b = bc >> lgC;
        size_t o = ((((size_t)(b << (lgC - 5)) + (c >> 5)) << lgHW) + px) * 32 + (c & 31);
        tout[o] = f2bf(v);
    }
}

// ---------------------- vector conv (c3 only) ------------------------------
template <int K, bool REFLECT, bool UP, int ACT>
__global__ __launch_bounds__(256) void conv_k(
    const float* __restrict__ src0, int C0,
    const float* __restrict__ src1, int C1,
    int srcH, int srcW,
    const float* __restrict__ w, const float* __restrict__ bias,
    float* __restrict__ out, int outC)
{
    constexpr int P  = (K - 1) / 2;
    constexpr int LT = 16 + K - 1;
    __shared__ float tile[LT * LT];

    const int b     = blockIdx.z;
    const int oc0   = blockIdx.y * 4;
    const int outH  = srcH * (UP ? 2 : 1);
    const int outW  = srcW * (UP ? 2 : 1);
    const int tilesX = outW / 16;
    const int tileY = (blockIdx.x / tilesX) * 16;
    const int tileX = (blockIdx.x % tilesX) * 16;
    const int ty = threadIdx.x / 16, tx = threadIdx.x % 16;
    const int Cin = C0 + C1;
    const int HWs = srcH * srcW;

    const float* wbase[4];
#pragma unroll
    for (int o = 0; o < 4; ++o) {
        int oc = oc0 + o; if (oc > outC - 1) oc = outC - 1;
        wbase[o] = w + (size_t)oc * Cin * K * K;
    }

    float acc[4] = {0.f, 0.f, 0.f, 0.f};

    for (int ic = 0; ic < Cin; ++ic) {
        const float* sp = (ic < C0)
            ? src0 + ((size_t)b * C0 + ic) * HWs
            : src1 + ((size_t)b * C1 + (ic - C0)) * HWs;

        for (int l = threadIdx.x; l < LT * LT; l += 256) {
            int gy = tileY - P + l / LT;
            int gx = tileX - P + l % LT;
            float v;
            if (REFLECT) {
                if (gy < 0) gy = -gy;
                if (gy >= outH) gy = 2 * outH - 2 - gy;
                if (gx < 0) gx = -gx;
                if (gx >= outW) gx = 2 * outW - 2 - gx;
                int sy = UP ? (gy >> 1) : gy;
                int sx = UP ? (gx >> 1) : gx;
                v = sp[sy * srcW + sx];
            } else {
                bool okv = (gy >= 0) & (gy < outH) & (gx >= 0) & (gx < outW);
                int sy = UP ? (gy >> 1) : gy;
                int sx = UP ? (gx >> 1) : gx;
                v = okv ? sp[sy * srcW + sx] : 0.f;
            }
            tile[l] = v;
        }
        __syncthreads();

        const int wo = ic * K * K;
#pragma unroll
        for (int ky = 0; ky < K; ++ky) {
#pragma unroll
            for (int kx = 0; kx < K; ++kx) {
                float v = tile[(ty + ky) * LT + tx + kx];
#pragma unroll
                for (int o = 0; o < 4; ++o)
                    acc[o] = fmaf(wbase[o][wo + ky * K + kx], v, acc[o]);
            }
        }
        __syncthreads();
    }

    const size_t HWo = (size_t)outH * outW;
#pragma unroll
    for (int o = 0; o < 4; ++o) {
        int oc = oc0 + o;
        if (oc >= outC) break;
        float r = acc[o] + bias[oc];
        if (ACT == 2) r = tanhf(r);
        out[((size_t)b * outC + oc) * HWo + (size_t)(tileY + ty) * outW + tileX + tx] = r;
    }
}

// ---------------------- deformable conv -----------------------------------
__global__ __launch_bounds__(256) void transpose_w(
    const float* __restrict__ w, float* __restrict__ wt, int C, int O)
{
    int i = blockIdx.x * 256 + threadIdx.x;
    if (i >= O * C * 9) return;
    int k = i % 9;
    int c = (i / 9) % C;
    int o = i / (9 * C);
    wt[((size_t)k * C + c) * O + o] = w[i];
}

template <int C, int O, bool TOUT>
__global__ __launch_bounds__(256) void deform_conv(
    const float* __restrict__ feat, const float* __restrict__ om,
    const float* __restrict__ wt, const float* __restrict__ bias,
    float* __restrict__ out, u16* __restrict__ outT, int H, int W)
{
    constexpr int J = O / 8;
    const int b = blockIdx.y;
    const int pixBase = blockIdx.x * 32;
    const int lane = threadIdx.x >> 5;
    const int pix  = threadIdx.x & 31;
    const int HW = H * W;
    const int pg = pixBase + pix;

    __shared__ int   sY0[32], sX0[32];
    __shared__ float sWt[4][32];
    __shared__ float sVal[8][32];
    __shared__ __align__(16) float sWgt[8 * O];

    float acc[J];
#pragma unroll
    for (int j = 0; j < J; ++j) acc[j] = 0.f;

    const float* ombase = om + (size_t)b * 27 * HW;

    for (int k = 0; k < 9; ++k) {
        if (threadIdx.x < 32) {
            int p2 = pixBase + (int)threadIdx.x;
            int hh = p2 / W, ww = p2 % W;
            float dy = ombase[(size_t)k * HW + p2];
            float dx = ombase[(size_t)(9 + k) * HW + p2];
            float mk = 1.f / (1.f + __expf(-ombase[(size_t)(18 + k) * HW + p2]));
            float py = (float)(hh + (k / 3) - 1) + dy;
            float px = (float)(ww + (k % 3) - 1) + dx;
            float y0f = floorf(py), x0f = floorf(px);
            int y0 = (int)y0f, x0 = (int)x0f;
            float wy = py - y0f, wx = px - x0f;
            float vy0 = ((unsigned)y0       < (unsigned)H) ? 1.f : 0.f;
            float vy1 = ((unsigned)(y0 + 1) < (unsigned)H) ? 1.f : 0.f;
            float vx0 = ((unsigned)x0       < (unsigned)W) ? 1.f : 0.f;
            float vx1 = ((unsigned)(x0 + 1) < (unsigned)W) ? 1.f : 0.f;
            sY0[threadIdx.x] = y0;
            sX0[threadIdx.x] = x0;
            sWt[0][threadIdx.x] = (1.f - wy) * (1.f - wx) * vy0 * vx0 * mk;
            sWt[1][threadIdx.x] = (1.f - wy) * wx         * vy0 * vx1 * mk;
            sWt[2][threadIdx.x] = wy         * (1.f - wx) * vy1 * vx0 * mk;
            sWt[3][threadIdx.x] = wy         * wx         * vy1 * vx1 * mk;
        }
        __syncthreads();

        int y0 = sY0[pix], x0 = sX0[pix];
        int y0c = min(max(y0, 0), H - 1), y1c = min(max(y0 + 1, 0), H - 1);
        int x0c = min(max(x0, 0), W - 1), x1c = min(max(x0 + 1, 0), W - 1);
        float w00 = sWt[0][pix], w01 = sWt[1][pix];
        float w10 = sWt[2][pix], w11 = sWt[3][pix];
        int o00 = y0c * W + x0c, o01 = y0c * W + x1c;
        int o10 = y1c * W + x0c, o11 = y1c * W + x1c;

        const float* wk = wt + (size_t)k * C * O;
        for (int cb = 0; cb < C; cb += 8) {
            const float* fp = feat + ((size_t)b * C + cb + lane) * HW;
            float v = w00 * fp[o00] + w01 * fp[o01] + w10 * fp[o10] + w11 * fp[o11];
            sVal[lane][pix] = v;

            constexpr int CNT4 = 2 * O;
            if (threadIdx.x < CNT4) {
                const float4* srcw = reinterpret_cast<const float4*>(wk + (size_t)cb * O)
                                   + threadIdx.x;
                reinterpret_cast<float4*>(sWgt)[threadIdx.x] = *srcw;
            }
            __syncthreads();

#pragma unroll
            for (int cc = 0; cc < 8; ++cc) {
                float vv = sVal[cc][pix];
                const float* wrow = &sWgt[cc * O + lane * J];
#pragma unroll
                for (int j = 0; j < J; ++j)
                    acc[j] = fmaf(wrow[j], vv, acc[j]);
            }
            __syncthreads();
        }
    }

#pragma unroll
    for (int j = 0; j < J; ++j) {
        int oc = lane * J + j;
        float r = acc[j] + bias[oc];
        if (TOUT)
            outT[(((size_t)(b * (O / 32) + (oc >> 5))) * HW + pg) * 32 + (oc & 31)] = f2bf(r);
        else
            out[((size_t)b * O + oc) * HW + pg] = r;
    }
}

// ---------------------- offset |mean| reductions --------------------------
__global__ __launch_bounds__(256) void absmean_partial(
    const float* __restrict__ om, int HW, float* __restrict__ partial)
{
    const int n18 = 18 * HW;
    const long long total = 4LL * n18;
    float s = 0.f;
    for (long long i = (long long)blockIdx.x * 256 + threadIdx.x; i < total;
         i += (long long)gridDim.x * 256) {
        int b = (int)(i / n18);
        int r = (int)(i % n18);
        s += fabsf(om[(size_t)b * 27 * HW + r]);
    }
    __shared__ float sh[4];
#pragma unroll
    for (int o = 32; o; o >>= 1) s += __shfl_down(s, o);
    if ((threadIdx.x & 63) == 0) sh[threadIdx.x >> 6] = s;
    __syncthreads();
    if (threadIdx.x == 0) partial[blockIdx.x] = sh[0] + sh[1] + sh[2] + sh[3];
}

__global__ __launch_bounds__(256) void finalize_k(
    const float* __restrict__ p1, const float* __restrict__ p2,
    float* __restrict__ outScalar)
{
    __shared__ float sh[8];
    float a = p1[threadIdx.x] + p1[threadIdx.x + 256];
    float b = p2[threadIdx.x] + p2[threadIdx.x + 256];
#pragma unroll
    for (int o = 32; o; o >>= 1) { a += __shfl_down(a, o); b += __shfl_down(b, o); }
    if ((threadIdx.x & 63) == 0) {
        sh[(threadIdx.x >> 6) * 2]     = a;
        sh[(threadIdx.x >> 6) * 2 + 1] = b;
    }
    __syncthreads();
    if (threadIdx.x == 0) {
        a = sh[0] + sh[2] + sh[4] + sh[6];
        b = sh[1] + sh[3] + sh[5] + sh[7];
        *outScalar = 0.5f * (a / (4.f * 18.f * 16384.f) + b / (4.f * 18.f * 4096.f));
    }
}

// ---------------------------------------------------------------------------
extern "C" void kernel_launch(void* const* d_in, const int* in_sizes, int n_in,
                              void* d_out, int out_size, void* d_ws, size_t ws_size,
                              hipStream_t stream)
{
    const float* x      = (const float*)d_in[0];
    const float* skip1  = (const float*)d_in[1];
    const float* skip2  = (const float*)d_in[2];
    const float* rb1_w1 = (const float*)d_in[3];
    const float* rb1_b1 = (const float*)d_in[4];
    const float* rb1_w2 = (const float*)d_in[5];
    const float* rb1_b2 = (const float*)d_in[6];
    const float* rb2_w1 = (const float*)d_in[7];
    const float* rb2_b1 = (const float*)d_in[8];
    const float* rb2_w2 = (const float*)d_in[9];
    const float* rb2_b2 = (const float*)d_in[10];
    const float* c1_w   = (const float*)d_in[11];
    const float* c1_b   = (const float*)d_in[12];
    const float* c2_w   = (const float*)d_in[13];
    const float* c2_b   = (const float*)d_in[14];
    const float* c3_w   = (const float*)d_in[15];
    const float* c3_b   = (const float*)d_in[16];
    const float* off2_w = (const float*)d_in[17];
    const float* off2_b = (const float*)d_in[18];
    const float* d2_w   = (const float*)d_in[19];
    const float* d2_b   = (const float*)d_in[20];
    const float* off1_w = (const float*)d_in[21];
    const float* off1_b = (const float*)d_in[22];
    const float* d1_w   = (const float*)d_in[23];
    const float* d1_b   = (const float*)d_in[24];

    float* ws    = (float*)d_ws;
    float* stats = ws;
    float* part2 = ws + 2048;
    float* part1 = ws + 2560;

    // ---- weight pack arenas (words) ----
    u16* wtRB = (u16*)(ws + 4096);     // 294912 w, JIT-reused for all 4 rb convs
    u16* wtC1 = (u16*)(ws + 299008);   // 409600 w
    u16* wtC2 = (u16*)(ws + 708608);   // 204800 w
    u16* wtO2 = (u16*)(ws + 913408);   // 36864 w
    u16* wtO1 = (u16*)(ws + 950272);   // 18432 w
    // ---- Z1 region: R2 fp32 (4M w) with early overlays ----
    float* R2  = ws + 968704;                  // [c2 -> c3]
    u16*  xT   = (u16*)(ws + 968704);          // 512K w  [->rb1c1]; then A1T
    u16*  A1T  = xT;
    u16*  A2T  = (u16*)(ws + 968704 + 524288); // 512K w; then A3T
    u16*  A3T  = A2T;
    float* A1  = ws + 968704 + 1048576;        // 1M w
    float* A2  = ws + 968704 + 2097152;        // 1M w
    float* A3  = ws + 968704 + 3145728;        // 1M w
    float* OM2 = ws + 968704;                  // 442368 w [off2 -> deform2]
    // ---- Z2/Z3: s1T + R2T, union = CP1 ----
    u16*  s1T  = (u16*)(ws + 5163008);         // 2M w [-> off1]
    u16*  R2T  = (u16*)(ws + 7260160);         // 2M w [apply -> off1]
    float* R1  = ws + 7260160;                 // 2M w [c1 -> apply]
    float* WT2d = ws + 7260160;                // 147456 w [-> deform2]
    float* CP1 = ws + 5163008;                 // 4M w [deform1 -> c3]
    // ---- Z4: R1T then OM1 ----
    u16*  R1T  = (u16*)(ws + 9357312);         // 1M w [-> c2]
    float* OM1 = ws + 9357312;                 // 1769472 w [off1 -> deform1]
    float* WT1d = ws + 9357312 + 1769472;      // 36864 w [-> deform1]
    // ---- Z5: s2T then CP2T ----
    u16*  s2T  = (u16*)(ws + 10405888);        // 1M w [-> off2]
    u16*  CP2T = (u16*)(ws + 10405888);        // 1M w [deform2 -> c2]

    float* outp = (float*)d_out;
    dim3 blk(256);

    // ---- input transforms ----
    act2t<<<4096, blk, 0, stream>>>(x, xT, 10, 8, 1048576);
    act2t<<<16384, blk, 0, stream>>>(skip1, s1T, 14, 6, 4194304);
    act2t<<<8192, blk, 0, stream>>>(skip2, s2T, 12, 7, 2097152);

    // ---- resblock 1 conv 1 ----
    wtrans<<<2304, blk, 0, stream>>>(rb1_w1, wtRB, 256, 256, 9, 16, 589824);
    mconv<3, false, true, 4><<<dim3(4, 4, 4), blk, 21760, stream>>>(
        xT, 8, nullptr, 8, wtRB, 16, rb1_b1, A1, 256, 32, 5, 8, 32, 32);
    inorm_stats<<<1024, blk, 0, stream>>>(A1, stats, 1024);
    inorm_apply<1, false, true><<<4096, blk, 0, stream>>>(A1, stats, nullptr, 10, 8, 1048576, A1T);
    // ---- resblock 1 conv 2 ----
    wtrans<<<2304, blk, 0, stream>>>(rb1_w2, wtRB, 256, 256, 9, 16, 589824);
    mconv<3, false, true, 4><<<dim3(4, 4, 4), blk, 21760, stream>>>(
        A1T, 8, nullptr, 8, wtRB, 16, rb1_b2, A2, 256, 32, 5, 8, 32, 32);
    inorm_stats<<<1024, blk, 0, stream>>>(A2, stats, 1024);
    inorm_apply<2, true, true><<<4096, blk, 0, stream>>>(A2, stats, x, 10, 8, 1048576, A2T);
    // ---- resblock 2 conv 1 ----
    wtrans<<<2304, blk, 0, stream>>>(rb2_w1, wtRB, 256, 256, 9, 16, 589824);
    mconv<3, false, true, 4><<<dim3(4, 4, 4), blk, 21760, stream>>>(
        A2T, 8, nullptr, 8, wtRB, 16, rb2_b1, A1, 256, 32, 5, 8, 32, 32);
    inorm_stats<<<1024, blk, 0, stream>>>(A1, stats, 1024);
    inorm_apply<1, false, true><<<4096, blk, 0, stream>>>(A1, stats, nullptr, 10, 8, 1048576, A1T);
    // ---- resblock 2 conv 2 ----
    wtrans<<<2304, blk, 0, stream>>>(rb2_w2, wtRB, 256, 256, 9, 16, 589824);
    mconv<3, false, true, 4><<<dim3(4, 4, 4), blk, 21760, stream>>>(
        A1T, 8, nullptr, 8, wtRB, 16, rb2_b2, A3, 256, 32, 5, 8, 32, 32);
    inorm_stats<<<1024, blk, 0, stream>>>(A3, stats, 1024);
    inorm_apply<2, false, true><<<4096, blk, 0, stream>>>(A3, stats, A2, 10, 8, 1048576, A3T);
    // ---- c1: up2 + 5x5 reflect, 256->128 @64 ----
    wtrans<<<3200, blk, 0, stream>>>(c1_w, wtC1, 128, 256, 25, 8, 819200);
    mconv<5, true, true, 4><<<dim3(16, 2, 4), blk, 34816, stream>>>(
        A3T, 8, nullptr, 8, wtC1, 8, c1_b, R1, 128, 64, 6, 4, 32, 64);
    inorm_stats<<<512, blk, 0, stream>>>(R1, stats, 4096);
    inorm_apply<1, false, true><<<8192, blk, 0, stream>>>(R1, stats, nullptr, 12, 7, 2097152, R1T);
    // ---- off2: concat(R1T, s2T) 3x3 zero-pad -> 27ch ----
    wtrans<<<288, blk, 0, stream>>>(off2_w, wtO2, 27, 256, 9, 2, 73728);
    mconv<3, false, false, 2><<<dim3(16, 1, 4), blk, 25344, stream>>>(
        R1T, 4, s2T, 8, wtO2, 2, off2_b, OM2, 27, 64, 6, 4, 64, 64);
    absmean_partial<<<512, blk, 0, stream>>>(OM2, 4096, part2);
    // ---- deform 2 ----  (4096 px / 32 = 128 blocks — was 512: OOB corruption)
    transpose_w<<<(128 * 128 * 9 + 255) / 256, blk, 0, stream>>>(d2_w, WT2d, 128, 128);
    deform_conv<128, 128, true><<<dim3(128, 4), blk, 0, stream>>>(
        skip2, OM2, WT2d, d2_b, nullptr, CP2T, 64, 64);
    // ---- c2: up2(concat(CP2T, R1T)) + 5x5 reflect, 256->64 @128 ----
    wtrans<<<1600, blk, 0, stream>>>(c2_w, wtC2, 64, 256, 25, 4, 409600);
    mconv<5, true, true, 4><<<dim3(64, 1, 4), blk, 50688, stream>>>(
        CP2T, 4, R1T, 8, wtC2, 4, c2_b, R2, 64, 128, 7, 2, 64, 128);
    inorm_stats<<<256, blk, 0, stream>>>(R2, stats, 16384);
    inorm_apply<1, true, true><<<16384, blk, 0, stream>>>(R2, stats, nullptr, 14, 6, 4194304, R2T);
    // ---- off1: concat(R2T, s1T) 3x3 zero-pad -> 27ch ----
    wtrans<<<144, blk, 0, stream>>>(off1_w, wtO1, 27, 128, 9, 2, 36864);
    mconv<3, false, false, 2><<<dim3(64, 1, 4), blk, 33280, stream>>>(
        R2T, 2, s1T, 4, wtO1, 2, off1_b, OM1, 27, 128, 7, 2, 128, 128);
    absmean_partial<<<512, blk, 0, stream>>>(OM1, 16384, part1);
    // ---- deform 1 ----  (16384 px / 32 = 512 blocks — was 2048: OOB corruption)
    transpose_w<<<(64 * 64 * 9 + 255) / 256, blk, 0, stream>>>(d1_w, WT1d, 64, 64);
    deform_conv<64, 64, false><<<dim3(512, 4), blk, 0, stream>>>(
        skip1, OM1, WT1d, d1_b, CP1, nullptr, 128, 128);
    // ---- c3: concat(CP1, R2) 7x7 reflect + tanh -> 3ch ----
    conv_k<7, true, false, 2><<<dim3(64, 1, 4), blk, 0, stream>>>(
        CP1, 64, R2, 64, 128, 128, c3_w, c3_b, outp, 3);
    // ---- offset_sum ----
    finalize_k<<<1, blk, 0, stream>>>(part1, part2, outp + 196608);
}

// Round 4
// 1314.777 us; speedup vs baseline: 3.4305x; 1.1665x over previous
//
#include <hip/hip_runtime.h>
#include <hip/hip_bf16.h>

#define DEV __device__ __forceinline__

typedef unsigned short u16;
typedef __attribute__((ext_vector_type(8))) short short8;
typedef __attribute__((ext_vector_type(4))) float float4v;

DEV u16 f2bf(float v) {
    __hip_bfloat16 h = __float2bfloat16(v);
    return *reinterpret_cast<u16*>(&h);
}

DEV float4v mfma16(short8 a, short8 b, float4v c) {
    return __builtin_amdgcn_mfma_f32_16x16x32_bf16(a, b, c, 0, 0, 0);
}

// ---------------------------------------------------------------------------
// MFMA conv. Input: bf16 channels-last-chunked [b][ch][px][32ic] (virtual
// concat X0|X1 at chunk granularity), optional 2x upsample fused, reflect or
// zero pad. Weights pre-packed in A-fragment order. Output fp32 NCHW.
// Block: 4 waves x 64 px = 256 px (TH rows of width W). Wave: MF*16 oc x 64 px.
// ---------------------------------------------------------------------------
template <int K, bool UP, bool REFLECT, int MF>
__global__ __launch_bounds__(256) void mconv(
    const u16* __restrict__ X0, int c0ch,
    const u16* __restrict__ X1, int nch,
    const u16* __restrict__ WT, int NOB,
    const float* __restrict__ bias, float* __restrict__ out,
    int OC, int W, int lgW, int TH, int SW, int H)
{
    constexpr int P  = (K - 1) / 2;
    constexpr int K2 = K * K;
    extern __shared__ char smem[];
    u16* Xs = (u16*)smem;
    const int LW   = W + K - 1;
    const int tid  = threadIdx.x;
    const int wv   = tid >> 6;
    const int lane = tid & 63;
    const int lm   = lane & 15;
    const int lg   = lane >> 4;
    const int rows0  = blockIdx.x * TH;
    const int b      = blockIdx.z;
    const int obBase = blockIdx.y * MF;
    const int SH  = UP ? (H >> 1) : H;
    const int HWs = SW * SH;

    int pbyte[4];
#pragma unroll
    for (int nf = 0; nf < 4; ++nf) {
        int pxo = wv * 64 + nf * 16;
        int ro  = pxo >> lgW;
        int c0  = pxo & (W - 1);
        pbyte[nf] = (ro * LW + c0 + lm) * 64 + lg * 16;
    }

    float4v acc[MF][4];
#pragma unroll
    for (int m = 0; m < MF; ++m)
#pragma unroll
        for (int n = 0; n < 4; ++n) acc[m][n] = (float4v){0.f, 0.f, 0.f, 0.f};

    const int items = (TH + K - 1) * LW * 4;

    for (int ch = 0; ch < nch; ++ch) {
        const u16* src = (ch < c0ch)
            ? X0 + (size_t)(b * c0ch + ch) * HWs * 32
            : X1 + (size_t)(b * (nch - c0ch) + (ch - c0ch)) * HWs * 32;

        for (int it = tid; it < items; it += 256) {
            int icg = it & 3;
            int t   = it >> 2;
            int tr  = t / LW;
            int tc  = t - tr * LW;
            int gy = rows0 - P + tr;
            int gx = tc - P;
            uint4 v = {0u, 0u, 0u, 0u};
            bool ok = true;
            if (REFLECT) {
                gy = gy < 0 ? -gy : (gy >= H ? 2 * H - 2 - gy : gy);
                gx = gx < 0 ? -gx : (gx >= W ? 2 * W - 2 - gx : gx);
            } else {
                ok = (gy >= 0) & (gy < H) & (gx >= 0) & (gx < W);
            }
            if (ok) {
                int sy = UP ? (gy >> 1) : gy;
                int sx = UP ? (gx >> 1) : gx;
                v = *(const uint4*)(src + (size_t)(sy * SW + sx) * 32 + icg * 8);
            }
            *(uint4*)(Xs + (t * 32 + icg * 8)) = v;
        }
        __syncthreads();

        const u16* wch = WT + (size_t)(ch * NOB) * K2 * 512;
#pragma unroll
        for (int ky = 0; ky < K; ++ky) {
#pragma unroll
            for (int kx = 0; kx < K; ++kx) {
                const int toff = (ky * LW + kx) * 64;
                short8 Bf[4];
#pragma unroll
                for (int nf = 0; nf < 4; ++nf)
                    Bf[nf] = *(const short8*)((const char*)Xs + pbyte[nf] + toff);
                const int tap = ky * K + kx;
#pragma unroll
                for (int m = 0; m < MF; ++m) {
                    short8 Af = *(const short8*)(wch + (size_t)((obBase + m) * K2 + tap) * 512 + lane * 8);
#pragma unroll
                    for (int nf = 0; nf < 4; ++nf)
                        acc[m][nf] = mfma16(Af, Bf[nf], acc[m][nf]);
                }
            }
        }
        __syncthreads();
    }

    const size_t HWo = (size_t)H * W;
#pragma unroll
    for (int m = 0; m < MF; ++m) {
        int oc0 = obBase * 16 + m * 16 + lg * 4;
#pragma unroll
        for (int nf = 0; nf < 4; ++nf) {
            int px = rows0 * W + wv * 64 + nf * 16 + lm;
#pragma unroll
            for (int r = 0; r < 4; ++r) {
                int oc = oc0 + r;
                if (oc < OC)
                    out[(size_t)(b * OC + oc) * HWo + px] = acc[m][nf][r] + bias[oc];
            }
        }
    }
}

// ---------------------------------------------------------------------------
// Weight pack: w[OC][IC][K2] fp32 -> wt[ch][ob][tap][lane][8] bf16 (A-frag).
// ---------------------------------------------------------------------------
__global__ __launch_bounds__(256) void wtrans(
    const float* __restrict__ w, u16* __restrict__ wt,
    int OC, int IC, int K2, int NOB, int total)
{
    int i = blockIdx.x * 256 + threadIdx.x;
    if (i >= total) return;
    int e = i & 7;
    int l = (i >> 3) & 63;
    int rest = i >> 9;
    int tap = rest % K2;
    rest /= K2;
    int ob = rest % NOB;
    int ch = rest / NOB;
    int oc = ob * 16 + (l & 15);
    if (oc >= OC) oc = OC - 1;
    int ic = ch * 32 + (l >> 4) * 8 + e;
    wt[i] = f2bf(w[((size_t)oc * IC + ic) * K2 + tap]);
}

// ---------------------------------------------------------------------------
// fp32 NCHW -> bf16 [b][chunk][px][32ic]
// ---------------------------------------------------------------------------
__global__ __launch_bounds__(256) void act2t(
    const float* __restrict__ in, u16* __restrict__ out,
    int lgHW, int lgC, size_t total)
{
    size_t i = (size_t)blockIdx.x * 256 + threadIdx.x;
    if (i >= total) return;
    int px = (int)(i & (((size_t)1 << lgHW) - 1));
    int bc = (int)(i >> lgHW);
    int c = bc & ((1 << lgC) - 1);
    int b = bc >> lgC;
    size_t o = ((((size_t)(b << (lgC - 5)) + (c >> 5)) << lgHW) + px) * 32 + (c & 31);
    out[o] = f2bf(in[i]);
}

// ---------------------- instance norm -------------------------------------
__global__ __launch_bounds__(256) void inorm_stats(
    const float* __restrict__ x, float* __restrict__ stats, int HW)
{
    __shared__ float sh[8];
    const int bc = blockIdx.x;
    const float* p = x + (size_t)bc * HW;
    float s = 0.f, ss = 0.f;
    for (int i = threadIdx.x; i < HW; i += 256) {
        float v = p[i];
        s += v; ss = fmaf(v, v, ss);
    }
#pragma unroll
    for (int o = 32; o; o >>= 1) { s += __shfl_down(s, o); ss += __shfl_down(ss, o); }
    if ((threadIdx.x & 63) == 0) {
        sh[(threadIdx.x >> 6) * 2] = s;
        sh[(threadIdx.x >> 6) * 2 + 1] = ss;
    }
    __syncthreads();
    if (threadIdx.x == 0) {
        s  = sh[0] + sh[2] + sh[4] + sh[6];
        ss = sh[1] + sh[3] + sh[5] + sh[7];
        float m   = s / HW;
        float var = ss / HW - m * m;
        stats[2 * bc]     = m;
        stats[2 * bc + 1] = rsqrtf(var + 1e-5f);
    }
}

// MODE: 1 = norm+relu, 2 = norm+residual. WF32: write fp32 in place.
// WT16: write bf16 transformed.
template <int MODE, bool WF32, bool WT16>
__global__ __launch_bounds__(256) void inorm_apply(
    float* __restrict__ x, const float* __restrict__ stats,
    const float* __restrict__ res, int lgHW, int lgC, size_t total,
    u16* __restrict__ tout)
{
    size_t i = (size_t)blockIdx.x * 256 + threadIdx.x;
    if (i >= total) return;
    int bc = (int)(i >> lgHW);
    float m = stats[2 * bc], r = stats[2 * bc + 1];
    float v = (x[i] - m) * r;
    if (MODE == 1) v = fmaxf(v, 0.f);
    if (MODE == 2) v += res[i];
    if (WF32) x[i] = v;
    if (WT16) {
        int px = (int)(i & (((size_t)1 << lgHW) - 1));
        int c = bc & ((1 << lgC) - 1);
        int b = bc >> lgC;
        size_t o = ((((size_t)(b << (lgC - 5)) + (c >> 5)) << lgHW) + px) * 32 + (c & 31);
        tout[o] = f2bf(v);
    }
}

// ---------------------- c3: two-stage fp32 conv ----------------------------
// Stage 1: partial conv over a 16-ic chunk. part[chunk][b][3][HW].
// grid (tiles, 8, 4). Reflect indices precomputed once per thread.
template <int K>
__global__ __launch_bounds__(256) void conv_part(
    const float* __restrict__ src0,   // 64 ch (CP1)
    const float* __restrict__ src1,   // 64 ch (R2)
    const float* __restrict__ w,      // [3][128][K2]
    float* __restrict__ part, int H, int W)
{
    constexpr int P = (K - 1) / 2, LT = 16 + K - 1, K2 = K * K;
    __shared__ float tile[LT * LT];
    __shared__ float wsm[16 * 3 * K2];
    const int b = blockIdx.z;
    const int chunk = blockIdx.y;
    const int tilesX = W / 16;
    const int tileY = (blockIdx.x / tilesX) * 16;
    const int tileX = (blockIdx.x % tilesX) * 16;
    const int ty = threadIdx.x / 16, tx = threadIdx.x % 16;
    const int HW = H * W;

    for (int i = threadIdx.x; i < 16 * 3 * K2; i += 256) {
        int tap = i % K2;
        int oc  = (i / K2) % 3;
        int icl = i / (3 * K2);
        wsm[i] = w[((size_t)oc * 128 + chunk * 16 + icl) * K2 + tap];
    }

    int pidx0 = -1, pidx1 = -1;
    {
        int l = threadIdx.x;
        if (l < LT * LT) {
            int gy = tileY - P + l / LT, gx = tileX - P + l % LT;
            gy = gy < 0 ? -gy : (gy >= H ? 2 * H - 2 - gy : gy);
            gx = gx < 0 ? -gx : (gx >= W ? 2 * W - 2 - gx : gx);
            pidx0 = gy * W + gx;
        }
        l += 256;
        if (l < LT * LT) {
            int gy = tileY - P + l / LT, gx = tileX - P + l % LT;
            gy = gy < 0 ? -gy : (gy >= H ? 2 * H - 2 - gy : gy);
            gx = gx < 0 ? -gx : (gx >= W ? 2 * W - 2 - gx : gx);
            pidx1 = gy * W + gx;
        }
    }

    float acc[3] = {0.f, 0.f, 0.f};
    for (int icl = 0; icl < 16; ++icl) {
        int ic = chunk * 16 + icl;
        const float* sp = (ic < 64)
            ? src0 + ((size_t)b * 64 + ic) * HW
            : src1 + ((size_t)b * 64 + (ic - 64)) * HW;
        __syncthreads();
        if (pidx0 >= 0) tile[threadIdx.x] = sp[pidx0];
        if (pidx1 >= 0) tile[threadIdx.x + 256] = sp[pidx1];
        __syncthreads();
        const float* wr = &wsm[icl * 3 * K2];
#pragma unroll
        for (int ky = 0; ky < K; ++ky) {
#pragma unroll
            for (int kx = 0; kx < K; ++kx) {
                float v = tile[(ty + ky) * LT + tx + kx];
                int tap = ky * K + kx;
                acc[0] = fmaf(wr[tap], v, acc[0]);
                acc[1] = fmaf(wr[K2 + tap], v, acc[1]);
                acc[2] = fmaf(wr[2 * K2 + tap], v, acc[2]);
            }
        }
    }
    int px = (tileY + ty) * W + tileX + tx;
    size_t base = (((size_t)chunk * 4 + b) * 3) * HW + px;
    part[base]          = acc[0];
    part[base + HW]     = acc[1];
    part[base + 2 * HW] = acc[2];
}

// Stage 2: sum 8 chunk-partials + bias + tanh -> NCHW output.
__global__ __launch_bounds__(256) void conv_reduce(
    const float* __restrict__ part, const float* __restrict__ bias,
    float* __restrict__ out, int HW)
{
    int i = blockIdx.x * 256 + threadIdx.x;
    if (i >= 12 * HW) return;
    int px = i % HW;
    int oc = (i / HW) % 3;
    int b  = i / (3 * HW);
    float s = bias[oc];
#pragma unroll
    for (int ch = 0; ch < 8; ++ch)
        s += part[(((size_t)ch * 4 + b) * 3 + oc) * HW + px];
    out[i] = tanhf(s);
}

// ---------------------- deformable conv -----------------------------------
__global__ __launch_bounds__(256) void transpose_w(
    const float* __restrict__ w, float* __restrict__ wt, int C, int O)
{
    int i = blockIdx.x * 256 + threadIdx.x;
    if (i >= O * C * 9) return;
    int k = i % 9;
    int c = (i / 9) % C;
    int o = i / (9 * C);
    wt[((size_t)k * C + c) * O + o] = w[i];
}

template <int C, int O, bool TOUT>
__global__ __launch_bounds__(256) void deform_conv(
    const float* __restrict__ feat, const float* __restrict__ om,
    const float* __restrict__ wt, const float* __restrict__ bias,
    float* __restrict__ out, u16* __restrict__ outT, int H, int W)
{
    constexpr int J = O / 8;
    const int b = blockIdx.y;
    const int pixBase = blockIdx.x * 32;
    const int lane = threadIdx.x >> 5;
    const int pix  = threadIdx.x & 31;
    const int HW = H * W;
    const int pg = pixBase + pix;

    __shared__ int   sY0[32], sX0[32];
    __shared__ float sWt[4][32];
    __shared__ float sVal[8][32];
    __shared__ __align__(16) float sWgt[8 * O];

    float acc[J];
#pragma unroll
    for (int j = 0; j < J; ++j) acc[j] = 0.f;

    const float* ombase = om + (size_t)b * 27 * HW;

    for (int k = 0; k < 9; ++k) {
        if (threadIdx.x < 32) {
            int p2 = pixBase + (int)threadIdx.x;
            int hh = p2 / W, ww = p2 % W;
            float dy = ombase[(size_t)k * HW + p2];
            float dx = ombase[(size_t)(9 + k) * HW + p2];
            float mk = 1.f / (1.f + __expf(-ombase[(size_t)(18 + k) * HW + p2]));
            float py = (float)(hh + (k / 3) - 1) + dy;
            float px = (float)(ww + (k % 3) - 1) + dx;
            float y0f = floorf(py), x0f = floorf(px);
            int y0 = (int)y0f, x0 = (int)x0f;
            float wy = py - y0f, wx = px - x0f;
            float vy0 = ((unsigned)y0       < (unsigned)H) ? 1.f : 0.f;
            float vy1 = ((unsigned)(y0 + 1) < (unsigned)H) ? 1.f : 0.f;
            float vx0 = ((unsigned)x0       < (unsigned)W) ? 1.f : 0.f;
            float vx1 = ((unsigned)(x0 + 1) < (unsigned)W) ? 1.f : 0.f;
            sY0[threadIdx.x] = y0;
            sX0[threadIdx.x] = x0;
            sWt[0][threadIdx.x] = (1.f - wy) * (1.f - wx) * vy0 * vx0 * mk;
            sWt[1][threadIdx.x] = (1.f - wy) * wx         * vy0 * vx1 * mk;
            sWt[2][threadIdx.x] = wy         * (1.f - wx) * vy1 * vx0 * mk;
            sWt[3][threadIdx.x] = wy         * wx         * vy1 * vx1 * mk;
        }
        __syncthreads();

        int y0 = sY0[pix], x0 = sX0[pix];
        int y0c = min(max(y0, 0), H - 1), y1c = min(max(y0 + 1, 0), H - 1);
        int x0c = min(max(x0, 0), W - 1), x1c = min(max(x0 + 1, 0), W - 1);
        float w00 = sWt[0][pix], w01 = sWt[1][pix];
        float w10 = sWt[2][pix], w11 = sWt[3][pix];
        int o00 = y0c * W + x0c, o01 = y0c * W + x1c;
        int o10 = y1c * W + x0c, o11 = y1c * W + x1c;

        const float* wk = wt + (size_t)k * C * O;
        for (int cb = 0; cb < C; cb += 8) {
            const float* fp = feat + ((size_t)b * C + cb + lane) * HW;
            float v = w00 * fp[o00] + w01 * fp[o01] + w10 * fp[o10] + w11 * fp[o11];
            sVal[lane][pix] = v;

            constexpr int CNT4 = 2 * O;
            if (threadIdx.x < CNT4) {
                const float4* srcw = reinterpret_cast<const float4*>(wk + (size_t)cb * O)
                                   + threadIdx.x;
                reinterpret_cast<float4*>(sWgt)[threadIdx.x] = *srcw;
            }
            __syncthreads();

#pragma unroll
            for (int cc = 0; cc < 8; ++cc) {
                float vv = sVal[cc][pix];
                const float* wrow = &sWgt[cc * O + lane * J];
#pragma unroll
                for (int j = 0; j < J; ++j)
                    acc[j] = fmaf(wrow[j], vv, acc[j]);
            }
            __syncthreads();
        }
    }

#pragma unroll
    for (int j = 0; j < J; ++j) {
        int oc = lane * J + j;
        float r = acc[j] + bias[oc];
        if (TOUT)
            outT[(((size_t)(b * (O / 32) + (oc >> 5))) * HW + pg) * 32 + (oc & 31)] = f2bf(r);
        else
            out[((size_t)b * O + oc) * HW + pg] = r;
    }
}

// ---------------------- offset |mean| reductions --------------------------
__global__ __launch_bounds__(256) void absmean_partial(
    const float* __restrict__ om, int HW, float* __restrict__ partial)
{
    const int n18 = 18 * HW;
    const long long total = 4LL * n18;
    float s = 0.f;
    for (long long i = (long long)blockIdx.x * 256 + threadIdx.x; i < total;
         i += (long long)gridDim.x * 256) {
        int b = (int)(i / n18);
        int r = (int)(i % n18);
        s += fabsf(om[(size_t)b * 27 * HW + r]);
    }
    __shared__ float sh[4];
#pragma unroll
    for (int o = 32; o; o >>= 1) s += __shfl_down(s, o);
    if ((threadIdx.x & 63) == 0) sh[threadIdx.x >> 6] = s;
    __syncthreads();
    if (threadIdx.x == 0) partial[blockIdx.x] = sh[0] + sh[1] + sh[2] + sh[3];
}

__global__ __launch_bounds__(256) void finalize_k(
    const float* __restrict__ p1, const float* __restrict__ p2,
    float* __restrict__ outScalar)
{
    __shared__ float sh[8];
    float a = p1[threadIdx.x] + p1[threadIdx.x + 256];
    float b = p2[threadIdx.x] + p2[threadIdx.x + 256];
#pragma unroll
    for (int o = 32; o; o >>= 1) { a += __shfl_down(a, o); b += __shfl_down(b, o); }
    if ((threadIdx.x & 63) == 0) {
        sh[(threadIdx.x >> 6) * 2]     = a;
        sh[(threadIdx.x >> 6) * 2 + 1] = b;
    }
    __syncthreads();
    if (threadIdx.x == 0) {
        a = sh[0] + sh[2] + sh[4] + sh[6];
        b = sh[1] + sh[3] + sh[5] + sh[7];
        *outScalar = 0.5f * (a / (4.f * 18.f * 16384.f) + b / (4.f * 18.f * 4096.f));
    }
}

// ---------------------------------------------------------------------------
extern "C" void kernel_launch(void* const* d_in, const int* in_sizes, int n_in,
                              void* d_out, int out_size, void* d_ws, size_t ws_size,
                              hipStream_t stream)
{
    const float* x      = (const float*)d_in[0];
    const float* skip1  = (const float*)d_in[1];
    const float* skip2  = (const float*)d_in[2];
    const float* rb1_w1 = (const float*)d_in[3];
    const float* rb1_b1 = (const float*)d_in[4];
    const float* rb1_w2 = (const float*)d_in[5];
    const float* rb1_b2 = (const float*)d_in[6];
    const float* rb2_w1 = (const float*)d_in[7];
    const float* rb2_b1 = (const float*)d_in[8];
    const float* rb2_w2 = (const float*)d_in[9];
    const float* rb2_b2 = (const float*)d_in[10];
    const float* c1_w   = (const float*)d_in[11];
    const float* c1_b   = (const float*)d_in[12];
    const float* c2_w   = (const float*)d_in[13];
    const float* c2_b   = (const float*)d_in[14];
    const float* c3_w   = (const float*)d_in[15];
    const float* c3_b   = (const float*)d_in[16];
    const float* off2_w = (const float*)d_in[17];
    const float* off2_b = (const float*)d_in[18];
    const float* d2_w   = (const float*)d_in[19];
    const float* d2_b   = (const float*)d_in[20];
    const float* off1_w = (const float*)d_in[21];
    const float* off1_b = (const float*)d_in[22];
    const float* d1_w   = (const float*)d_in[23];
    const float* d1_b   = (const float*)d_in[24];

    float* ws    = (float*)d_ws;
    float* stats = ws;
    float* part2 = ws + 2048;
    float* part1 = ws + 2560;

    // ---- weight pack arenas (words) ----
    u16* wtRB = (u16*)(ws + 4096);     // 294912 w, JIT-reused for all 4 rb convs
    u16* wtC1 = (u16*)(ws + 299008);   // 409600 w
    u16* wtC2 = (u16*)(ws + 708608);   // 204800 w
    u16* wtO2 = (u16*)(ws + 913408);   // 36864 w
    u16* wtO1 = (u16*)(ws + 950272);   // 18432 w
    // ---- Z1 region: R2 fp32 (4M w) with early overlays ----
    float* R2  = ws + 968704;                  // [c2 -> c3]
    u16*  xT   = (u16*)(ws + 968704);          // 512K w  [->rb1c1]; then A1T
    u16*  A1T  = xT;
    u16*  A2T  = (u16*)(ws + 968704 + 524288); // 512K w; then A3T
    u16*  A3T  = A2T;
    float* A1  = ws + 968704 + 1048576;        // 1M w
    float* A2  = ws + 968704 + 2097152;        // 1M w
    float* A3  = ws + 968704 + 3145728;        // 1M w
    float* OM2 = ws + 968704;                  // 442368 w [off2 -> deform2]
    // ---- Z2/Z3: s1T + R2T, union = CP1 ----
    u16*  s1T  = (u16*)(ws + 5163008);         // 2M w [-> off1]
    u16*  R2T  = (u16*)(ws + 7260160);         // 2M w [apply -> off1]
    float* R1  = ws + 7260160;                 // 2M w [c1 -> apply]
    float* WT2d = ws + 7260160;                // 147456 w [-> deform2]
    float* CP1 = ws + 5163008;                 // 4M w [deform1 -> c3]
    // ---- Z4: R1T then OM1, then c3 partials ----
    u16*  R1T  = (u16*)(ws + 9357312);         // 1M w [-> c2]
    float* OM1 = ws + 9357312;                 // 1769472 w [off1 -> deform1]
    float* WT1d = ws + 9357312 + 1769472;      // 36864 w [-> deform1]
    float* PART = ws + 9357312;                // 1572864 w [c3 stage1 -> stage2]
    // ---- Z5: s2T then CP2T ----
    u16*  s2T  = (u16*)(ws + 10405888);        // 1M w [-> off2]
    u16*  CP2T = (u16*)(ws + 10405888);        // 1M w [deform2 -> c2]

    float* outp = (float*)d_out;
    dim3 blk(256);

    // ---- input transforms ----
    act2t<<<4096, blk, 0, stream>>>(x, xT, 10, 8, 1048576);
    act2t<<<16384, blk, 0, stream>>>(skip1, s1T, 14, 6, 4194304);
    act2t<<<8192, blk, 0, stream>>>(skip2, s2T, 12, 7, 2097152);

    // ---- resblock 1 conv 1 ----
    wtrans<<<2304, blk, 0, stream>>>(rb1_w1, wtRB, 256, 256, 9, 16, 589824);
    mconv<3, false, true, 4><<<dim3(4, 4, 4), blk, 21760, stream>>>(
        xT, 8, nullptr, 8, wtRB, 16, rb1_b1, A1, 256, 32, 5, 8, 32, 32);
    inorm_stats<<<1024, blk, 0, stream>>>(A1, stats, 1024);
    inorm_apply<1, false, true><<<4096, blk, 0, stream>>>(A1, stats, nullptr, 10, 8, 1048576, A1T);
    // ---- resblock 1 conv 2 ----
    wtrans<<<2304, blk, 0, stream>>>(rb1_w2, wtRB, 256, 256, 9, 16, 589824);
    mconv<3, false, true, 4><<<dim3(4, 4, 4), blk, 21760, stream>>>(
        A1T, 8, nullptr, 8, wtRB, 16, rb1_b2, A2, 256, 32, 5, 8, 32, 32);
    inorm_stats<<<1024, blk, 0, stream>>>(A2, stats, 1024);
    inorm_apply<2, true, true><<<4096, blk, 0, stream>>>(A2, stats, x, 10, 8, 1048576, A2T);
    // ---- resblock 2 conv 1 ----
    wtrans<<<2304, blk, 0, stream>>>(rb2_w1, wtRB, 256, 256, 9, 16, 589824);
    mconv<3, false, true, 4><<<dim3(4, 4, 4), blk, 21760, stream>>>(
        A2T, 8, nullptr, 8, wtRB, 16, rb2_b1, A1, 256, 32, 5, 8, 32, 32);
    inorm_stats<<<1024, blk, 0, stream>>>(A1, stats, 1024);
    inorm_apply<1, false, true><<<4096, blk, 0, stream>>>(A1, stats, nullptr, 10, 8, 1048576, A1T);
    // ---- resblock 2 conv 2 ----
    wtrans<<<2304, blk, 0, stream>>>(rb2_w2, wtRB, 256, 256, 9, 16, 589824);
    mconv<3, false, true, 4><<<dim3(4, 4, 4), blk, 21760, stream>>>(
        A1T, 8, nullptr, 8, wtRB, 16, rb2_b2, A3, 256, 32, 5, 8, 32, 32);
    inorm_stats<<<1024, blk, 0, stream>>>(A3, stats, 1024);
    inorm_apply<2, false, true><<<4096, blk, 0, stream>>>(A3, stats, A2, 10, 8, 1048576, A3T);
    // ---- c1: up2 + 5x5 reflect, 256->128 @64 ----
    wtrans<<<3200, blk, 0, stream>>>(c1_w, wtC1, 128, 256, 25, 8, 819200);
    mconv<5, true, true, 4><<<dim3(16, 2, 4), blk, 34816, stream>>>(
        A3T, 8, nullptr, 8, wtC1, 8, c1_b, R1, 128, 64, 6, 4, 32, 64);
    inorm_stats<<<512, blk, 0, stream>>>(R1, stats, 4096);
    inorm_apply<1, false, true><<<8192, blk, 0, stream>>>(R1, stats, nullptr, 12, 7, 2097152, R1T);
    // ---- off2: concat(R1T, s2T) 3x3 zero-pad -> 27ch ----
    wtrans<<<288, blk, 0, stream>>>(off2_w, wtO2, 27, 256, 9, 2, 73728);
    mconv<3, false, false, 2><<<dim3(16, 1, 4), blk, 25344, stream>>>(
        R1T, 4, s2T, 8, wtO2, 2, off2_b, OM2, 27, 64, 6, 4, 64, 64);
    absmean_partial<<<512, blk, 0, stream>>>(OM2, 4096, part2);
    // ---- deform 2 ---- (4096 px / 32 = 128 blocks)
    transpose_w<<<(128 * 128 * 9 + 255) / 256, blk, 0, stream>>>(d2_w, WT2d, 128, 128);
    deform_conv<128, 128, true><<<dim3(128, 4), blk, 0, stream>>>(
        skip2, OM2, WT2d, d2_b, nullptr, CP2T, 64, 64);
    // ---- c2: up2(concat(CP2T, R1T)) + 5x5 reflect, 256->64 @128 ----
    wtrans<<<1600, blk, 0, stream>>>(c2_w, wtC2, 64, 256, 25, 4, 409600);
    mconv<5, true, true, 4><<<dim3(64, 1, 4), blk, 50688, stream>>>(
        CP2T, 4, R1T, 8, wtC2, 4, c2_b, R2, 64, 128, 7, 2, 64, 128);
    inorm_stats<<<256, blk, 0, stream>>>(R2, stats, 16384);
    inorm_apply<1, true, true><<<16384, blk, 0, stream>>>(R2, stats, nullptr, 14, 6, 4194304, R2T);
    // ---- off1: concat(R2T, s1T) 3x3 zero-pad -> 27ch ----
    wtrans<<<144, blk, 0, stream>>>(off1_w, wtO1, 27, 128, 9, 2, 36864);
    mconv<3, false, false, 2><<<dim3(64, 1, 4), blk, 33280, stream>>>(
        R2T, 2, s1T, 4, wtO1, 2, off1_b, OM1, 27, 128, 7, 2, 128, 128);
    absmean_partial<<<512, blk, 0, stream>>>(OM1, 16384, part1);
    // ---- deform 1 ---- (16384 px / 32 = 512 blocks)
    transpose_w<<<(64 * 64 * 9 + 255) / 256, blk, 0, stream>>>(d1_w, WT1d, 64, 64);
    deform_conv<64, 64, false><<<dim3(512, 4), blk, 0, stream>>>(
        skip1, OM1, WT1d, d1_b, CP1, nullptr, 128, 128);
    // ---- c3: concat(CP1, R2) 7x7 reflect + tanh -> 3ch, two-stage ----
    conv_part<7><<<dim3(64, 8, 4), blk, 0, stream>>>(CP1, R2, c3_w, PART, 128, 128);
    conv_reduce<<<768, blk, 0, stream>>>(PART, c3_b, outp, 16384);
    // ---- offset_sum ----
    finalize_k<<<1, blk, 0, stream>>>(part1, part2, outp + 196608);
}

// Round 5
// 1044.050 us; speedup vs baseline: 4.3200x; 1.2593x over previous
//
#include <hip/hip_runtime.h>
#include <hip/hip_bf16.h>

#define DEV __device__ __forceinline__

typedef unsigned short u16;
typedef __attribute__((ext_vector_type(8))) short short8;
typedef __attribute__((ext_vector_type(4))) float float4v;

DEV u16 f2bf(float v) {
    __hip_bfloat16 h = __float2bfloat16(v);
    return *reinterpret_cast<u16*>(&h);
}
DEV float bf2f(u16 u) { return __uint_as_float(((unsigned)u) << 16); }

DEV float4v mfma16(short8 a, short8 b, float4v c) {
    return __builtin_amdgcn_mfma_f32_16x16x32_bf16(a, b, c, 0, 0, 0);
}

// ---------------------------------------------------------------------------
// MFMA conv. Input: bf16 channels-last-chunked [b][ch][px][32ic] (virtual
// concat X0|X1 at chunk granularity), optional 2x upsample fused, reflect or
// zero pad. Weights pre-packed in A-fragment order. Output fp32 NCHW.
// ---------------------------------------------------------------------------
template <int K, bool UP, bool REFLECT, int MF>
__global__ __launch_bounds__(256) void mconv(
    const u16* __restrict__ X0, int c0ch,
    const u16* __restrict__ X1, int nch,
    const u16* __restrict__ WT, int NOB,
    const float* __restrict__ bias, float* __restrict__ out,
    int OC, int W, int lgW, int TH, int SW, int H)
{
    constexpr int P  = (K - 1) / 2;
    constexpr int K2 = K * K;
    extern __shared__ char smem[];
    u16* Xs = (u16*)smem;
    const int LW   = W + K - 1;
    const int tid  = threadIdx.x;
    const int wv   = tid >> 6;
    const int lane = tid & 63;
    const int lm   = lane & 15;
    const int lg   = lane >> 4;
    const int rows0  = blockIdx.x * TH;
    const int b      = blockIdx.z;
    const int obBase = blockIdx.y * MF;
    const int SH  = UP ? (H >> 1) : H;
    const int HWs = SW * SH;

    int pbyte[4];
#pragma unroll
    for (int nf = 0; nf < 4; ++nf) {
        int pxo = wv * 64 + nf * 16;
        int ro  = pxo >> lgW;
        int c0  = pxo & (W - 1);
        pbyte[nf] = (ro * LW + c0 + lm) * 64 + lg * 16;
    }

    float4v acc[MF][4];
#pragma unroll
    for (int m = 0; m < MF; ++m)
#pragma unroll
        for (int n = 0; n < 4; ++n) acc[m][n] = (float4v){0.f, 0.f, 0.f, 0.f};

    const int items = (TH + K - 1) * LW * 4;

    for (int ch = 0; ch < nch; ++ch) {
        const u16* src = (ch < c0ch)
            ? X0 + (size_t)(b * c0ch + ch) * HWs * 32
            : X1 + (size_t)(b * (nch - c0ch) + (ch - c0ch)) * HWs * 32;

        for (int it = tid; it < items; it += 256) {
            int icg = it & 3;
            int t   = it >> 2;
            int tr  = t / LW;
            int tc  = t - tr * LW;
            int gy = rows0 - P + tr;
            int gx = tc - P;
            uint4 v = {0u, 0u, 0u, 0u};
            bool ok = true;
            if (REFLECT) {
                gy = gy < 0 ? -gy : (gy >= H ? 2 * H - 2 - gy : gy);
                gx = gx < 0 ? -gx : (gx >= W ? 2 * W - 2 - gx : gx);
            } else {
                ok = (gy >= 0) & (gy < H) & (gx >= 0) & (gx < W);
            }
            if (ok) {
                int sy = UP ? (gy >> 1) : gy;
                int sx = UP ? (gx >> 1) : gx;
                v = *(const uint4*)(src + (size_t)(sy * SW + sx) * 32 + icg * 8);
            }
            *(uint4*)(Xs + (t * 32 + icg * 8)) = v;
        }
        __syncthreads();

        const u16* wch = WT + (size_t)(ch * NOB) * K2 * 512;
#pragma unroll
        for (int ky = 0; ky < K; ++ky) {
#pragma unroll
            for (int kx = 0; kx < K; ++kx) {
                const int toff = (ky * LW + kx) * 64;
                short8 Bf[4];
#pragma unroll
                for (int nf = 0; nf < 4; ++nf)
                    Bf[nf] = *(const short8*)((const char*)Xs + pbyte[nf] + toff);
                const int tap = ky * K + kx;
#pragma unroll
                for (int m = 0; m < MF; ++m) {
                    short8 Af = *(const short8*)(wch + (size_t)((obBase + m) * K2 + tap) * 512 + lane * 8);
#pragma unroll
                    for (int nf = 0; nf < 4; ++nf)
                        acc[m][nf] = mfma16(Af, Bf[nf], acc[m][nf]);
                }
            }
        }
        __syncthreads();
    }

    const size_t HWo = (size_t)H * W;
#pragma unroll
    for (int m = 0; m < MF; ++m) {
        int oc0 = obBase * 16 + m * 16 + lg * 4;
#pragma unroll
        for (int nf = 0; nf < 4; ++nf) {
            int px = rows0 * W + wv * 64 + nf * 16 + lm;
#pragma unroll
            for (int r = 0; r < 4; ++r) {
                int oc = oc0 + r;
                if (oc < OC)
                    out[(size_t)(b * OC + oc) * HWo + px] = acc[m][nf][r] + bias[oc];
            }
        }
    }
}

// ---------------------------------------------------------------------------
// Weight pack: w[OC][IC][K2] fp32 -> wt[ch][ob][tap][lane][8] bf16 (A-frag).
// ---------------------------------------------------------------------------
__global__ __launch_bounds__(256) void wtrans(
    const float* __restrict__ w, u16* __restrict__ wt,
    int OC, int IC, int K2, int NOB, int total)
{
    int i = blockIdx.x * 256 + threadIdx.x;
    if (i >= total) return;
    int e = i & 7;
    int l = (i >> 3) & 63;
    int rest = i >> 9;
    int tap = rest % K2;
    rest /= K2;
    int ob = rest % NOB;
    int ch = rest / NOB;
    int oc = ob * 16 + (l & 15);
    if (oc >= OC) oc = OC - 1;
    int ic = ch * 32 + (l >> 4) * 8 + e;
    wt[i] = f2bf(w[((size_t)oc * IC + ic) * K2 + tap]);
}

// Deform weight pack: w[O][C][9] fp32 -> dwt[k][ob][cc][lane][8] bf16.
template <int C, int O>
__global__ __launch_bounds__(256) void dwtrans(
    const float* __restrict__ w, u16* __restrict__ dwt)
{
    constexpr int NOB = O / 16, NCC = C / 32;
    constexpr int total = 9 * NOB * NCC * 512;
    int i = blockIdx.x * 256 + threadIdx.x;
    if (i >= total) return;
    int e = i & 7;
    int l = (i >> 3) & 63;
    int rest = i >> 9;
    int cc = rest % NCC;
    rest /= NCC;
    int ob = rest % NOB;
    int k  = rest / NOB;
    int oc = ob * 16 + (l & 15);
    int ic = cc * 32 + (l >> 4) * 8 + e;
    dwt[i] = f2bf(w[((size_t)oc * C + ic) * 9 + k]);
}

// ---------------------------------------------------------------------------
// fp32 NCHW -> bf16 [b][chunk][px][32ic]
// ---------------------------------------------------------------------------
__global__ __launch_bounds__(256) void act2t(
    const float* __restrict__ in, u16* __restrict__ out,
    int lgHW, int lgC, size_t total)
{
    size_t i = (size_t)blockIdx.x * 256 + threadIdx.x;
    if (i >= total) return;
    int px = (int)(i & (((size_t)1 << lgHW) - 1));
    int bc = (int)(i >> lgHW);
    int c = bc & ((1 << lgC) - 1);
    int b = bc >> lgC;
    size_t o = ((((size_t)(b << (lgC - 5)) + (c >> 5)) << lgHW) + px) * 32 + (c & 31);
    out[o] = f2bf(in[i]);
}

// ---------------------- instance norm -------------------------------------
__global__ __launch_bounds__(256) void inorm_stats(
    const float* __restrict__ x, float* __restrict__ stats, int HW)
{
    __shared__ float sh[8];
    const int bc = blockIdx.x;
    const float* p = x + (size_t)bc * HW;
    float s = 0.f, ss = 0.f;
    for (int i = threadIdx.x; i < HW; i += 256) {
        float v = p[i];
        s += v; ss = fmaf(v, v, ss);
    }
#pragma unroll
    for (int o = 32; o; o >>= 1) { s += __shfl_down(s, o); ss += __shfl_down(ss, o); }
    if ((threadIdx.x & 63) == 0) {
        sh[(threadIdx.x >> 6) * 2] = s;
        sh[(threadIdx.x >> 6) * 2 + 1] = ss;
    }
    __syncthreads();
    if (threadIdx.x == 0) {
        s  = sh[0] + sh[2] + sh[4] + sh[6];
        ss = sh[1] + sh[3] + sh[5] + sh[7];
        float m   = s / HW;
        float var = ss / HW - m * m;
        stats[2 * bc]     = m;
        stats[2 * bc + 1] = rsqrtf(var + 1e-5f);
    }
}

template <int MODE, bool WF32, bool WT16>
__global__ __launch_bounds__(256) void inorm_apply(
    float* __restrict__ x, const float* __restrict__ stats,
    const float* __restrict__ res, int lgHW, int lgC, size_t total,
    u16* __restrict__ tout)
{
    size_t i = (size_t)blockIdx.x * 256 + threadIdx.x;
    if (i >= total) return;
    int bc = (int)(i >> lgHW);
    float m = stats[2 * bc], r = stats[2 * bc + 1];
    float v = (x[i] - m) * r;
    if (MODE == 1) v = fmaxf(v, 0.f);
    if (MODE == 2) v += res[i];
    if (WF32) x[i] = v;
    if (WT16) {
        int px = (int)(i & (((size_t)1 << lgHW) - 1));
        int c = bc & ((1 << lgC) - 1);
        int b = bc >> lgC;
        size_t o = ((((size_t)(b << (lgC - 5)) + (c >> 5)) << lgHW) + px) * 32 + (c & 31);
        tout[o] = f2bf(v);
    }
}

// ---------------------- c3: two-stage conv ---------------------------------
// src0 = CP1T bf16 chunked [b][2][HW][32] (ch 0..63), src1 = R2 fp32 NCHW.
template <int K>
__global__ __launch_bounds__(256) void conv_part(
    const u16* __restrict__ src0,
    const float* __restrict__ src1,
    const float* __restrict__ w,      // [3][128][K2]
    float* __restrict__ part, int H, int W)
{
    constexpr int P = (K - 1) / 2, LT = 16 + K - 1, K2 = K * K;
    __shared__ float tile[LT * LT];
    __shared__ float wsm[16 * 3 * K2];
    const int b = blockIdx.z;
    const int chunk = blockIdx.y;
    const int tilesX = W / 16;
    const int tileY = (blockIdx.x / tilesX) * 16;
    const int tileX = (blockIdx.x % tilesX) * 16;
    const int ty = threadIdx.x / 16, tx = threadIdx.x % 16;
    const int HW = H * W;

    for (int i = threadIdx.x; i < 16 * 3 * K2; i += 256) {
        int tap = i % K2;
        int oc  = (i / K2) % 3;
        int icl = i / (3 * K2);
        wsm[i] = w[((size_t)oc * 128 + chunk * 16 + icl) * K2 + tap];
    }

    int pidx0 = -1, pidx1 = -1;
    {
        int l = threadIdx.x;
        if (l < LT * LT) {
            int gy = tileY - P + l / LT, gx = tileX - P + l % LT;
            gy = gy < 0 ? -gy : (gy >= H ? 2 * H - 2 - gy : gy);
            gx = gx < 0 ? -gx : (gx >= W ? 2 * W - 2 - gx : gx);
            pidx0 = gy * W + gx;
        }
        l += 256;
        if (l < LT * LT) {
            int gy = tileY - P + l / LT, gx = tileX - P + l % LT;
            gy = gy < 0 ? -gy : (gy >= H ? 2 * H - 2 - gy : gy);
            gx = gx < 0 ? -gx : (gx >= W ? 2 * W - 2 - gx : gx);
            pidx1 = gy * W + gx;
        }
    }

    float acc[3] = {0.f, 0.f, 0.f};
    for (int icl = 0; icl < 16; ++icl) {
        int ic = chunk * 16 + icl;
        __syncthreads();
        if (ic < 64) {
            const u16* sp = src0 + ((size_t)(b * 2 + (ic >> 5)) * HW) * 32 + (ic & 31);
            if (pidx0 >= 0) tile[threadIdx.x] = bf2f(sp[(size_t)pidx0 * 32]);
            if (pidx1 >= 0) tile[threadIdx.x + 256] = bf2f(sp[(size_t)pidx1 * 32]);
        } else {
            const float* sp = src1 + ((size_t)b * 64 + (ic - 64)) * HW;
            if (pidx0 >= 0) tile[threadIdx.x] = sp[pidx0];
            if (pidx1 >= 0) tile[threadIdx.x + 256] = sp[pidx1];
        }
        __syncthreads();
        const float* wr = &wsm[icl * 3 * K2];
#pragma unroll
        for (int ky = 0; ky < K; ++ky) {
#pragma unroll
            for (int kx = 0; kx < K; ++kx) {
                float v = tile[(ty + ky) * LT + tx + kx];
                int tap = ky * K + kx;
                acc[0] = fmaf(wr[tap], v, acc[0]);
                acc[1] = fmaf(wr[K2 + tap], v, acc[1]);
                acc[2] = fmaf(wr[2 * K2 + tap], v, acc[2]);
            }
        }
    }
    int px = (tileY + ty) * W + tileX + tx;
    size_t base = (((size_t)chunk * 4 + b) * 3) * HW + px;
    part[base]          = acc[0];
    part[base + HW]     = acc[1];
    part[base + 2 * HW] = acc[2];
}

__global__ __launch_bounds__(256) void conv_reduce(
    const float* __restrict__ part, const float* __restrict__ bias,
    float* __restrict__ out, int HW)
{
    int i = blockIdx.x * 256 + threadIdx.x;
    if (i >= 12 * HW) return;
    int px = i % HW;
    int oc = (i / HW) % 3;
    int b  = i / (3 * HW);
    float s = bias[oc];
#pragma unroll
    for (int ch = 0; ch < 8; ++ch)
        s += part[(((size_t)ch * 4 + b) * 3 + oc) * HW + px];
    out[i] = tanhf(s);
}

// ---------------------------------------------------------------------------
// MFMA deformable conv. featT = bf16 chunked [b][C/32][HW][32] (gather along
// channels: coalesced 64B lines). Per tap: build val[64px][C] bf16 in LDS
// (bilinear*mask folded, XOR-swizzled), then 16x16x32 MFMA vs packed weights.
// Output bf16 chunked [b][O/32][HW][32].
// ---------------------------------------------------------------------------
template <int C, int O, int MF>
__global__ __launch_bounds__(256) void deform_mfma(
    const u16* __restrict__ featT, const float* __restrict__ om,
    const u16* __restrict__ dwt, const float* __restrict__ bias,
    u16* __restrict__ outT, int H, int W, int lgW)
{
    constexpr int NOB = O / 16, NCC = C / 32;
    constexpr int NT = 576;          // 64 px * 9 taps
    constexpr int CPT = C / 4;       // channels per gather thread
    const int HW = H * W;
    const int b  = blockIdx.y;
    const int p0 = blockIdx.x * 64;
    const int tid = threadIdx.x;
    const int wv = tid >> 6, lane = tid & 63, lm = lane & 15, lg = lane >> 4;

    __shared__ int   sO[4][NT];
    __shared__ float sW[4][NT];
    __shared__ u16   val[64 * C];

    // ---- Phase A: per-(px,tap) bilinear offsets/weights ----
    for (int t = tid; t < NT; t += 256) {
        int px = t & 63, k = t >> 6;
        int p  = p0 + px;
        int hh = p >> lgW, ww = p & (W - 1);
        float dy = om[((size_t)b * 27 + k) * HW + p];
        float dx = om[((size_t)b * 27 + 9 + k) * HW + p];
        float mk = 1.f / (1.f + __expf(-om[((size_t)b * 27 + 18 + k) * HW + p]));
        float py  = (float)(hh + k / 3 - 1) + dy;
        float pxf = (float)(ww + k % 3 - 1) + dx;
        float y0f = floorf(py), x0f = floorf(pxf);
        int y0 = (int)y0f, x0 = (int)x0f;
        float wy = py - y0f, wx = pxf - x0f;
        float vy0 = ((unsigned)y0       < (unsigned)H) ? 1.f : 0.f;
        float vy1 = ((unsigned)(y0 + 1) < (unsigned)H) ? 1.f : 0.f;
        float vx0 = ((unsigned)x0       < (unsigned)W) ? 1.f : 0.f;
        float vx1 = ((unsigned)(x0 + 1) < (unsigned)W) ? 1.f : 0.f;
        int y0c = min(max(y0, 0), H - 1), y1c = min(max(y0 + 1, 0), H - 1);
        int x0c = min(max(x0, 0), W - 1), x1c = min(max(x0 + 1, 0), W - 1);
        sO[0][t] = y0c * W + x0c;  sO[1][t] = y0c * W + x1c;
        sO[2][t] = y1c * W + x0c;  sO[3][t] = y1c * W + x1c;
        sW[0][t] = (1.f - wy) * (1.f - wx) * vy0 * vx0 * mk;
        sW[1][t] = (1.f - wy) * wx         * vy0 * vx1 * mk;
        sW[2][t] = wy         * (1.f - wx) * vy1 * vx0 * mk;
        sW[3][t] = wy         * wx         * vy1 * vx1 * mk;
    }
    __syncthreads();

    float4v acc[MF][4];
#pragma unroll
    for (int m = 0; m < MF; ++m)
#pragma unroll
        for (int n = 0; n < 4; ++n) acc[m][n] = (float4v){0.f, 0.f, 0.f, 0.f};

    const int gpx = tid >> 2, gc0 = (tid & 3) * CPT;

    for (int k = 0; k < 9; ++k) {
        if (k) __syncthreads();
        // ---- gather + lerp -> val[gpx][gc0..gc0+CPT) ----
        {
            int t = k * 64 + gpx;
            int o0 = sO[0][t], o1 = sO[1][t], o2 = sO[2][t], o3 = sO[3][t];
            float w0 = sW[0][t], w1 = sW[1][t], w2 = sW[2][t], w3 = sW[3][t];
#pragma unroll
            for (int c8 = 0; c8 < CPT / 8; ++c8) {
                int c = gc0 + c8 * 8;
                const u16* base = featT + ((size_t)(b * NCC + (c >> 5)) * HW) * 32 + (c & 31);
                uint4 r0 = *(const uint4*)(base + (size_t)o0 * 32);
                uint4 r1 = *(const uint4*)(base + (size_t)o1 * 32);
                uint4 r2 = *(const uint4*)(base + (size_t)o2 * 32);
                uint4 r3 = *(const uint4*)(base + (size_t)o3 * 32);
                const u16* p0_ = (const u16*)&r0;
                const u16* p1_ = (const u16*)&r1;
                const u16* p2_ = (const u16*)&r2;
                const u16* p3_ = (const u16*)&r3;
                u16 outv[8];
#pragma unroll
                for (int j = 0; j < 8; ++j) {
                    float s = w0 * bf2f(p0_[j]) + w1 * bf2f(p1_[j])
                            + w2 * bf2f(p2_[j]) + w3 * bf2f(p3_[j]);
                    outv[j] = f2bf(s);
                }
                int csw = c ^ ((gpx & 7) << 3);   // XOR swizzle (bank spread)
                *(uint4*)(val + gpx * C + csw) = *(uint4*)outv;
            }
        }
        __syncthreads();
        // ---- MFMA: acc += W[k] * val ----
        const u16* wk = dwt + (size_t)k * NOB * NCC * 512;
#pragma unroll
        for (int m = 0; m < MF; ++m) {
            int ob = wv * MF + m;
#pragma unroll
            for (int cc = 0; cc < NCC; ++cc) {
                short8 Af = *(const short8*)(wk + ((size_t)ob * NCC + cc) * 512 + lane * 8);
#pragma unroll
                for (int nf = 0; nf < 4; ++nf) {
                    int row = nf * 16 + lm;
                    int csw = (cc * 32 + lg * 8) ^ ((row & 7) << 3);
                    short8 Bf = *(const short8*)(val + row * C + csw);
                    acc[m][nf] = mfma16(Af, Bf, acc[m][nf]);
                }
            }
        }
    }

    // ---- epilogue: bias + bf16 chunked store ----
#pragma unroll
    for (int m = 0; m < MF; ++m) {
        int oc0 = (wv * MF + m) * 16 + lg * 4;
#pragma unroll
        for (int nf = 0; nf < 4; ++nf) {
            int p = p0 + nf * 16 + lm;
#pragma unroll
            for (int r = 0; r < 4; ++r) {
                int oc = oc0 + r;
                outT[((size_t)(b * (O / 32) + (oc >> 5)) * HW + p) * 32 + (oc & 31)]
                    = f2bf(acc[m][nf][r] + bias[oc]);
            }
        }
    }
}

// ---------------------- offset |mean| reductions --------------------------
__global__ __launch_bounds__(256) void absmean_partial(
    const float* __restrict__ om, int HW, float* __restrict__ partial)
{
    const int n18 = 18 * HW;
    const long long total = 4LL * n18;
    float s = 0.f;
    for (long long i = (long long)blockIdx.x * 256 + threadIdx.x; i < total;
         i += (long long)gridDim.x * 256) {
        int b = (int)(i / n18);
        int r = (int)(i % n18);
        s += fabsf(om[(size_t)b * 27 * HW + r]);
    }
    __shared__ float sh[4];
#pragma unroll
    for (int o = 32; o; o >>= 1) s += __shfl_down(s, o);
    if ((threadIdx.x & 63) == 0) sh[threadIdx.x >> 6] = s;
    __syncthreads();
    if (threadIdx.x == 0) partial[blockIdx.x] = sh[0] + sh[1] + sh[2] + sh[3];
}

__global__ __launch_bounds__(256) void finalize_k(
    const float* __restrict__ p1, const float* __restrict__ p2,
    float* __restrict__ outScalar)
{
    __shared__ float sh[8];
    float a = p1[threadIdx.x] + p1[threadIdx.x + 256];
    float b = p2[threadIdx.x] + p2[threadIdx.x + 256];
#pragma unroll
    for (int o = 32; o; o >>= 1) { a += __shfl_down(a, o); b += __shfl_down(b, o); }
    if ((threadIdx.x & 63) == 0) {
        sh[(threadIdx.x >> 6) * 2]     = a;
        sh[(threadIdx.x >> 6) * 2 + 1] = b;
    }
    __syncthreads();
    if (threadIdx.x == 0) {
        a = sh[0] + sh[2] + sh[4] + sh[6];
        b = sh[1] + sh[3] + sh[5] + sh[7];
        *outScalar = 0.5f * (a / (4.f * 18.f * 16384.f) + b / (4.f * 18.f * 4096.f));
    }
}

// ---------------------------------------------------------------------------
extern "C" void kernel_launch(void* const* d_in, const int* in_sizes, int n_in,
                              void* d_out, int out_size, void* d_ws, size_t ws_size,
                              hipStream_t stream)
{
    const float* x      = (const float*)d_in[0];
    const float* skip1  = (const float*)d_in[1];
    const float* skip2  = (const float*)d_in[2];
    const float* rb1_w1 = (const float*)d_in[3];
    const float* rb1_b1 = (const float*)d_in[4];
    const float* rb1_w2 = (const float*)d_in[5];
    const float* rb1_b2 = (const float*)d_in[6];
    const float* rb2_w1 = (const float*)d_in[7];
    const float* rb2_b1 = (const float*)d_in[8];
    const float* rb2_w2 = (const float*)d_in[9];
    const float* rb2_b2 = (const float*)d_in[10];
    const float* c1_w   = (const float*)d_in[11];
    const float* c1_b   = (const float*)d_in[12];
    const float* c2_w   = (const float*)d_in[13];
    const float* c2_b   = (const float*)d_in[14];
    const float* c3_w   = (const float*)d_in[15];
    const float* c3_b   = (const float*)d_in[16];
    const float* off2_w = (const float*)d_in[17];
    const float* off2_b = (const float*)d_in[18];
    const float* d2_w   = (const float*)d_in[19];
    const float* d2_b   = (const float*)d_in[20];
    const float* off1_w = (const float*)d_in[21];
    const float* off1_b = (const float*)d_in[22];
    const float* d1_w   = (const float*)d_in[23];
    const float* d1_b   = (const float*)d_in[24];

    float* ws    = (float*)d_ws;
    float* stats = ws;
    float* part2 = ws + 2048;
    float* part1 = ws + 2560;

    // ---- weight pack arenas (words) ----
    u16* wtRB = (u16*)(ws + 4096);     // 294912 w, JIT-reused for 4 rb convs
    u16* wtC1 = (u16*)(ws + 299008);   // 409600 w
    u16* wtC2 = (u16*)(ws + 708608);   // 204800 w
    u16* wtO2 = (u16*)(ws + 913408);   // 36864 w
    u16* wtO1 = (u16*)(ws + 950272);   // 18432 w
    // ---- Z1: R2 fp32 (4M w) with early overlays ----
    float* R2  = ws + 968704;                  // [c2 -> c3]
    u16*  xT   = (u16*)(ws + 968704);          // then A1T
    u16*  A1T  = xT;
    u16*  A2T  = (u16*)(ws + 968704 + 524288); // then A3T
    u16*  A3T  = A2T;
    float* A1  = ws + 968704 + 1048576;
    float* A2  = ws + 968704 + 2097152;
    float* A3  = ws + 968704 + 3145728;
    float* OM2 = ws + 968704;                  // [off2 -> deform2]
    // ---- Z2: s1T (gather source for deform1) ----
    u16*  s1T  = (u16*)(ws + 5163008);         // 2M w [-> deform1]
    float* PART = ws + 5163008;                // 1572864 w [c3 s1 -> s2, after deform1]
    // ---- Z3: R1 / wtD2+CP2T / R2T / CP1T overlays ----
    float* R1  = ws + 7260160;                 // 2M w [c1 -> apply]
    u16*  wtD2 = (u16*)(ws + 7260160);         // 73728 w [-> deform2]
    u16*  CP2T = (u16*)(ws + 7333888);         // 1048576 w [deform2 -> c2]
    u16*  R2T  = (u16*)(ws + 7260160);         // 2M w [apply(after c2) -> off1]
    u16*  CP1T = (u16*)(ws + 7260160);         // 2M w [deform1 -> c3]
    // ---- Z4: R1T then OM1 ----
    u16*  R1T  = (u16*)(ws + 9357312);         // 1M w [-> c2]
    float* OM1 = ws + 9357312;                 // 1769472 w [off1 -> deform1]
    // ---- Z5: s2T (gather source for deform2); tail holds wtD1 ----
    u16*  s2T  = (u16*)(ws + 10405888);        // 1M w [-> deform2]
    u16*  wtD1 = (u16*)(ws + 11126784);        // 18432 w [-> deform1]

    float* outp = (float*)d_out;
    dim3 blk(256);

    // ---- input transforms ----
    act2t<<<4096, blk, 0, stream>>>(x, xT, 10, 8, 1048576);
    act2t<<<16384, blk, 0, stream>>>(skip1, s1T, 14, 6, 4194304);
    act2t<<<8192, blk, 0, stream>>>(skip2, s2T, 12, 7, 2097152);

    // ---- resblock 1 conv 1 ----
    wtrans<<<2304, blk, 0, stream>>>(rb1_w1, wtRB, 256, 256, 9, 16, 589824);
    mconv<3, false, true, 4><<<dim3(4, 4, 4), blk, 21760, stream>>>(
        xT, 8, nullptr, 8, wtRB, 16, rb1_b1, A1, 256, 32, 5, 8, 32, 32);
    inorm_stats<<<1024, blk, 0, stream>>>(A1, stats, 1024);
    inorm_apply<1, false, true><<<4096, blk, 0, stream>>>(A1, stats, nullptr, 10, 8, 1048576, A1T);
    // ---- resblock 1 conv 2 ----
    wtrans<<<2304, blk, 0, stream>>>(rb1_w2, wtRB, 256, 256, 9, 16, 589824);
    mconv<3, false, true, 4><<<dim3(4, 4, 4), blk, 21760, stream>>>(
        A1T, 8, nullptr, 8, wtRB, 16, rb1_b2, A2, 256, 32, 5, 8, 32, 32);
    inorm_stats<<<1024, blk, 0, stream>>>(A2, stats, 1024);
    inorm_apply<2, true, true><<<4096, blk, 0, stream>>>(A2, stats, x, 10, 8, 1048576, A2T);
    // ---- resblock 2 conv 1 ----
    wtrans<<<2304, blk, 0, stream>>>(rb2_w1, wtRB, 256, 256, 9, 16, 589824);
    mconv<3, false, true, 4><<<dim3(4, 4, 4), blk, 21760, stream>>>(
        A2T, 8, nullptr, 8, wtRB, 16, rb2_b1, A1, 256, 32, 5, 8, 32, 32);
    inorm_stats<<<1024, blk, 0, stream>>>(A1, stats, 1024);
    inorm_apply<1, false, true><<<4096, blk, 0, stream>>>(A1, stats, nullptr, 10, 8, 1048576, A1T);
    // ---- resblock 2 conv 2 ----
    wtrans<<<2304, blk, 0, stream>>>(rb2_w2, wtRB, 256, 256, 9, 16, 589824);
    mconv<3, false, true, 4><<<dim3(4, 4, 4), blk, 21760, stream>>>(
        A1T, 8, nullptr, 8, wtRB, 16, rb2_b2, A3, 256, 32, 5, 8, 32, 32);
    inorm_stats<<<1024, blk, 0, stream>>>(A3, stats, 1024);
    inorm_apply<2, false, true><<<4096, blk, 0, stream>>>(A3, stats, A2, 10, 8, 1048576, A3T);
    // ---- c1: up2 + 5x5 reflect, 256->128 @64 ----
    wtrans<<<3200, blk, 0, stream>>>(c1_w, wtC1, 128, 256, 25, 8, 819200);
    mconv<5, true, true, 4><<<dim3(16, 2, 4), blk, 34816, stream>>>(
        A3T, 8, nullptr, 8, wtC1, 8, c1_b, R1, 128, 64, 6, 4, 32, 64);
    inorm_stats<<<512, blk, 0, stream>>>(R1, stats, 4096);
    inorm_apply<1, false, true><<<8192, blk, 0, stream>>>(R1, stats, nullptr, 12, 7, 2097152, R1T);
    // ---- off2: concat(R1T, s2T) 3x3 zero-pad -> 27ch ----
    wtrans<<<288, blk, 0, stream>>>(off2_w, wtO2, 27, 256, 9, 2, 73728);
    mconv<3, false, false, 2><<<dim3(16, 1, 4), blk, 25344, stream>>>(
        R1T, 4, s2T, 8, wtO2, 2, off2_b, OM2, 27, 64, 6, 4, 64, 64);
    absmean_partial<<<512, blk, 0, stream>>>(OM2, 4096, part2);
    // ---- deform 2 (MFMA, gather from s2T) ----
    dwtrans<128, 128><<<576, blk, 0, stream>>>(d2_w, wtD2);
    deform_mfma<128, 128, 2><<<dim3(64, 4), blk, 0, stream>>>(
        s2T, OM2, wtD2, d2_b, CP2T, 64, 64, 6);
    // ---- c2: up2(concat(CP2T, R1T)) + 5x5 reflect, 256->64 @128 ----
    wtrans<<<1600, blk, 0, stream>>>(c2_w, wtC2, 64, 256, 25, 4, 409600);
    mconv<5, true, true, 4><<<dim3(64, 1, 4), blk, 50688, stream>>>(
        CP2T, 4, R1T, 8, wtC2, 4, c2_b, R2, 64, 128, 7, 2, 64, 128);
    inorm_stats<<<256, blk, 0, stream>>>(R2, stats, 16384);
    inorm_apply<1, true, true><<<16384, blk, 0, stream>>>(R2, stats, nullptr, 14, 6, 4194304, R2T);
    // ---- off1: concat(R2T, s1T) 3x3 zero-pad -> 27ch ----
    wtrans<<<144, blk, 0, stream>>>(off1_w, wtO1, 27, 128, 9, 2, 36864);
    mconv<3, false, false, 2><<<dim3(64, 1, 4), blk, 33280, stream>>>(
        R2T, 2, s1T, 4, wtO1, 2, off1_b, OM1, 27, 128, 7, 2, 128, 128);
    absmean_partial<<<512, blk, 0, stream>>>(OM1, 16384, part1);
    // ---- deform 1 (MFMA, gather from s1T) ----
    dwtrans<64, 64><<<144, blk, 0, stream>>>(d1_w, wtD1);
    deform_mfma<64, 64, 1><<<dim3(256, 4), blk, 0, stream>>>(
        s1T, OM1, wtD1, d1_b, CP1T, 128, 128, 7);
    // ---- c3: concat(CP1T, R2) 7x7 reflect + tanh -> 3ch, two-stage ----
    conv_part<7><<<dim3(64, 8, 4), blk, 0, stream>>>(CP1T, R2, c3_w, PART, 128, 128);
    conv_reduce<<<768, blk, 0, stream>>>(PART, c3_b, outp, 16384);
    // ---- offset_sum ----
    finalize_k<<<1, blk, 0, stream>>>(part1, part2, outp + 196608);
}

// Round 7
// 744.421 us; speedup vs baseline: 6.0588x; 1.4025x over previous
//
#include <hip/hip_runtime.h>
#include <hip/hip_bf16.h>

#define DEV __device__ __forceinline__

typedef unsigned short u16;
typedef __attribute__((ext_vector_type(8))) short short8;
typedef __attribute__((ext_vector_type(4))) float float4v;

DEV u16 f2bf(float v) {
    __hip_bfloat16 h = __float2bfloat16(v);
    return *reinterpret_cast<u16*>(&h);
}
DEV float bf2f(u16 u) { return __uint_as_float(((unsigned)u) << 16); }

DEV float4v mfma16(short8 a, short8 b, float4v c) {
    return __builtin_amdgcn_mfma_f32_16x16x32_bf16(a, b, c, 0, 0, 0);
}

// ---------------------------------------------------------------------------
// MFMA conv, 2-phase pipelined. Input bf16 chunked [b][ch][px][32ic] (virtual
// concat X0|X1), optional fused 2x upsample, reflect or zero pad.
// Block: 256 thr = 4 waves = NWO oc-groups x NWP px-groups; wave = 16oc x 64px.
// Tile: TW x TH output px (TW*TH = NWP*64). LDS: double-buffered, icg-major
// [icg][t][8ch] -> conflict-free ds_read_b128, compile-time offsets.
// Per-chunk: issue next loads (regs) -> MFMA cur buf -> ds_write next -> bar.
// ---------------------------------------------------------------------------
template <int K, bool UP, bool REFLECT, int NWO, int LGTW, int TH>
__global__ __launch_bounds__(256) void mconv(
    const u16* __restrict__ X0, int c0ch,
    const u16* __restrict__ X1, int nch,
    const u16* __restrict__ WT, int NOB,
    const float* __restrict__ bias, float* __restrict__ out,
    int OC, int W, int H, int tilesX, int SW)
{
    constexpr int P    = (K - 1) / 2;
    constexpr int K2   = K * K;
    constexpr int NWP  = 4 / NWO;
    constexpr int TW   = 1 << LGTW;
    constexpr int LW   = TW + K - 1;
    constexpr int ROWS = TH + K - 1;
    constexpr int IT   = ROWS * LW;          // 16B slots per icg
    constexpr int ITEMS = IT * 4;            // total 16B slots
    constexpr int CEIL = (ITEMS + 255) / 256;
    constexpr int BUF  = CEIL * 2048;        // u16 per buffer

    extern __shared__ u16 Xs[];
    const int tid = threadIdx.x;
    const int wv = tid >> 6, lane = tid & 63, lm = lane & 15, lg = lane >> 4;
    const int wo = wv / NWP, wp = wv % NWP;
    const int bx = blockIdx.x, b = blockIdx.z;
    const int ty = bx / tilesX, tx = bx - ty * tilesX;
    const int row0 = ty * TH, col0 = tx * TW;
    const int SH  = UP ? (H >> 1) : H;
    const int HWs = SW * SH;
    const int ob  = blockIdx.y * NWO + wo;

    // ---- per-item source offsets (u16 units in channel plane), ch-invariant
    int offr[CEIL];
#pragma unroll
    for (int i = 0; i < CEIL; ++i) {
        int q = i * 256 + tid;
        bool tail = q >= ITEMS;
        if (tail) q = ITEMS - 1;
        int icg = q / IT;
        int t   = q - icg * IT;
        int tr  = t / LW, tc = t - tr * LW;
        int gy = row0 - P + tr, gx = col0 - P + tc;
        if (REFLECT) {
            gy = gy < 0 ? -gy : (gy >= H ? 2 * H - 2 - gy : gy);
            gx = gx < 0 ? -gx : (gx >= W ? 2 * W - 2 - gx : gx);
            int sy = UP ? (gy >> 1) : gy, sx = UP ? (gx >> 1) : gx;
            offr[i] = (sy * SW + sx) * 32 + icg * 8;
        } else {
            bool ok = (gy >= 0) & (gy < H) & (gx >= 0) & (gx < W) & !tail;
            int sy = UP ? (gy >> 1) : gy, sx = UP ? (gx >> 1) : gx;
            offr[i] = ok ? (sy * SW + sx) * 32 + icg * 8 : -1;
        }
    }

    // ---- per-nf bases: LDS read offset (u16) and output pixel
    int rb16[4], opx[4];
#pragma unroll
    for (int nf = 0; nf < 4; ++nf) {
        int pt = wp * 64 + nf * 16 + lm;
        int ro = pt >> LGTW, co = pt & (TW - 1);
        rb16[nf] = (lg * IT + ro * LW + co) * 8;
        opx[nf]  = (row0 + ro) * W + col0 + co;
    }

    float4v acc[4];
#pragma unroll
    for (int n = 0; n < 4; ++n) acc[n] = (float4v){0.f, 0.f, 0.f, 0.f};

    auto planeptr = [&](int ch) -> const u16* {
        return (ch < c0ch)
            ? X0 + (size_t)(b * c0ch + ch) * HWs * 32
            : X1 + (size_t)(b * (nch - c0ch) + (ch - c0ch)) * HWs * 32;
    };
    const uint4 UZ = {0u, 0u, 0u, 0u};
    uint4 rv[CEIL];

    // ---- prologue: chunk 0 ----
    {
        const u16* src = planeptr(0);
#pragma unroll
        for (int i = 0; i < CEIL; ++i)
            rv[i] = (offr[i] >= 0) ? *(const uint4*)(src + offr[i]) : UZ;
#pragma unroll
        for (int i = 0; i < CEIL; ++i)
            *(uint4*)(Xs + (size_t)(i * 256 + tid) * 8) = rv[i];
    }
    __syncthreads();

    int cur = 0;
    for (int ch = 0; ch < nch; ++ch) {
        // issue next-chunk loads (hide under MFMA phase)
        if (ch + 1 < nch) {
            const u16* src = planeptr(ch + 1);
#pragma unroll
            for (int i = 0; i < CEIL; ++i)
                rv[i] = (offr[i] >= 0) ? *(const uint4*)(src + offr[i]) : UZ;
        }
        // MFMA on current buffer
        const u16* base = Xs + cur * BUF;
        const u16* wch  = WT + ((size_t)ch * NOB + ob) * K2 * 512 + lane * 8;
#pragma unroll
        for (int ky = 0; ky < K; ++ky) {
#pragma unroll
            for (int kx = 0; kx < K; ++kx) {
                short8 Af = *(const short8*)(wch + (size_t)(ky * K + kx) * 512);
#pragma unroll
                for (int nf = 0; nf < 4; ++nf) {
                    short8 Bf = *(const short8*)(base + rb16[nf] + (ky * LW + kx) * 8);
                    acc[nf] = mfma16(Af, Bf, acc[nf]);
                }
            }
        }
        // write next buffer, one barrier per chunk
        if (ch + 1 < nch) {
            u16* dst = Xs + (cur ^ 1) * BUF;
#pragma unroll
            for (int i = 0; i < CEIL; ++i)
                *(uint4*)(dst + (size_t)(i * 256 + tid) * 8) = rv[i];
            __syncthreads();
            cur ^= 1;
        }
    }

    // ---- epilogue ----
    const size_t HWo = (size_t)H * W;
    int oc0 = ob * 16 + lg * 4;
#pragma unroll
    for (int nf = 0; nf < 4; ++nf) {
#pragma unroll
        for (int r = 0; r < 4; ++r) {
            int oc = oc0 + r;
            if (oc < OC)
                out[(size_t)(b * OC + oc) * HWo + opx[nf]] = acc[nf][r] + bias[oc];
        }
    }
}

// ---------------------------------------------------------------------------
// Weight pack: w[OC][IC][K2] fp32 -> wt[ch][ob][tap][lane][8] bf16 (A-frag).
// ---------------------------------------------------------------------------
__global__ __launch_bounds__(256) void wtrans(
    const float* __restrict__ w, u16* __restrict__ wt,
    int OC, int IC, int K2, int NOB, int total)
{
    int i = blockIdx.x * 256 + threadIdx.x;
    if (i >= total) return;
    int e = i & 7;
    int l = (i >> 3) & 63;
    int rest = i >> 9;
    int tap = rest % K2;
    rest /= K2;
    int ob = rest % NOB;
    int ch = rest / NOB;
    int oc = ob * 16 + (l & 15);
    if (oc >= OC) oc = OC - 1;
    int ic = ch * 32 + (l >> 4) * 8 + e;
    wt[i] = f2bf(w[((size_t)oc * IC + ic) * K2 + tap]);
}

// Deform weight pack: w[O][C][9] fp32 -> dwt[k][ob][cc][lane][8] bf16.
template <int C, int O>
__global__ __launch_bounds__(256) void dwtrans(
    const float* __restrict__ w, u16* __restrict__ dwt)
{
    constexpr int NOB = O / 16, NCC = C / 32;
    constexpr int total = 9 * NOB * NCC * 512;
    int i = blockIdx.x * 256 + threadIdx.x;
    if (i >= total) return;
    int e = i & 7;
    int l = (i >> 3) & 63;
    int rest = i >> 9;
    int cc = rest % NCC;
    rest /= NCC;
    int ob = rest % NOB;
    int k  = rest / NOB;
    int oc = ob * 16 + (l & 15);
    int ic = cc * 32 + (l >> 4) * 8 + e;
    dwt[i] = f2bf(w[((size_t)oc * C + ic) * 9 + k]);
}

// ---------------------------------------------------------------------------
// fp32 NCHW -> bf16 [b][chunk][px][32ic]
// ---------------------------------------------------------------------------
__global__ __launch_bounds__(256) void act2t(
    const float* __restrict__ in, u16* __restrict__ out,
    int lgHW, int lgC, size_t total)
{
    size_t i = (size_t)blockIdx.x * 256 + threadIdx.x;
    if (i >= total) return;
    int px = (int)(i & (((size_t)1 << lgHW) - 1));
    int bc = (int)(i >> lgHW);
    int c = bc & ((1 << lgC) - 1);
    int b = bc >> lgC;
    size_t o = ((((size_t)(b << (lgC - 5)) + (c >> 5)) << lgHW) + px) * 32 + (c & 31);
    out[o] = f2bf(in[i]);
}

// ---------------------- instance norm -------------------------------------
__global__ __launch_bounds__(256) void inorm_stats(
    const float* __restrict__ x, float* __restrict__ stats, int HW)
{
    __shared__ float sh[8];
    const int bc = blockIdx.x;
    const float* p = x + (size_t)bc * HW;
    float s = 0.f, ss = 0.f;
    for (int i = threadIdx.x; i < HW; i += 256) {
        float v = p[i];
        s += v; ss = fmaf(v, v, ss);
    }
#pragma unroll
    for (int o = 32; o; o >>= 1) { s += __shfl_down(s, o); ss += __shfl_down(ss, o); }
    if ((threadIdx.x & 63) == 0) {
        sh[(threadIdx.x >> 6) * 2] = s;
        sh[(threadIdx.x >> 6) * 2 + 1] = ss;
    }
    __syncthreads();
    if (threadIdx.x == 0) {
        s  = sh[0] + sh[2] + sh[4] + sh[6];
        ss = sh[1] + sh[3] + sh[5] + sh[7];
        float m   = s / HW;
        float var = ss / HW - m * m;
        stats[2 * bc]     = m;
        stats[2 * bc + 1] = rsqrtf(var + 1e-5f);
    }
}

template <int MODE, bool WF32, bool WT16>
__global__ __launch_bounds__(256) void inorm_apply(
    float* __restrict__ x, const float* __restrict__ stats,
    const float* __restrict__ res, int lgHW, int lgC, size_t total,
    u16* __restrict__ tout)
{
    size_t i = (size_t)blockIdx.x * 256 + threadIdx.x;
    if (i >= total) return;
    int bc = (int)(i >> lgHW);
    float m = stats[2 * bc], r = stats[2 * bc + 1];
    float v = (x[i] - m) * r;
    if (MODE == 1) v = fmaxf(v, 0.f);
    if (MODE == 2) v += res[i];
    if (WF32) x[i] = v;
    if (WT16) {
        int px = (int)(i & (((size_t)1 << lgHW) - 1));
        int c = bc & ((1 << lgC) - 1);
        int b = bc >> lgC;
        size_t o = ((((size_t)(b << (lgC - 5)) + (c >> 5)) << lgHW) + px) * 32 + (c & 31);
        tout[o] = f2bf(v);
    }
}

// ---------------------- c3: two-stage conv ---------------------------------
template <int K>
__global__ __launch_bounds__(256) void conv_part(
    const u16* __restrict__ src0,
    const float* __restrict__ src1,
    const float* __restrict__ w,      // [3][128][K2]
    float* __restrict__ part, int H, int W)
{
    constexpr int P = (K - 1) / 2, LT = 16 + K - 1, K2 = K * K;
    __shared__ float tile[LT * LT];
    __shared__ float wsm[16 * 3 * K2];
    const int b = blockIdx.z;
    const int chunk = blockIdx.y;
    const int tilesX = W / 16;
    const int tileY = (blockIdx.x / tilesX) * 16;
    const int tileX = (blockIdx.x % tilesX) * 16;
    const int ty = threadIdx.x / 16, tx = threadIdx.x % 16;
    const int HW = H * W;

    for (int i = threadIdx.x; i < 16 * 3 * K2; i += 256) {
        int tap = i % K2;
        int oc  = (i / K2) % 3;
        int icl = i / (3 * K2);
        wsm[i] = w[((size_t)oc * 128 + chunk * 16 + icl) * K2 + tap];
    }

    int pidx0 = -1, pidx1 = -1;
    {
        int l = threadIdx.x;
        if (l < LT * LT) {
            int gy = tileY - P + l / LT, gx = tileX - P + l % LT;
            gy = gy < 0 ? -gy : (gy >= H ? 2 * H - 2 - gy : gy);
            gx = gx < 0 ? -gx : (gx >= W ? 2 * W - 2 - gx : gx);
            pidx0 = gy * W + gx;
        }
        l += 256;
        if (l < LT * LT) {
            int gy = tileY - P + l / LT, gx = tileX - P + l % LT;
            gy = gy < 0 ? -gy : (gy >= H ? 2 * H - 2 - gy : gy);
            gx = gx < 0 ? -gx : (gx >= W ? 2 * W - 2 - gx : gx);
            pidx1 = gy * W + gx;
        }
    }

    float acc[3] = {0.f, 0.f, 0.f};
    for (int icl = 0; icl < 16; ++icl) {
        int ic = chunk * 16 + icl;
        __syncthreads();
        if (ic < 64) {
            const u16* sp = src0 + ((size_t)(b * 2 + (ic >> 5)) * HW) * 32 + (ic & 31);
            if (pidx0 >= 0) tile[threadIdx.x] = bf2f(sp[(size_t)pidx0 * 32]);
            if (pidx1 >= 0) tile[threadIdx.x + 256] = bf2f(sp[(size_t)pidx1 * 32]);
        } else {
            const float* sp = src1 + ((size_t)b * 64 + (ic - 64)) * HW;
            if (pidx0 >= 0) tile[threadIdx.x] = sp[pidx0];
            if (pidx1 >= 0) tile[threadIdx.x + 256] = sp[pidx1];
        }
        __syncthreads();
        const float* wr = &wsm[icl * 3 * K2];
#pragma unroll
        for (int ky = 0; ky < K; ++ky) {
#pragma unroll
            for (int kx = 0; kx < K; ++kx) {
                float v = tile[(ty + ky) * LT + tx + kx];
                int tap = ky * K + kx;
                acc[0] = fmaf(wr[tap], v, acc[0]);
                acc[1] = fmaf(wr[K2 + tap], v, acc[1]);
                acc[2] = fmaf(wr[2 * K2 + tap], v, acc[2]);
            }
        }
    }
    int px = (tileY + ty) * W + tileX + tx;
    size_t base = (((size_t)chunk * 4 + b) * 3) * HW + px;
    part[base]          = acc[0];
    part[base + HW]     = acc[1];
    part[base + 2 * HW] = acc[2];
}

__global__ __launch_bounds__(256) void conv_reduce(
    const float* __restrict__ part, const float* __restrict__ bias,
    float* __restrict__ out, int HW)
{
    int i = blockIdx.x * 256 + threadIdx.x;
    if (i >= 12 * HW) return;
    int px = i % HW;
    int oc = (i / HW) % 3;
    int b  = i / (3 * HW);
    float s = bias[oc];
#pragma unroll
    for (int ch = 0; ch < 8; ++ch)
        s += part[(((size_t)ch * 4 + b) * 3 + oc) * HW + px];
    out[i] = tanhf(s);
}

// ---------------------------------------------------------------------------
// MFMA deformable conv.
// ---------------------------------------------------------------------------
template <int C, int O, int MF>
__global__ __launch_bounds__(256) void deform_mfma(
    const u16* __restrict__ featT, const float* __restrict__ om,
    const u16* __restrict__ dwt, const float* __restrict__ bias,
    u16* __restrict__ outT, int H, int W, int lgW)
{
    constexpr int NOB = O / 16, NCC = C / 32;
    constexpr int NT = 576;
    constexpr int CPT = C / 4;
    const int HW = H * W;
    const int b  = blockIdx.y;
    const int p0 = blockIdx.x * 64;
    const int tid = threadIdx.x;
    const int wv = tid >> 6, lane = tid & 63, lm = lane & 15, lg = lane >> 4;

    __shared__ int   sO[4][NT];
    __shared__ float sW[4][NT];
    __shared__ u16   val[64 * C];

    for (int t = tid; t < NT; t += 256) {
        int px = t & 63, k = t >> 6;
        int p  = p0 + px;
        int hh = p >> lgW, ww = p & (W - 1);
        float dy = om[((size_t)b * 27 + k) * HW + p];
        float dx = om[((size_t)b * 27 + 9 + k) * HW + p];
        float mk = 1.f / (1.f + __expf(-om[((size_t)b * 27 + 18 + k) * HW + p]));
        float py  = (float)(hh + k / 3 - 1) + dy;
        float pxf = (float)(ww + k % 3 - 1) + dx;
        float y0f = floorf(py), x0f = floorf(pxf);
        int y0 = (int)y0f, x0 = (int)x0f;
        float wy = py - y0f, wx = pxf - x0f;
        float vy0 = ((unsigned)y0       < (unsigned)H) ? 1.f : 0.f;
        float vy1 = ((unsigned)(y0 + 1) < (unsigned)H) ? 1.f : 0.f;
        float vx0 = ((unsigned)x0       < (unsigned)W) ? 1.f : 0.f;
        float vx1 = ((unsigned)(x0 + 1) < (unsigned)W) ? 1.f : 0.f;
        int y0c = min(max(y0, 0), H - 1), y1c = min(max(y0 + 1, 0), H - 1);
        int x0c = min(max(x0, 0), W - 1), x1c = min(max(x0 + 1, 0), W - 1);
        sO[0][t] = y0c * W + x0c;  sO[1][t] = y0c * W + x1c;
        sO[2][t] = y1c * W + x0c;  sO[3][t] = y1c * W + x1c;
        sW[0][t] = (1.f - wy) * (1.f - wx) * vy0 * vx0 * mk;
        sW[1][t] = (1.f - wy) * wx         * vy0 * vx1 * mk;
        sW[2][t] = wy         * (1.f - wx) * vy1 * vx0 * mk;
        sW[3][t] = wy         * wx         * vy1 * vx1 * mk;
    }
    __syncthreads();

    float4v acc[MF][4];
#pragma unroll
    for (int m = 0; m < MF; ++m)
#pragma unroll
        for (int n = 0; n < 4; ++n) acc[m][n] = (float4v){0.f, 0.f, 0.f, 0.f};

    const int gpx = tid >> 2, gc0 = (tid & 3) * CPT;

    for (int k = 0; k < 9; ++k) {
        if (k) __syncthreads();
        {
            int t = k * 64 + gpx;
            int o0 = sO[0][t], o1 = sO[1][t], o2 = sO[2][t], o3 = sO[3][t];
            float w0 = sW[0][t], w1 = sW[1][t], w2 = sW[2][t], w3 = sW[3][t];
#pragma unroll
            for (int c8 = 0; c8 < CPT / 8; ++c8) {
                int c = gc0 + c8 * 8;
                const u16* base = featT + ((size_t)(b * NCC + (c >> 5)) * HW) * 32 + (c & 31);
                uint4 r0 = *(const uint4*)(base + (size_t)o0 * 32);
                uint4 r1 = *(const uint4*)(base + (size_t)o1 * 32);
                uint4 r2 = *(const uint4*)(base + (size_t)o2 * 32);
                uint4 r3 = *(const uint4*)(base + (size_t)o3 * 32);
                const u16* p0_ = (const u16*)&r0;
                const u16* p1_ = (const u16*)&r1;
                const u16* p2_ = (const u16*)&r2;
                const u16* p3_ = (const u16*)&r3;
                u16 outv[8];
#pragma unroll
                for (int j = 0; j < 8; ++j) {
                    float s = w0 * bf2f(p0_[j]) + w1 * bf2f(p1_[j])
                            + w2 * bf2f(p2_[j]) + w3 * bf2f(p3_[j]);
                    outv[j] = f2bf(s);
                }
                int csw = c ^ ((gpx & 7) << 3);
                *(uint4*)(val + gpx * C + csw) = *(uint4*)outv;
            }
        }
        __syncthreads();
        const u16* wk = dwt + (size_t)k * NOB * NCC * 512;
#pragma unroll
        for (int m = 0; m < MF; ++m) {
            int ob = wv * MF + m;
#pragma unroll
            for (int cc = 0; cc < NCC; ++cc) {
                short8 Af = *(const short8*)(wk + ((size_t)ob * NCC + cc) * 512 + lane * 8);
#pragma unroll
                for (int nf = 0; nf < 4; ++nf) {
                    int row = nf * 16 + lm;
                    int csw = (cc * 32 + lg * 8) ^ ((row & 7) << 3);
                    short8 Bf = *(const short8*)(val + row * C + csw);
                    acc[m][nf] = mfma16(Af, Bf, acc[m][nf]);
                }
            }
        }
    }

#pragma unroll
    for (int m = 0; m < MF; ++m) {
        int oc0 = (wv * MF + m) * 16 + lg * 4;
#pragma unroll
        for (int nf = 0; nf < 4; ++nf) {
            int p = p0 + nf * 16 + lm;
#pragma unroll
            for (int r = 0; r < 4; ++r) {
                int oc = oc0 + r;
                outT[((size_t)(b * (O / 32) + (oc >> 5)) * HW + p) * 32 + (oc & 31)]
                    = f2bf(acc[m][nf][r] + bias[oc]);
            }
        }
    }
}

// ---------------------- offset |mean| reductions --------------------------
__global__ __launch_bounds__(256) void absmean_partial(
    const float* __restrict__ om, int HW, float* __restrict__ partial)
{
    const int n18 = 18 * HW;
    const long long total = 4LL * n18;
    float s = 0.f;
    for (long long i = (long long)blockIdx.x * 256 + threadIdx.x; i < total;
         i += (long long)gridDim.x * 256) {
        int b = (int)(i / n18);
        int r = (int)(i % n18);
        s += fabsf(om[(size_t)b * 27 * HW + r]);
    }
    __shared__ float sh[4];
#pragma unroll
    for (int o = 32; o; o >>= 1) s += __shfl_down(s, o);
    if ((threadIdx.x & 63) == 0) sh[threadIdx.x >> 6] = s;
    __syncthreads();
    if (threadIdx.x == 0) partial[blockIdx.x] = sh[0] + sh[1] + sh[2] + sh[3];
}

__global__ __launch_bounds__(256) void finalize_k(
    const float* __restrict__ p1, const float* __restrict__ p2,
    float* __restrict__ outScalar)
{
    __shared__ float sh[8];
    float a = p1[threadIdx.x] + p1[threadIdx.x + 256];
    float b = p2[threadIdx.x] + p2[threadIdx.x + 256];
#pragma unroll
    for (int o = 32; o; o >>= 1) { a += __shfl_down(a, o); b += __shfl_down(b, o); }
    if ((threadIdx.x & 63) == 0) {
        sh[(threadIdx.x >> 6) * 2]     = a;
        sh[(threadIdx.x >> 6) * 2 + 1] = b;
    }
    __syncthreads();
    if (threadIdx.x == 0) {
        a = sh[0] + sh[2] + sh[4] + sh[6];
        b = sh[1] + sh[3] + sh[5] + sh[7];
        *outScalar = 0.5f * (a / (4.f * 18.f * 16384.f) + b / (4.f * 18.f * 4096.f));
    }
}

// ---------------------------------------------------------------------------
extern "C" void kernel_launch(void* const* d_in, const int* in_sizes, int n_in,
                              void* d_out, int out_size, void* d_ws, size_t ws_size,
                              hipStream_t stream)
{
    const float* x      = (const float*)d_in[0];
    const float* skip1  = (const float*)d_in[1];
    const float* skip2  = (const float*)d_in[2];
    const float* rb1_w1 = (const float*)d_in[3];
    const float* rb1_b1 = (const float*)d_in[4];
    const float* rb1_w2 = (const float*)d_in[5];
    const float* rb1_b2 = (const float*)d_in[6];
    const float* rb2_w1 = (const float*)d_in[7];
    const float* rb2_b1 = (const float*)d_in[8];
    const float* rb2_w2 = (const float*)d_in[9];
    const float* rb2_b2 = (const float*)d_in[10];
    const float* c1_w   = (const float*)d_in[11];
    const float* c1_b   = (const float*)d_in[12];
    const float* c2_w   = (const float*)d_in[13];
    const float* c2_b   = (const float*)d_in[14];
    const float* c3_w   = (const float*)d_in[15];
    const float* c3_b   = (const float*)d_in[16];
    const float* off2_w = (const float*)d_in[17];
    const float* off2_b = (const float*)d_in[18];
    const float* d2_w   = (const float*)d_in[19];
    const float* d2_b   = (const float*)d_in[20];
    const float* off1_w = (const float*)d_in[21];
    const float* off1_b = (const float*)d_in[22];
    const float* d1_w   = (const float*)d_in[23];
    const float* d1_b   = (const float*)d_in[24];

    float* ws    = (float*)d_ws;
    float* stats = ws;
    float* part2 = ws + 2048;
    float* part1 = ws + 2560;

    // ---- weight pack arenas (words) ----
    u16* wtRB = (u16*)(ws + 4096);
    u16* wtC1 = (u16*)(ws + 299008);
    u16* wtC2 = (u16*)(ws + 708608);
    u16* wtO2 = (u16*)(ws + 913408);
    u16* wtO1 = (u16*)(ws + 950272);
    // ---- Z1: R2 fp32 (4M w) with early overlays ----
    float* R2  = ws + 968704;
    u16*  xT   = (u16*)(ws + 968704);
    u16*  A1T  = xT;
    u16*  A2T  = (u16*)(ws + 968704 + 524288);
    u16*  A3T  = A2T;
    float* A1  = ws + 968704 + 1048576;
    float* A2  = ws + 968704 + 2097152;
    float* A3  = ws + 968704 + 3145728;
    float* OM2 = ws + 968704;
    // ---- Z2: s1T ----
    u16*  s1T  = (u16*)(ws + 5163008);
    float* PART = ws + 5163008;
    // ---- Z3: R1 / wtD2+CP2T / R2T / CP1T overlays ----
    float* R1  = ws + 7260160;
    u16*  wtD2 = (u16*)(ws + 7260160);
    u16*  CP2T = (u16*)(ws + 7333888);
    u16*  R2T  = (u16*)(ws + 7260160);
    u16*  CP1T = (u16*)(ws + 7260160);
    // ---- Z4: R1T then OM1 ----
    u16*  R1T  = (u16*)(ws + 9357312);
    float* OM1 = ws + 9357312;
    // ---- Z5: s2T; tail holds wtD1 ----
    u16*  s2T  = (u16*)(ws + 10405888);
    u16*  wtD1 = (u16*)(ws + 11126784);

    float* outp = (float*)d_out;
    dim3 blk(256);

    // ---- input transforms ----
    act2t<<<4096, blk, 0, stream>>>(x, xT, 10, 8, 1048576);
    act2t<<<16384, blk, 0, stream>>>(skip1, s1T, 14, 6, 4194304);
    act2t<<<8192, blk, 0, stream>>>(skip2, s2T, 12, 7, 2097152);

    // ---- resblock 1 conv 1 ----
    wtrans<<<2304, blk, 0, stream>>>(rb1_w1, wtRB, 256, 256, 9, 16, 589824);
    mconv<3, false, true, 2, 5, 4><<<dim3(8, 8, 4), blk, 32768, stream>>>(
        xT, 8, nullptr, 8, wtRB, 16, rb1_b1, A1, 256, 32, 32, 1, 32);
    inorm_stats<<<1024, blk, 0, stream>>>(A1, stats, 1024);
    inorm_apply<1, false, true><<<4096, blk, 0, stream>>>(A1, stats, nullptr, 10, 8, 1048576, A1T);
    // ---- resblock 1 conv 2 ----
    wtrans<<<2304, blk, 0, stream>>>(rb1_w2, wtRB, 256, 256, 9, 16, 589824);
    mconv<3, false, true, 2, 5, 4><<<dim3(8, 8, 4), blk, 32768, stream>>>(
        A1T, 8, nullptr, 8, wtRB, 16, rb1_b2, A2, 256, 32, 32, 1, 32);
    inorm_stats<<<1024, blk, 0, stream>>>(A2, stats, 1024);
    inorm_apply<2, true, true><<<4096, blk, 0, stream>>>(A2, stats, x, 10, 8, 1048576, A2T);
    // ---- resblock 2 conv 1 ----
    wtrans<<<2304, blk, 0, stream>>>(rb2_w1, wtRB, 256, 256, 9, 16, 589824);
    mconv<3, false, true, 2, 5, 4><<<dim3(8, 8, 4), blk, 32768, stream>>>(
        A2T, 8, nullptr, 8, wtRB, 16, rb2_b1, A1, 256, 32, 32, 1, 32);
    inorm_stats<<<1024, blk, 0, stream>>>(A1, stats, 1024);
    inorm_apply<1, false, true><<<4096, blk, 0, stream>>>(A1, stats, nullptr, 10, 8, 1048576, A1T);
    // ---- resblock 2 conv 2 ----
    wtrans<<<2304, blk, 0, stream>>>(rb2_w2, wtRB, 256, 256, 9, 16, 589824);
    mconv<3, false, true, 2, 5, 4><<<dim3(8, 8, 4), blk, 32768, stream>>>(
        A1T, 8, nullptr, 8, wtRB, 16, rb2_b2, A3, 256, 32, 32, 1, 32);
    inorm_stats<<<1024, blk, 0, stream>>>(A3, stats, 1024);
    inorm_apply<2, false, true><<<4096, blk, 0, stream>>>(A3, stats, A2, 10, 8, 1048576, A3T);
    // ---- c1: up2 + 5x5 reflect, 256->128 @64 ----
    wtrans<<<3200, blk, 0, stream>>>(c1_w, wtC1, 128, 256, 25, 8, 819200);
    mconv<5, true, true, 2, 6, 2><<<dim3(32, 4, 4), blk, 57344, stream>>>(
        A3T, 8, nullptr, 8, wtC1, 8, c1_b, R1, 128, 64, 64, 1, 32);
    inorm_stats<<<512, blk, 0, stream>>>(R1, stats, 4096);
    inorm_apply<1, false, true><<<8192, blk, 0, stream>>>(R1, stats, nullptr, 12, 7, 2097152, R1T);
    // ---- off2: concat(R1T, s2T) 3x3 zero-pad -> 27ch ----
    wtrans<<<288, blk, 0, stream>>>(off2_w, wtO2, 27, 256, 9, 2, 73728);
    mconv<3, false, false, 2, 6, 2><<<dim3(32, 1, 4), blk, 40960, stream>>>(
        R1T, 4, s2T, 8, wtO2, 2, off2_b, OM2, 27, 64, 64, 1, 64);
    absmean_partial<<<512, blk, 0, stream>>>(OM2, 4096, part2);
    // ---- deform 2 (MFMA, gather from s2T) ----
    dwtrans<128, 128><<<576, blk, 0, stream>>>(d2_w, wtD2);
    deform_mfma<128, 128, 2><<<dim3(64, 4), blk, 0, stream>>>(
        s2T, OM2, wtD2, d2_b, CP2T, 64, 64, 6);
    // ---- c2: up2(concat(CP2T, R1T)) + 5x5 reflect, 256->64 @128 ----
    wtrans<<<1600, blk, 0, stream>>>(c2_w, wtC2, 64, 256, 25, 4, 409600);
    mconv<5, true, true, 4, 6, 1><<<dim3(256, 1, 4), blk, 49152, stream>>>(
        CP2T, 4, R1T, 8, wtC2, 4, c2_b, R2, 64, 128, 128, 2, 64);
    inorm_stats<<<256, blk, 0, stream>>>(R2, stats, 16384);
    inorm_apply<1, true, true><<<16384, blk, 0, stream>>>(R2, stats, nullptr, 14, 6, 4194304, R2T);
    // ---- off1: concat(R2T (2 chunks), s1T (2 chunks)) -> 27ch ----
    wtrans<<<144, blk, 0, stream>>>(off1_w, wtO1, 27, 128, 9, 2, 36864);
    mconv<3, false, false, 2, 6, 2><<<dim3(128, 1, 4), blk, 40960, stream>>>(
        R2T, 2, s1T, 4, wtO1, 2, off1_b, OM1, 27, 128, 128, 2, 128);
    absmean_partial<<<512, blk, 0, stream>>>(OM1, 16384, part1);
    // ---- deform 1 (MFMA, gather from s1T) ----
    dwtrans<64, 64><<<144, blk, 0, stream>>>(d1_w, wtD1);
    deform_mfma<64, 64, 1><<<dim3(256, 4), blk, 0, stream>>>(
        s1T, OM1, wtD1, d1_b, CP1T, 128, 128, 7);
    // ---- c3: concat(CP1T, R2) 7x7 reflect + tanh -> 3ch, two-stage ----
    conv_part<7><<<dim3(64, 8, 4), blk, 0, stream>>>(CP1T, R2, c3_w, PART, 128, 128);
    conv_reduce<<<768, blk, 0, stream>>>(PART, c3_b, outp, 16384);
    // ---- offset_sum ----
    finalize_k<<<1, blk, 0, stream>>>(part1, part2, outp + 196608);
}

// Round 8
// 677.242 us; speedup vs baseline: 6.6598x; 1.0992x over previous
//
#include <hip/hip_runtime.h>
#include <hip/hip_bf16.h>

#define DEV __device__ __forceinline__

typedef unsigned short u16;
typedef __attribute__((ext_vector_type(8))) short short8;
typedef __attribute__((ext_vector_type(4))) float float4v;

DEV u16 f2bf(float v) {
    __hip_bfloat16 h = __float2bfloat16(v);
    return *reinterpret_cast<u16*>(&h);
}
DEV float bf2f(u16 u) { return __uint_as_float(((unsigned)u) << 16); }

DEV float4v mfma16(short8 a, short8 b, float4v c) {
    return __builtin_amdgcn_mfma_f32_16x16x32_bf16(a, b, c, 0, 0, 0);
}

// ---------------------------------------------------------------------------
// MFMA conv, 2-phase pipelined. Input bf16 chunked [b][ch][px][32ic] (virtual
// concat X0|X1), optional fused 2x upsample, reflect or zero pad.
// Block: 256 thr = 4 waves = NWO oc-groups x NWP px-groups; wave = 16oc x 64px.
// Tile: TW x TH output px (TW*TH = NWP*64). LDS: double-buffered, icg-major
// [icg][t][8ch] -> conflict-free ds_read_b128, compile-time offsets.
// Per-chunk: issue next loads (regs) -> MFMA cur buf -> ds_write next -> bar.
// ACT: 0 = none, 2 = tanh.
// ---------------------------------------------------------------------------
template <int K, bool UP, bool REFLECT, int NWO, int LGTW, int TH, int ACT = 0>
__global__ __launch_bounds__(256) void mconv(
    const u16* __restrict__ X0, int c0ch,
    const u16* __restrict__ X1, int nch,
    const u16* __restrict__ WT, int NOB,
    const float* __restrict__ bias, float* __restrict__ out,
    int OC, int W, int H, int tilesX, int SW)
{
    constexpr int P    = (K - 1) / 2;
    constexpr int K2   = K * K;
    constexpr int NWP  = 4 / NWO;
    constexpr int TW   = 1 << LGTW;
    constexpr int LW   = TW + K - 1;
    constexpr int ROWS = TH + K - 1;
    constexpr int IT   = ROWS * LW;          // 16B slots per icg
    constexpr int ITEMS = IT * 4;            // total 16B slots
    constexpr int CEIL = (ITEMS + 255) / 256;
    constexpr int BUF  = CEIL * 2048;        // u16 per buffer

    extern __shared__ u16 Xs[];
    const int tid = threadIdx.x;
    const int wv = tid >> 6, lane = tid & 63, lm = lane & 15, lg = lane >> 4;
    const int wo = wv / NWP, wp = wv % NWP;
    const int bx = blockIdx.x, b = blockIdx.z;
    const int ty = bx / tilesX, tx = bx - ty * tilesX;
    const int row0 = ty * TH, col0 = tx * TW;
    const int SH  = UP ? (H >> 1) : H;
    const int HWs = SW * SH;
    const int ob  = blockIdx.y * NWO + wo;

    // ---- per-item source offsets (u16 units in channel plane), ch-invariant
    int offr[CEIL];
#pragma unroll
    for (int i = 0; i < CEIL; ++i) {
        int q = i * 256 + tid;
        bool tail = q >= ITEMS;
        if (tail) q = ITEMS - 1;
        int icg = q / IT;
        int t   = q - icg * IT;
        int tr  = t / LW, tc = t - tr * LW;
        int gy = row0 - P + tr, gx = col0 - P + tc;
        if (REFLECT) {
            gy = gy < 0 ? -gy : (gy >= H ? 2 * H - 2 - gy : gy);
            gx = gx < 0 ? -gx : (gx >= W ? 2 * W - 2 - gx : gx);
            int sy = UP ? (gy >> 1) : gy, sx = UP ? (gx >> 1) : gx;
            offr[i] = (sy * SW + sx) * 32 + icg * 8;
        } else {
            bool ok = (gy >= 0) & (gy < H) & (gx >= 0) & (gx < W) & !tail;
            int sy = UP ? (gy >> 1) : gy, sx = UP ? (gx >> 1) : gx;
            offr[i] = ok ? (sy * SW + sx) * 32 + icg * 8 : -1;
        }
    }

    // ---- per-nf bases: LDS read offset (u16) and output pixel
    int rb16[4], opx[4];
#pragma unroll
    for (int nf = 0; nf < 4; ++nf) {
        int pt = wp * 64 + nf * 16 + lm;
        int ro = pt >> LGTW, co = pt & (TW - 1);
        rb16[nf] = (lg * IT + ro * LW + co) * 8;
        opx[nf]  = (row0 + ro) * W + col0 + co;
    }

    float4v acc[4];
#pragma unroll
    for (int n = 0; n < 4; ++n) acc[n] = (float4v){0.f, 0.f, 0.f, 0.f};

    auto planeptr = [&](int ch) -> const u16* {
        return (ch < c0ch)
            ? X0 + (size_t)(b * c0ch + ch) * HWs * 32
            : X1 + (size_t)(b * (nch - c0ch) + (ch - c0ch)) * HWs * 32;
    };
    const uint4 UZ = {0u, 0u, 0u, 0u};
    uint4 rv[CEIL];

    // ---- prologue: chunk 0 ----
    {
        const u16* src = planeptr(0);
#pragma unroll
        for (int i = 0; i < CEIL; ++i)
            rv[i] = (offr[i] >= 0) ? *(const uint4*)(src + offr[i]) : UZ;
#pragma unroll
        for (int i = 0; i < CEIL; ++i)
            *(uint4*)(Xs + (size_t)(i * 256 + tid) * 8) = rv[i];
    }
    __syncthreads();

    int cur = 0;
    for (int ch = 0; ch < nch; ++ch) {
        // issue next-chunk loads (hide under MFMA phase)
        if (ch + 1 < nch) {
            const u16* src = planeptr(ch + 1);
#pragma unroll
            for (int i = 0; i < CEIL; ++i)
                rv[i] = (offr[i] >= 0) ? *(const uint4*)(src + offr[i]) : UZ;
        }
        // MFMA on current buffer
        const u16* base = Xs + cur * BUF;
        const u16* wch  = WT + ((size_t)ch * NOB + ob) * K2 * 512 + lane * 8;
#pragma unroll
        for (int ky = 0; ky < K; ++ky) {
#pragma unroll
            for (int kx = 0; kx < K; ++kx) {
                short8 Af = *(const short8*)(wch + (size_t)(ky * K + kx) * 512);
#pragma unroll
                for (int nf = 0; nf < 4; ++nf) {
                    short8 Bf = *(const short8*)(base + rb16[nf] + (ky * LW + kx) * 8);
                    acc[nf] = mfma16(Af, Bf, acc[nf]);
                }
            }
        }
        // write next buffer, one barrier per chunk
        if (ch + 1 < nch) {
            u16* dst = Xs + (cur ^ 1) * BUF;
#pragma unroll
            for (int i = 0; i < CEIL; ++i)
                *(uint4*)(dst + (size_t)(i * 256 + tid) * 8) = rv[i];
            __syncthreads();
            cur ^= 1;
        }
    }

    // ---- epilogue ----
    const size_t HWo = (size_t)H * W;
    int oc0 = ob * 16 + lg * 4;
#pragma unroll
    for (int nf = 0; nf < 4; ++nf) {
#pragma unroll
        for (int r = 0; r < 4; ++r) {
            int oc = oc0 + r;
            if (oc < OC) {
                float v = acc[nf][r] + bias[oc];
                if (ACT == 2) v = tanhf(v);
                out[(size_t)(b * OC + oc) * HWo + opx[nf]] = v;
            }
        }
    }
}

// ---------------------------------------------------------------------------
// Weight pack: w[OC][IC][K2] fp32 -> wt[ch][ob][tap][lane][8] bf16 (A-frag).
// ---------------------------------------------------------------------------
__global__ __launch_bounds__(256) void wtrans(
    const float* __restrict__ w, u16* __restrict__ wt,
    int OC, int IC, int K2, int NOB, int total)
{
    int i = blockIdx.x * 256 + threadIdx.x;
    if (i >= total) return;
    int e = i & 7;
    int l = (i >> 3) & 63;
    int rest = i >> 9;
    int tap = rest % K2;
    rest /= K2;
    int ob = rest % NOB;
    int ch = rest / NOB;
    int oc = ob * 16 + (l & 15);
    if (oc >= OC) oc = OC - 1;
    int ic = ch * 32 + (l >> 4) * 8 + e;
    wt[i] = f2bf(w[((size_t)oc * IC + ic) * K2 + tap]);
}

// Deform weight pack: w[O][C][9] fp32 -> dwt[k][ob][cc][lane][8] bf16.
template <int C, int O>
__global__ __launch_bounds__(256) void dwtrans(
    const float* __restrict__ w, u16* __restrict__ dwt)
{
    constexpr int NOB = O / 16, NCC = C / 32;
    constexpr int total = 9 * NOB * NCC * 512;
    int i = blockIdx.x * 256 + threadIdx.x;
    if (i >= total) return;
    int e = i & 7;
    int l = (i >> 3) & 63;
    int rest = i >> 9;
    int cc = rest % NCC;
    rest /= NCC;
    int ob = rest % NOB;
    int k  = rest / NOB;
    int oc = ob * 16 + (l & 15);
    int ic = cc * 32 + (l >> 4) * 8 + e;
    dwt[i] = f2bf(w[((size_t)oc * C + ic) * 9 + k]);
}

// ---------------------------------------------------------------------------
// fp32 NCHW -> bf16 [b][chunk][px][32ic]
// ---------------------------------------------------------------------------
__global__ __launch_bounds__(256) void act2t(
    const float* __restrict__ in, u16* __restrict__ out,
    int lgHW, int lgC, size_t total)
{
    size_t i = (size_t)blockIdx.x * 256 + threadIdx.x;
    if (i >= total) return;
    int px = (int)(i & (((size_t)1 << lgHW) - 1));
    int bc = (int)(i >> lgHW);
    int c = bc & ((1 << lgC) - 1);
    int b = bc >> lgC;
    size_t o = ((((size_t)(b << (lgC - 5)) + (c >> 5)) << lgHW) + px) * 32 + (c & 31);
    out[o] = f2bf(in[i]);
}

// ---------------------- instance norm -------------------------------------
__global__ __launch_bounds__(256) void inorm_stats(
    const float* __restrict__ x, float* __restrict__ stats, int HW)
{
    __shared__ float sh[8];
    const int bc = blockIdx.x;
    const float* p = x + (size_t)bc * HW;
    float s = 0.f, ss = 0.f;
    for (int i = threadIdx.x; i < HW; i += 256) {
        float v = p[i];
        s += v; ss = fmaf(v, v, ss);
    }
#pragma unroll
    for (int o = 32; o; o >>= 1) { s += __shfl_down(s, o); ss += __shfl_down(ss, o); }
    if ((threadIdx.x & 63) == 0) {
        sh[(threadIdx.x >> 6) * 2] = s;
        sh[(threadIdx.x >> 6) * 2 + 1] = ss;
    }
    __syncthreads();
    if (threadIdx.x == 0) {
        s  = sh[0] + sh[2] + sh[4] + sh[6];
        ss = sh[1] + sh[3] + sh[5] + sh[7];
        float m   = s / HW;
        float var = ss / HW - m * m;
        stats[2 * bc]     = m;
        stats[2 * bc + 1] = rsqrtf(var + 1e-5f);
    }
}

template <int MODE, bool WF32, bool WT16>
__global__ __launch_bounds__(256) void inorm_apply(
    float* __restrict__ x, const float* __restrict__ stats,
    const float* __restrict__ res, int lgHW, int lgC, size_t total,
    u16* __restrict__ tout)
{
    size_t i = (size_t)blockIdx.x * 256 + threadIdx.x;
    if (i >= total) return;
    int bc = (int)(i >> lgHW);
    float m = stats[2 * bc], r = stats[2 * bc + 1];
    float v = (x[i] - m) * r;
    if (MODE == 1) v = fmaxf(v, 0.f);
    if (MODE == 2) v += res[i];
    if (WF32) x[i] = v;
    if (WT16) {
        int px = (int)(i & (((size_t)1 << lgHW) - 1));
        int c = bc & ((1 << lgC) - 1);
        int b = bc >> lgC;
        size_t o = ((((size_t)(b << (lgC - 5)) + (c >> 5)) << lgHW) + px) * 32 + (c & 31);
        tout[o] = f2bf(v);
    }
}

// ---------------------------------------------------------------------------
// MFMA deformable conv.
// ---------------------------------------------------------------------------
template <int C, int O, int MF>
__global__ __launch_bounds__(256) void deform_mfma(
    const u16* __restrict__ featT, const float* __restrict__ om,
    const u16* __restrict__ dwt, const float* __restrict__ bias,
    u16* __restrict__ outT, int H, int W, int lgW)
{
    constexpr int NOB = O / 16, NCC = C / 32;
    constexpr int NT = 576;
    constexpr int CPT = C / 4;
    const int HW = H * W;
    const int b  = blockIdx.y;
    const int p0 = blockIdx.x * 64;
    const int tid = threadIdx.x;
    const int wv = tid >> 6, lane = tid & 63, lm = lane & 15, lg = lane >> 4;

    __shared__ int   sO[4][NT];
    __shared__ float sW[4][NT];
    __shared__ u16   val[64 * C];

    for (int t = tid; t < NT; t += 256) {
        int px = t & 63, k = t >> 6;
        int p  = p0 + px;
        int hh = p >> lgW, ww = p & (W - 1);
        float dy = om[((size_t)b * 27 + k) * HW + p];
        float dx = om[((size_t)b * 27 + 9 + k) * HW + p];
        float mk = 1.f / (1.f + __expf(-om[((size_t)b * 27 + 18 + k) * HW + p]));
        float py  = (float)(hh + k / 3 - 1) + dy;
        float pxf = (float)(ww + k % 3 - 1) + dx;
        float y0f = floorf(py), x0f = floorf(pxf);
        int y0 = (int)y0f, x0 = (int)x0f;
        float wy = py - y0f, wx = pxf - x0f;
        float vy0 = ((unsigned)y0       < (unsigned)H) ? 1.f : 0.f;
        float vy1 = ((unsigned)(y0 + 1) < (unsigned)H) ? 1.f : 0.f;
        float vx0 = ((unsigned)x0       < (unsigned)W) ? 1.f : 0.f;
        float vx1 = ((unsigned)(x0 + 1) < (unsigned)W) ? 1.f : 0.f;
        int y0c = min(max(y0, 0), H - 1), y1c = min(max(y0 + 1, 0), H - 1);
        int x0c = min(max(x0, 0), W - 1), x1c = min(max(x0 + 1, 0), W - 1);
        sO[0][t] = y0c * W + x0c;  sO[1][t] = y0c * W + x1c;
        sO[2][t] = y1c * W + x0c;  sO[3][t] = y1c * W + x1c;
        sW[0][t] = (1.f - wy) * (1.f - wx) * vy0 * vx0 * mk;
        sW[1][t] = (1.f - wy) * wx         * vy0 * vx1 * mk;
        sW[2][t] = wy         * (1.f - wx) * vy1 * vx0 * mk;
        sW[3][t] = wy         * wx         * vy1 * vx1 * mk;
    }
    __syncthreads();

    float4v acc[MF][4];
#pragma unroll
    for (int m = 0; m < MF; ++m)
#pragma unroll
        for (int n = 0; n < 4; ++n) acc[m][n] = (float4v){0.f, 0.f, 0.f, 0.f};

    const int gpx = tid >> 2, gc0 = (tid & 3) * CPT;

    for (int k = 0; k < 9; ++k) {
        if (k) __syncthreads();
        {
            int t = k * 64 + gpx;
            int o0 = sO[0][t], o1 = sO[1][t], o2 = sO[2][t], o3 = sO[3][t];
            float w0 = sW[0][t], w1 = sW[1][t], w2 = sW[2][t], w3 = sW[3][t];
#pragma unroll
            for (int c8 = 0; c8 < CPT / 8; ++c8) {
                int c = gc0 + c8 * 8;
                const u16* base = featT + ((size_t)(b * NCC + (c >> 5)) * HW) * 32 + (c & 31);
                uint4 r0 = *(const uint4*)(base + (size_t)o0 * 32);
                uint4 r1 = *(const uint4*)(base + (size_t)o1 * 32);
                uint4 r2 = *(const uint4*)(base + (size_t)o2 * 32);
                uint4 r3 = *(const uint4*)(base + (size_t)o3 * 32);
                const u16* p0_ = (const u16*)&r0;
                const u16* p1_ = (const u16*)&r1;
                const u16* p2_ = (const u16*)&r2;
                const u16* p3_ = (const u16*)&r3;
                u16 outv[8];
#pragma unroll
                for (int j = 0; j < 8; ++j) {
                    float s = w0 * bf2f(p0_[j]) + w1 * bf2f(p1_[j])
                            + w2 * bf2f(p2_[j]) + w3 * bf2f(p3_[j]);
                    outv[j] = f2bf(s);
                }
                int csw = c ^ ((gpx & 7) << 3);
                *(uint4*)(val + gpx * C + csw) = *(uint4*)outv;
            }
        }
        __syncthreads();
        const u16* wk = dwt + (size_t)k * NOB * NCC * 512;
#pragma unroll
        for (int m = 0; m < MF; ++m) {
            int ob = wv * MF + m;
#pragma unroll
            for (int cc = 0; cc < NCC; ++cc) {
                short8 Af = *(const short8*)(wk + ((size_t)ob * NCC + cc) * 512 + lane * 8);
#pragma unroll
                for (int nf = 0; nf < 4; ++nf) {
                    int row = nf * 16 + lm;
                    int csw = (cc * 32 + lg * 8) ^ ((row & 7) << 3);
                    short8 Bf = *(const short8*)(val + row * C + csw);
                    acc[m][nf] = mfma16(Af, Bf, acc[m][nf]);
                }
            }
        }
    }

#pragma unroll
    for (int m = 0; m < MF; ++m) {
        int oc0 = (wv * MF + m) * 16 + lg * 4;
#pragma unroll
        for (int nf = 0; nf < 4; ++nf) {
            int p = p0 + nf * 16 + lm;
#pragma unroll
            for (int r = 0; r < 4; ++r) {
                int oc = oc0 + r;
                outT[((size_t)(b * (O / 32) + (oc >> 5)) * HW + p) * 32 + (oc & 31)]
                    = f2bf(acc[m][nf][r] + bias[oc]);
            }
        }
    }
}

// ---------------------- offset |mean| reductions --------------------------
__global__ __launch_bounds__(256) void absmean_partial(
    const float* __restrict__ om, int HW, float* __restrict__ partial)
{
    const int n18 = 18 * HW;
    const long long total = 4LL * n18;
    float s = 0.f;
    for (long long i = (long long)blockIdx.x * 256 + threadIdx.x; i < total;
         i += (long long)gridDim.x * 256) {
        int b = (int)(i / n18);
        int r = (int)(i % n18);
        s += fabsf(om[(size_t)b * 27 * HW + r]);
    }
    __shared__ float sh[4];
#pragma unroll
    for (int o = 32; o; o >>= 1) s += __shfl_down(s, o);
    if ((threadIdx.x & 63) == 0) sh[threadIdx.x >> 6] = s;
    __syncthreads();
    if (threadIdx.x == 0) partial[blockIdx.x] = sh[0] + sh[1] + sh[2] + sh[3];
}

__global__ __launch_bounds__(256) void finalize_k(
    const float* __restrict__ p1, const float* __restrict__ p2,
    float* __restrict__ outScalar)
{
    __shared__ float sh[8];
    float a = p1[threadIdx.x] + p1[threadIdx.x + 256];
    float b = p2[threadIdx.x] + p2[threadIdx.x + 256];
#pragma unroll
    for (int o = 32; o; o >>= 1) { a += __shfl_down(a, o); b += __shfl_down(b, o); }
    if ((threadIdx.x & 63) == 0) {
        sh[(threadIdx.x >> 6) * 2]     = a;
        sh[(threadIdx.x >> 6) * 2 + 1] = b;
    }
    __syncthreads();
    if (threadIdx.x == 0) {
        a = sh[0] + sh[2] + sh[4] + sh[6];
        b = sh[1] + sh[3] + sh[5] + sh[7];
        *outScalar = 0.5f * (a / (4.f * 18.f * 16384.f) + b / (4.f * 18.f * 4096.f));
    }
}

// ---------------------------------------------------------------------------
extern "C" void kernel_launch(void* const* d_in, const int* in_sizes, int n_in,
                              void* d_out, int out_size, void* d_ws, size_t ws_size,
                              hipStream_t stream)
{
    const float* x      = (const float*)d_in[0];
    const float* skip1  = (const float*)d_in[1];
    const float* skip2  = (const float*)d_in[2];
    const float* rb1_w1 = (const float*)d_in[3];
    const float* rb1_b1 = (const float*)d_in[4];
    const float* rb1_w2 = (const float*)d_in[5];
    const float* rb1_b2 = (const float*)d_in[6];
    const float* rb2_w1 = (const float*)d_in[7];
    const float* rb2_b1 = (const float*)d_in[8];
    const float* rb2_w2 = (const float*)d_in[9];
    const float* rb2_b2 = (const float*)d_in[10];
    const float* c1_w   = (const float*)d_in[11];
    const float* c1_b   = (const float*)d_in[12];
    const float* c2_w   = (const float*)d_in[13];
    const float* c2_b   = (const float*)d_in[14];
    const float* c3_w   = (const float*)d_in[15];
    const float* c3_b   = (const float*)d_in[16];
    const float* off2_w = (const float*)d_in[17];
    const float* off2_b = (const float*)d_in[18];
    const float* d2_w   = (const float*)d_in[19];
    const float* d2_b   = (const float*)d_in[20];
    const float* off1_w = (const float*)d_in[21];
    const float* off1_b = (const float*)d_in[22];
    const float* d1_w   = (const float*)d_in[23];
    const float* d1_b   = (const float*)d_in[24];

    float* ws    = (float*)d_ws;
    float* stats = ws;
    float* part2 = ws + 2048;
    float* part1 = ws + 2560;

    // ---- weight pack arenas (words) ----
    u16* wtRB = (u16*)(ws + 4096);
    u16* wtC1 = (u16*)(ws + 299008);
    u16* wtC2 = (u16*)(ws + 708608);
    u16* wtO2 = (u16*)(ws + 913408);
    u16* wtO1 = (u16*)(ws + 950272);
    // ---- Z1: R2 fp32 (4M w) with early overlays ----
    float* R2  = ws + 968704;                  // [c2 -> inorm_apply]
    u16*  xT   = (u16*)(ws + 968704);
    u16*  A1T  = xT;
    u16*  A2T  = (u16*)(ws + 968704 + 524288);
    u16*  A3T  = A2T;
    float* A1  = ws + 968704 + 1048576;
    float* A2  = ws + 968704 + 2097152;
    float* A3  = ws + 968704 + 3145728;
    float* OM2 = ws + 968704;                  // [off2 -> deform2]
    u16*  CP1T = (u16*)(ws + 968704);          // 2M u16 [deform1 -> c3] (R2 dead)
    u16*  wtC3 = (u16*)(ws + 3065856);         // 100352 u16 [-> c3] (A2 zone, dead)
    // ---- Z2: s1T ----
    u16*  s1T  = (u16*)(ws + 5163008);         // [-> deform1]
    // ---- Z3: R1 / wtD2+CP2T / R2T overlays ----
    float* R1  = ws + 7260160;                 // [c1 -> apply]
    u16*  wtD2 = (u16*)(ws + 7260160);         // [-> deform2]
    u16*  CP2T = (u16*)(ws + 7333888);         // [deform2 -> c2]
    u16*  R2T  = (u16*)(ws + 7260160);         // [apply(after c2) -> off1, c3]
    // ---- Z4: R1T then OM1 ----
    u16*  R1T  = (u16*)(ws + 9357312);         // [-> c2]
    float* OM1 = ws + 9357312;                 // [off1 -> deform1]
    // ---- Z5: s2T; tail holds wtD1 ----
    u16*  s2T  = (u16*)(ws + 10405888);        // [-> deform2]
    u16*  wtD1 = (u16*)(ws + 11126784);        // [-> deform1]

    float* outp = (float*)d_out;
    dim3 blk(256);

    // ---- input transforms ----
    act2t<<<4096, blk, 0, stream>>>(x, xT, 10, 8, 1048576);
    act2t<<<16384, blk, 0, stream>>>(skip1, s1T, 14, 6, 4194304);
    act2t<<<8192, blk, 0, stream>>>(skip2, s2T, 12, 7, 2097152);

    // ---- resblock 1 conv 1 ----
    wtrans<<<2304, blk, 0, stream>>>(rb1_w1, wtRB, 256, 256, 9, 16, 589824);
    mconv<3, false, true, 2, 5, 4><<<dim3(8, 8, 4), blk, 32768, stream>>>(
        xT, 8, nullptr, 8, wtRB, 16, rb1_b1, A1, 256, 32, 32, 1, 32);
    inorm_stats<<<1024, blk, 0, stream>>>(A1, stats, 1024);
    inorm_apply<1, false, true><<<4096, blk, 0, stream>>>(A1, stats, nullptr, 10, 8, 1048576, A1T);
    // ---- resblock 1 conv 2 ----
    wtrans<<<2304, blk, 0, stream>>>(rb1_w2, wtRB, 256, 256, 9, 16, 589824);
    mconv<3, false, true, 2, 5, 4><<<dim3(8, 8, 4), blk, 32768, stream>>>(
        A1T, 8, nullptr, 8, wtRB, 16, rb1_b2, A2, 256, 32, 32, 1, 32);
    inorm_stats<<<1024, blk, 0, stream>>>(A2, stats, 1024);
    inorm_apply<2, true, true><<<4096, blk, 0, stream>>>(A2, stats, x, 10, 8, 1048576, A2T);
    // ---- resblock 2 conv 1 ----
    wtrans<<<2304, blk, 0, stream>>>(rb2_w1, wtRB, 256, 256, 9, 16, 589824);
    mconv<3, false, true, 2, 5, 4><<<dim3(8, 8, 4), blk, 32768, stream>>>(
        A2T, 8, nullptr, 8, wtRB, 16, rb2_b1, A1, 256, 32, 32, 1, 32);
    inorm_stats<<<1024, blk, 0, stream>>>(A1, stats, 1024);
    inorm_apply<1, false, true><<<4096, blk, 0, stream>>>(A1, stats, nullptr, 10, 8, 1048576, A1T);
    // ---- resblock 2 conv 2 ----
    wtrans<<<2304, blk, 0, stream>>>(rb2_w2, wtRB, 256, 256, 9, 16, 589824);
    mconv<3, false, true, 2, 5, 4><<<dim3(8, 8, 4), blk, 32768, stream>>>(
        A1T, 8, nullptr, 8, wtRB, 16, rb2_b2, A3, 256, 32, 32, 1, 32);
    inorm_stats<<<1024, blk, 0, stream>>>(A3, stats, 1024);
    inorm_apply<2, false, true><<<4096, blk, 0, stream>>>(A3, stats, A2, 10, 8, 1048576, A3T);
    // ---- c1: up2 + 5x5 reflect, 256->128 @64 ----
    wtrans<<<3200, blk, 0, stream>>>(c1_w, wtC1, 128, 256, 25, 8, 819200);
    mconv<5, true, true, 2, 6, 2><<<dim3(32, 4, 4), blk, 57344, stream>>>(
        A3T, 8, nullptr, 8, wtC1, 8, c1_b, R1, 128, 64, 64, 1, 32);
    inorm_stats<<<512, blk, 0, stream>>>(R1, stats, 4096);
    inorm_apply<1, false, true><<<8192, blk, 0, stream>>>(R1, stats, nullptr, 12, 7, 2097152, R1T);
    // ---- off2: concat(R1T, s2T) 3x3 zero-pad -> 27ch ----
    wtrans<<<288, blk, 0, stream>>>(off2_w, wtO2, 27, 256, 9, 2, 73728);
    mconv<3, false, false, 2, 6, 2><<<dim3(32, 1, 4), blk, 40960, stream>>>(
        R1T, 4, s2T, 8, wtO2, 2, off2_b, OM2, 27, 64, 64, 1, 64);
    absmean_partial<<<512, blk, 0, stream>>>(OM2, 4096, part2);
    // ---- deform 2 (MFMA, gather from s2T) ----
    dwtrans<128, 128><<<576, blk, 0, stream>>>(d2_w, wtD2);
    deform_mfma<128, 128, 2><<<dim3(64, 4), blk, 0, stream>>>(
        s2T, OM2, wtD2, d2_b, CP2T, 64, 64, 6);
    // ---- c2: up2(concat(CP2T, R1T)) + 5x5 reflect, 256->64 @128 ----
    wtrans<<<1600, blk, 0, stream>>>(c2_w, wtC2, 64, 256, 25, 4, 409600);
    mconv<5, true, true, 4, 6, 1><<<dim3(256, 1, 4), blk, 49152, stream>>>(
        CP2T, 4, R1T, 8, wtC2, 4, c2_b, R2, 64, 128, 128, 2, 64);
    inorm_stats<<<256, blk, 0, stream>>>(R2, stats, 16384);
    // bf16 R2T only; fp32 R2 becomes dead after this (frees Z1 for CP1T)
    inorm_apply<1, false, true><<<16384, blk, 0, stream>>>(R2, stats, nullptr, 14, 6, 4194304, R2T);
    // ---- off1: concat(R2T (2 chunks), s1T (2 chunks)) -> 27ch ----
    wtrans<<<144, blk, 0, stream>>>(off1_w, wtO1, 27, 128, 9, 2, 36864);
    mconv<3, false, false, 2, 6, 2><<<dim3(128, 1, 4), blk, 40960, stream>>>(
        R2T, 2, s1T, 4, wtO1, 2, off1_b, OM1, 27, 128, 128, 2, 128);
    absmean_partial<<<512, blk, 0, stream>>>(OM1, 16384, part1);
    // ---- deform 1 (MFMA, gather from s1T) -> CP1T in freed Z1 ----
    dwtrans<64, 64><<<144, blk, 0, stream>>>(d1_w, wtD1);
    deform_mfma<64, 64, 1><<<dim3(256, 4), blk, 0, stream>>>(
        s1T, OM1, wtD1, d1_b, CP1T, 128, 128, 7);
    // ---- c3: concat(CP1T, R2T) 7x7 reflect + tanh -> 3ch via MFMA ----
    wtrans<<<392, blk, 0, stream>>>(c3_w, wtC3, 3, 128, 49, 1, 100352);
    mconv<7, false, true, 1, 4, 16, 2><<<dim3(64, 1, 4), blk, 65536, stream>>>(
        CP1T, 2, R2T, 4, wtC3, 1, c3_b, outp, 3, 128, 128, 8, 128);
    // ---- offset_sum ----
    finalize_k<<<1, blk, 0, stream>>>(part1, part2, outp + 196608);
}

// Round 9
// 663.220 us; speedup vs baseline: 6.8006x; 1.0211x over previous
//
#include <hip/hip_runtime.h>
#include <hip/hip_bf16.h>

#define DEV __device__ __forceinline__

typedef unsigned short u16;
typedef __attribute__((ext_vector_type(8))) short short8;
typedef __attribute__((ext_vector_type(4))) float float4v;

DEV u16 f2bf(float v) {
    __hip_bfloat16 h = __float2bfloat16(v);
    return *reinterpret_cast<u16*>(&h);
}
DEV float bf2f(u16 u) { return __uint_as_float(((unsigned)u) << 16); }

DEV float4v mfma16(short8 a, short8 b, float4v c) {
    return __builtin_amdgcn_mfma_f32_16x16x32_bf16(a, b, c, 0, 0, 0);
}

// ---------------------------------------------------------------------------
// MFMA conv, 2-phase pipelined. Input bf16 chunked [b][ch][px][32ic] (virtual
// concat X0|X1), optional fused 2x upsample, reflect or zero pad.
// Block: 256 thr = 4 waves = NWO oc-groups x NWP px-groups; wave = 16oc x 64px.
// Tile: TW x TH output px (TW*TH = NWP*64). LDS: double-buffered, icg-major
// [icg][t][8ch] -> conflict-free ds_read_b128, compile-time offsets.
// Per-chunk: issue next loads (regs) -> MFMA cur buf -> ds_write next -> bar.
// ACT: 0 = none, 2 = tanh.
// __launch_bounds__(256,3): VGPR cap ~170 — the default heuristic gave the
// K=7/CEIL=8 instantiation 44 VGPRs and spilled rv[] to scratch (148 MB of
// HBM write traffic, round-8 profile).
// ---------------------------------------------------------------------------
template <int K, bool UP, bool REFLECT, int NWO, int LGTW, int TH, int ACT = 0>
__global__ __launch_bounds__(256, 3) void mconv(
    const u16* __restrict__ X0, int c0ch,
    const u16* __restrict__ X1, int nch,
    const u16* __restrict__ WT, int NOB,
    const float* __restrict__ bias, float* __restrict__ out,
    int OC, int W, int H, int tilesX, int SW)
{
    constexpr int P    = (K - 1) / 2;
    constexpr int K2   = K * K;
    constexpr int NWP  = 4 / NWO;
    constexpr int TW   = 1 << LGTW;
    constexpr int LW   = TW + K - 1;
    constexpr int ROWS = TH + K - 1;
    constexpr int IT   = ROWS * LW;          // 16B slots per icg
    constexpr int ITEMS = IT * 4;            // total 16B slots
    constexpr int CEIL = (ITEMS + 255) / 256;
    constexpr int BUF  = CEIL * 2048;        // u16 per buffer

    extern __shared__ u16 Xs[];
    const int tid = threadIdx.x;
    const int wv = tid >> 6, lane = tid & 63, lm = lane & 15, lg = lane >> 4;
    const int wo = wv / NWP, wp = wv % NWP;
    const int bx = blockIdx.x, b = blockIdx.z;
    const int ty = bx / tilesX, tx = bx - ty * tilesX;
    const int row0 = ty * TH, col0 = tx * TW;
    const int SH  = UP ? (H >> 1) : H;
    const int HWs = SW * SH;
    const int ob  = blockIdx.y * NWO + wo;

    // ---- per-item source offsets (u16 units in channel plane), ch-invariant
    int offr[CEIL];
#pragma unroll
    for (int i = 0; i < CEIL; ++i) {
        int q = i * 256 + tid;
        bool tail = q >= ITEMS;
        if (tail) q = ITEMS - 1;
        int icg = q / IT;
        int t   = q - icg * IT;
        int tr  = t / LW, tc = t - tr * LW;
        int gy = row0 - P + tr, gx = col0 - P + tc;
        if (REFLECT) {
            gy = gy < 0 ? -gy : (gy >= H ? 2 * H - 2 - gy : gy);
            gx = gx < 0 ? -gx : (gx >= W ? 2 * W - 2 - gx : gx);
            int sy = UP ? (gy >> 1) : gy, sx = UP ? (gx >> 1) : gx;
            offr[i] = (sy * SW + sx) * 32 + icg * 8;
        } else {
            bool ok = (gy >= 0) & (gy < H) & (gx >= 0) & (gx < W) & !tail;
            int sy = UP ? (gy >> 1) : gy, sx = UP ? (gx >> 1) : gx;
            offr[i] = ok ? (sy * SW + sx) * 32 + icg * 8 : -1;
        }
    }

    // ---- per-nf bases: LDS read offset (u16) and output pixel
    int rb16[4], opx[4];
#pragma unroll
    for (int nf = 0; nf < 4; ++nf) {
        int pt = wp * 64 + nf * 16 + lm;
        int ro = pt >> LGTW, co = pt & (TW - 1);
        rb16[nf] = (lg * IT + ro * LW + co) * 8;
        opx[nf]  = (row0 + ro) * W + col0 + co;
    }

    float4v acc[4];
#pragma unroll
    for (int n = 0; n < 4; ++n) acc[n] = (float4v){0.f, 0.f, 0.f, 0.f};

    auto planeptr = [&](int ch) -> const u16* {
        return (ch < c0ch)
            ? X0 + (size_t)(b * c0ch + ch) * HWs * 32
            : X1 + (size_t)(b * (nch - c0ch) + (ch - c0ch)) * HWs * 32;
    };
    const uint4 UZ = {0u, 0u, 0u, 0u};
    uint4 rv[CEIL];

    // ---- prologue: chunk 0 ----
    {
        const u16* src = planeptr(0);
#pragma unroll
        for (int i = 0; i < CEIL; ++i)
            rv[i] = (offr[i] >= 0) ? *(const uint4*)(src + offr[i]) : UZ;
#pragma unroll
        for (int i = 0; i < CEIL; ++i)
            *(uint4*)(Xs + (size_t)(i * 256 + tid) * 8) = rv[i];
    }
    __syncthreads();

    int cur = 0;
    for (int ch = 0; ch < nch; ++ch) {
        // issue next-chunk loads (hide under MFMA phase)
        if (ch + 1 < nch) {
            const u16* src = planeptr(ch + 1);
#pragma unroll
            for (int i = 0; i < CEIL; ++i)
                rv[i] = (offr[i] >= 0) ? *(const uint4*)(src + offr[i]) : UZ;
        }
        // MFMA on current buffer
        const u16* base = Xs + cur * BUF;
        const u16* wch  = WT + ((size_t)ch * NOB + ob) * K2 * 512 + lane * 8;
#pragma unroll
        for (int ky = 0; ky < K; ++ky) {
#pragma unroll
            for (int kx = 0; kx < K; ++kx) {
                short8 Af = *(const short8*)(wch + (size_t)(ky * K + kx) * 512);
#pragma unroll
                for (int nf = 0; nf < 4; ++nf) {
                    short8 Bf = *(const short8*)(base + rb16[nf] + (ky * LW + kx) * 8);
                    acc[nf] = mfma16(Af, Bf, acc[nf]);
                }
            }
        }
        // write next buffer, one barrier per chunk
        if (ch + 1 < nch) {
            u16* dst = Xs + (cur ^ 1) * BUF;
#pragma unroll
            for (int i = 0; i < CEIL; ++i)
                *(uint4*)(dst + (size_t)(i * 256 + tid) * 8) = rv[i];
            __syncthreads();
            cur ^= 1;
        }
    }

    // ---- epilogue ----
    const size_t HWo = (size_t)H * W;
    int oc0 = ob * 16 + lg * 4;
#pragma unroll
    for (int nf = 0; nf < 4; ++nf) {
#pragma unroll
        for (int r = 0; r < 4; ++r) {
            int oc = oc0 + r;
            if (oc < OC) {
                float v = acc[nf][r] + bias[oc];
                if (ACT == 2) v = tanhf(v);
                out[(size_t)(b * OC + oc) * HWo + opx[nf]] = v;
            }
        }
    }
}

// ---------------------------------------------------------------------------
// Weight pack: w[OC][IC][K2] fp32 -> wt[ch][ob][tap][lane][8] bf16 (A-frag).
// ---------------------------------------------------------------------------
__global__ __launch_bounds__(256) void wtrans(
    const float* __restrict__ w, u16* __restrict__ wt,
    int OC, int IC, int K2, int NOB, int total)
{
    int i = blockIdx.x * 256 + threadIdx.x;
    if (i >= total) return;
    int e = i & 7;
    int l = (i >> 3) & 63;
    int rest = i >> 9;
    int tap = rest % K2;
    rest /= K2;
    int ob = rest % NOB;
    int ch = rest / NOB;
    int oc = ob * 16 + (l & 15);
    if (oc >= OC) oc = OC - 1;
    int ic = ch * 32 + (l >> 4) * 8 + e;
    wt[i] = f2bf(w[((size_t)oc * IC + ic) * K2 + tap]);
}

// Deform weight pack: w[O][C][9] fp32 -> dwt[k][ob][cc][lane][8] bf16.
template <int C, int O>
__global__ __launch_bounds__(256) void dwtrans(
    const float* __restrict__ w, u16* __restrict__ dwt)
{
    constexpr int NOB = O / 16, NCC = C / 32;
    constexpr int total = 9 * NOB * NCC * 512;
    int i = blockIdx.x * 256 + threadIdx.x;
    if (i >= total) return;
    int e = i & 7;
    int l = (i >> 3) & 63;
    int rest = i >> 9;
    int cc = rest % NCC;
    rest /= NCC;
    int ob = rest % NOB;
    int k  = rest / NOB;
    int oc = ob * 16 + (l & 15);
    int ic = cc * 32 + (l >> 4) * 8 + e;
    dwt[i] = f2bf(w[((size_t)oc * C + ic) * 9 + k]);
}

// ---------------------------------------------------------------------------
// fp32 NCHW -> bf16 [b][chunk][px][32ic]
// ---------------------------------------------------------------------------
__global__ __launch_bounds__(256) void act2t(
    const float* __restrict__ in, u16* __restrict__ out,
    int lgHW, int lgC, size_t total)
{
    size_t i = (size_t)blockIdx.x * 256 + threadIdx.x;
    if (i >= total) return;
    int px = (int)(i & (((size_t)1 << lgHW) - 1));
    int bc = (int)(i >> lgHW);
    int c = bc & ((1 << lgC) - 1);
    int b = bc >> lgC;
    size_t o = ((((size_t)(b << (lgC - 5)) + (c >> 5)) << lgHW) + px) * 32 + (c & 31);
    out[o] = f2bf(in[i]);
}

// ---------------------- instance norm -------------------------------------
__global__ __launch_bounds__(256) void inorm_stats(
    const float* __restrict__ x, float* __restrict__ stats, int HW)
{
    __shared__ float sh[8];
    const int bc = blockIdx.x;
    const float* p = x + (size_t)bc * HW;
    float s = 0.f, ss = 0.f;
    for (int i = threadIdx.x; i < HW; i += 256) {
        float v = p[i];
        s += v; ss = fmaf(v, v, ss);
    }
#pragma unroll
    for (int o = 32; o; o >>= 1) { s += __shfl_down(s, o); ss += __shfl_down(ss, o); }
    if ((threadIdx.x & 63) == 0) {
        sh[(threadIdx.x >> 6) * 2] = s;
        sh[(threadIdx.x >> 6) * 2 + 1] = ss;
    }
    __syncthreads();
    if (threadIdx.x == 0) {
        s  = sh[0] + sh[2] + sh[4] + sh[6];
        ss = sh[1] + sh[3] + sh[5] + sh[7];
        float m   = s / HW;
        float var = ss / HW - m * m;
        stats[2 * bc]     = m;
        stats[2 * bc + 1] = rsqrtf(var + 1e-5f);
    }
}

template <int MODE, bool WF32, bool WT16>
__global__ __launch_bounds__(256) void inorm_apply(
    float* __restrict__ x, const float* __restrict__ stats,
    const float* __restrict__ res, int lgHW, int lgC, size_t total,
    u16* __restrict__ tout)
{
    size_t i = (size_t)blockIdx.x * 256 + threadIdx.x;
    if (i >= total) return;
    int bc = (int)(i >> lgHW);
    float m = stats[2 * bc], r = stats[2 * bc + 1];
    float v = (x[i] - m) * r;
    if (MODE == 1) v = fmaxf(v, 0.f);
    if (MODE == 2) v += res[i];
    if (WF32) x[i] = v;
    if (WT16) {
        int px = (int)(i & (((size_t)1 << lgHW) - 1));
        int c = bc & ((1 << lgC) - 1);
        int b = bc >> lgC;
        size_t o = ((((size_t)(b << (lgC - 5)) + (c >> 5)) << lgHW) + px) * 32 + (c & 31);
        tout[o] = f2bf(v);
    }
}

// ---------------------------------------------------------------------------
// MFMA deformable conv.
// ---------------------------------------------------------------------------
template <int C, int O, int MF>
__global__ __launch_bounds__(256) void deform_mfma(
    const u16* __restrict__ featT, const float* __restrict__ om,
    const u16* __restrict__ dwt, const float* __restrict__ bias,
    u16* __restrict__ outT, int H, int W, int lgW)
{
    constexpr int NOB = O / 16, NCC = C / 32;
    constexpr int NT = 576;
    constexpr int CPT = C / 4;
    const int HW = H * W;
    const int b  = blockIdx.y;
    const int p0 = blockIdx.x * 64;
    const int tid = threadIdx.x;
    const int wv = tid >> 6, lane = tid & 63, lm = lane & 15, lg = lane >> 4;

    __shared__ int   sO[4][NT];
    __shared__ float sW[4][NT];
    __shared__ u16   val[64 * C];

    for (int t = tid; t < NT; t += 256) {
        int px = t & 63, k = t >> 6;
        int p  = p0 + px;
        int hh = p >> lgW, ww = p & (W - 1);
        float dy = om[((size_t)b * 27 + k) * HW + p];
        float dx = om[((size_t)b * 27 + 9 + k) * HW + p];
        float mk = 1.f / (1.f + __expf(-om[((size_t)b * 27 + 18 + k) * HW + p]));
        float py  = (float)(hh + k / 3 - 1) + dy;
        float pxf = (float)(ww + k % 3 - 1) + dx;
        float y0f = floorf(py), x0f = floorf(pxf);
        int y0 = (int)y0f, x0 = (int)x0f;
        float wy = py - y0f, wx = pxf - x0f;
        float vy0 = ((unsigned)y0       < (unsigned)H) ? 1.f : 0.f;
        float vy1 = ((unsigned)(y0 + 1) < (unsigned)H) ? 1.f : 0.f;
        float vx0 = ((unsigned)x0       < (unsigned)W) ? 1.f : 0.f;
        float vx1 = ((unsigned)(x0 + 1) < (unsigned)W) ? 1.f : 0.f;
        int y0c = min(max(y0, 0), H - 1), y1c = min(max(y0 + 1, 0), H - 1);
        int x0c = min(max(x0, 0), W - 1), x1c = min(max(x0 + 1, 0), W - 1);
        sO[0][t] = y0c * W + x0c;  sO[1][t] = y0c * W + x1c;
        sO[2][t] = y1c * W + x0c;  sO[3][t] = y1c * W + x1c;
        sW[0][t] = (1.f - wy) * (1.f - wx) * vy0 * vx0 * mk;
        sW[1][t] = (1.f - wy) * wx         * vy0 * vx1 * mk;
        sW[2][t] = wy         * (1.f - wx) * vy1 * vx0 * mk;
        sW[3][t] = wy         * wx         * vy1 * vx1 * mk;
    }
    __syncthreads();

    float4v acc[MF][4];
#pragma unroll
    for (int m = 0; m < MF; ++m)
#pragma unroll
        for (int n = 0; n < 4; ++n) acc[m][n] = (float4v){0.f, 0.f, 0.f, 0.f};

    const int gpx = tid >> 2, gc0 = (tid & 3) * CPT;

    for (int k = 0; k < 9; ++k) {
        if (k) __syncthreads();
        {
            int t = k * 64 + gpx;
            int o0 = sO[0][t], o1 = sO[1][t], o2 = sO[2][t], o3 = sO[3][t];
            float w0 = sW[0][t], w1 = sW[1][t], w2 = sW[2][t], w3 = sW[3][t];
#pragma unroll
            for (int c8 = 0; c8 < CPT / 8; ++c8) {
                int c = gc0 + c8 * 8;
                const u16* base = featT + ((size_t)(b * NCC + (c >> 5)) * HW) * 32 + (c & 31);
                uint4 r0 = *(const uint4*)(base + (size_t)o0 * 32);
                uint4 r1 = *(const uint4*)(base + (size_t)o1 * 32);
                uint4 r2 = *(const uint4*)(base + (size_t)o2 * 32);
                uint4 r3 = *(const uint4*)(base + (size_t)o3 * 32);
                const u16* p0_ = (const u16*)&r0;
                const u16* p1_ = (const u16*)&r1;
                const u16* p2_ = (const u16*)&r2;
                const u16* p3_ = (const u16*)&r3;
                u16 outv[8];
#pragma unroll
                for (int j = 0; j < 8; ++j) {
                    float s = w0 * bf2f(p0_[j]) + w1 * bf2f(p1_[j])
                            + w2 * bf2f(p2_[j]) + w3 * bf2f(p3_[j]);
                    outv[j] = f2bf(s);
                }
                int csw = c ^ ((gpx & 7) << 3);
                *(uint4*)(val + gpx * C + csw) = *(uint4*)outv;
            }
        }
        __syncthreads();
        const u16* wk = dwt + (size_t)k * NOB * NCC * 512;
#pragma unroll
        for (int m = 0; m < MF; ++m) {
            int ob = wv * MF + m;
#pragma unroll
            for (int cc = 0; cc < NCC; ++cc) {
                short8 Af = *(const short8*)(wk + ((size_t)ob * NCC + cc) * 512 + lane * 8);
#pragma unroll
                for (int nf = 0; nf < 4; ++nf) {
                    int row = nf * 16 + lm;
                    int csw = (cc * 32 + lg * 8) ^ ((row & 7) << 3);
                    short8 Bf = *(const short8*)(val + row * C + csw);
                    acc[m][nf] = mfma16(Af, Bf, acc[m][nf]);
                }
            }
        }
    }

#pragma unroll
    for (int m = 0; m < MF; ++m) {
        int oc0 = (wv * MF + m) * 16 + lg * 4;
#pragma unroll
        for (int nf = 0; nf < 4; ++nf) {
            int p = p0 + nf * 16 + lm;
#pragma unroll
            for (int r = 0; r < 4; ++r) {
                int oc = oc0 + r;
                outT[((size_t)(b * (O / 32) + (oc >> 5)) * HW + p) * 32 + (oc & 31)]
                    = f2bf(acc[m][nf][r] + bias[oc]);
            }
        }
    }
}

// ---------------------- offset |mean| reductions --------------------------
__global__ __launch_bounds__(256) void absmean_partial(
    const float* __restrict__ om, int HW, float* __restrict__ partial)
{
    const int n18 = 18 * HW;
    const long long total = 4LL * n18;
    float s = 0.f;
    for (long long i = (long long)blockIdx.x * 256 + threadIdx.x; i < total;
         i += (long long)gridDim.x * 256) {
        int b = (int)(i / n18);
        int r = (int)(i % n18);
        s += fabsf(om[(size_t)b * 27 * HW + r]);
    }
    __shared__ float sh[4];
#pragma unroll
    for (int o = 32; o; o >>= 1) s += __shfl_down(s, o);
    if ((threadIdx.x & 63) == 0) sh[threadIdx.x >> 6] = s;
    __syncthreads();
    if (threadIdx.x == 0) partial[blockIdx.x] = sh[0] + sh[1] + sh[2] + sh[3];
}

__global__ __launch_bounds__(256) void finalize_k(
    const float* __restrict__ p1, const float* __restrict__ p2,
    float* __restrict__ outScalar)
{
    __shared__ float sh[8];
    float a = p1[threadIdx.x] + p1[threadIdx.x + 256];
    float b = p2[threadIdx.x] + p2[threadIdx.x + 256];
#pragma unroll
    for (int o = 32; o; o >>= 1) { a += __shfl_down(a, o); b += __shfl_down(b, o); }
    if ((threadIdx.x & 63) == 0) {
        sh[(threadIdx.x >> 6) * 2]     = a;
        sh[(threadIdx.x >> 6) * 2 + 1] = b;
    }
    __syncthreads();
    if (threadIdx.x == 0) {
        a = sh[0] + sh[2] + sh[4] + sh[6];
        b = sh[1] + sh[3] + sh[5] + sh[7];
        *outScalar = 0.5f * (a / (4.f * 18.f * 16384.f) + b / (4.f * 18.f * 4096.f));
    }
}

// ---------------------------------------------------------------------------
extern "C" void kernel_launch(void* const* d_in, const int* in_sizes, int n_in,
                              void* d_out, int out_size, void* d_ws, size_t ws_size,
                              hipStream_t stream)
{
    const float* x      = (const float*)d_in[0];
    const float* skip1  = (const float*)d_in[1];
    const float* skip2  = (const float*)d_in[2];
    const float* rb1_w1 = (const float*)d_in[3];
    const float* rb1_b1 = (const float*)d_in[4];
    const float* rb1_w2 = (const float*)d_in[5];
    const float* rb1_b2 = (const float*)d_in[6];
    const float* rb2_w1 = (const float*)d_in[7];
    const float* rb2_b1 = (const float*)d_in[8];
    const float* rb2_w2 = (const float*)d_in[9];
    const float* rb2_b2 = (const float*)d_in[10];
    const float* c1_w   = (const float*)d_in[11];
    const float* c1_b   = (const float*)d_in[12];
    const float* c2_w   = (const float*)d_in[13];
    const float* c2_b   = (const float*)d_in[14];
    const float* c3_w   = (const float*)d_in[15];
    const float* c3_b   = (const float*)d_in[16];
    const float* off2_w = (const float*)d_in[17];
    const float* off2_b = (const float*)d_in[18];
    const float* d2_w   = (const float*)d_in[19];
    const float* d2_b   = (const float*)d_in[20];
    const float* off1_w = (const float*)d_in[21];
    const float* off1_b = (const float*)d_in[22];
    const float* d1_w   = (const float*)d_in[23];
    const float* d1_b   = (const float*)d_in[24];

    float* ws    = (float*)d_ws;
    float* stats = ws;
    float* part2 = ws + 2048;
    float* part1 = ws + 2560;

    // ---- weight pack arenas (words) ----
    u16* wtRB = (u16*)(ws + 4096);
    u16* wtC1 = (u16*)(ws + 299008);
    u16* wtC2 = (u16*)(ws + 708608);
    u16* wtO2 = (u16*)(ws + 913408);
    u16* wtO1 = (u16*)(ws + 950272);
    // ---- Z1: R2 fp32 (4M w) with early overlays ----
    float* R2  = ws + 968704;                  // [c2 -> inorm_apply]
    u16*  xT   = (u16*)(ws + 968704);
    u16*  A1T  = xT;
    u16*  A2T  = (u16*)(ws + 968704 + 524288);
    u16*  A3T  = A2T;
    float* A1  = ws + 968704 + 1048576;
    float* A2  = ws + 968704 + 2097152;
    float* A3  = ws + 968704 + 3145728;
    float* OM2 = ws + 968704;                  // [off2 -> deform2]
    u16*  CP1T = (u16*)(ws + 968704);          // 2M u16 [deform1 -> c3] (R2 dead)
    u16*  wtC3 = (u16*)(ws + 3065856);         // 100352 u16 [-> c3] (A2 zone, dead)
    // ---- Z2: s1T ----
    u16*  s1T  = (u16*)(ws + 5163008);         // [-> deform1]
    // ---- Z3: R1 / wtD2+CP2T / R2T overlays ----
    float* R1  = ws + 7260160;                 // [c1 -> apply]
    u16*  wtD2 = (u16*)(ws + 7260160);         // [-> deform2]
    u16*  CP2T = (u16*)(ws + 7333888);         // [deform2 -> c2]
    u16*  R2T  = (u16*)(ws + 7260160);         // [apply(after c2) -> off1, c3]
    // ---- Z4: R1T then OM1 ----
    u16*  R1T  = (u16*)(ws + 9357312);         // [-> c2]
    float* OM1 = ws + 9357312;                 // [off1 -> deform1]
    // ---- Z5: s2T; tail holds wtD1 ----
    u16*  s2T  = (u16*)(ws + 10405888);        // [-> deform2]
    u16*  wtD1 = (u16*)(ws + 11126784);        // [-> deform1]

    float* outp = (float*)d_out;
    dim3 blk(256);

    // ---- input transforms ----
    act2t<<<4096, blk, 0, stream>>>(x, xT, 10, 8, 1048576);
    act2t<<<16384, blk, 0, stream>>>(skip1, s1T, 14, 6, 4194304);
    act2t<<<8192, blk, 0, stream>>>(skip2, s2T, 12, 7, 2097152);

    // ---- resblock 1 conv 1 ----
    wtrans<<<2304, blk, 0, stream>>>(rb1_w1, wtRB, 256, 256, 9, 16, 589824);
    mconv<3, false, true, 2, 5, 4><<<dim3(8, 8, 4), blk, 32768, stream>>>(
        xT, 8, nullptr, 8, wtRB, 16, rb1_b1, A1, 256, 32, 32, 1, 32);
    inorm_stats<<<1024, blk, 0, stream>>>(A1, stats, 1024);
    inorm_apply<1, false, true><<<4096, blk, 0, stream>>>(A1, stats, nullptr, 10, 8, 1048576, A1T);
    // ---- resblock 1 conv 2 ----
    wtrans<<<2304, blk, 0, stream>>>(rb1_w2, wtRB, 256, 256, 9, 16, 589824);
    mconv<3, false, true, 2, 5, 4><<<dim3(8, 8, 4), blk, 32768, stream>>>(
        A1T, 8, nullptr, 8, wtRB, 16, rb1_b2, A2, 256, 32, 32, 1, 32);
    inorm_stats<<<1024, blk, 0, stream>>>(A2, stats, 1024);
    inorm_apply<2, true, true><<<4096, blk, 0, stream>>>(A2, stats, x, 10, 8, 1048576, A2T);
    // ---- resblock 2 conv 1 ----
    wtrans<<<2304, blk, 0, stream>>>(rb2_w1, wtRB, 256, 256, 9, 16, 589824);
    mconv<3, false, true, 2, 5, 4><<<dim3(8, 8, 4), blk, 32768, stream>>>(
        A2T, 8, nullptr, 8, wtRB, 16, rb2_b1, A1, 256, 32, 32, 1, 32);
    inorm_stats<<<1024, blk, 0, stream>>>(A1, stats, 1024);
    inorm_apply<1, false, true><<<4096, blk, 0, stream>>>(A1, stats, nullptr, 10, 8, 1048576, A1T);
    // ---- resblock 2 conv 2 ----
    wtrans<<<2304, blk, 0, stream>>>(rb2_w2, wtRB, 256, 256, 9, 16, 589824);
    mconv<3, false, true, 2, 5, 4><<<dim3(8, 8, 4), blk, 32768, stream>>>(
        A1T, 8, nullptr, 8, wtRB, 16, rb2_b2, A3, 256, 32, 32, 1, 32);
    inorm_stats<<<1024, blk, 0, stream>>>(A3, stats, 1024);
    inorm_apply<2, false, true><<<4096, blk, 0, stream>>>(A3, stats, A2, 10, 8, 1048576, A3T);
    // ---- c1: up2 + 5x5 reflect, 256->128 @64 ----
    wtrans<<<3200, blk, 0, stream>>>(c1_w, wtC1, 128, 256, 25, 8, 819200);
    mconv<5, true, true, 2, 6, 2><<<dim3(32, 4, 4), blk, 57344, stream>>>(
        A3T, 8, nullptr, 8, wtC1, 8, c1_b, R1, 128, 64, 64, 1, 32);
    inorm_stats<<<512, blk, 0, stream>>>(R1, stats, 4096);
    inorm_apply<1, false, true><<<8192, blk, 0, stream>>>(R1, stats, nullptr, 12, 7, 2097152, R1T);
    // ---- off2: concat(R1T, s2T) 3x3 zero-pad -> 27ch ----
    wtrans<<<288, blk, 0, stream>>>(off2_w, wtO2, 27, 256, 9, 2, 73728);
    mconv<3, false, false, 2, 6, 2><<<dim3(32, 1, 4), blk, 40960, stream>>>(
        R1T, 4, s2T, 8, wtO2, 2, off2_b, OM2, 27, 64, 64, 1, 64);
    absmean_partial<<<512, blk, 0, stream>>>(OM2, 4096, part2);
    // ---- deform 2 (MFMA, gather from s2T) ----
    dwtrans<128, 128><<<576, blk, 0, stream>>>(d2_w, wtD2);
    deform_mfma<128, 128, 2><<<dim3(64, 4), blk, 0, stream>>>(
        s2T, OM2, wtD2, d2_b, CP2T, 64, 64, 6);
    // ---- c2: up2(concat(CP2T, R1T)) + 5x5 reflect, 256->64 @128 ----
    wtrans<<<1600, blk, 0, stream>>>(c2_w, wtC2, 64, 256, 25, 4, 409600);
    mconv<5, true, true, 4, 6, 1><<<dim3(256, 1, 4), blk, 49152, stream>>>(
        CP2T, 4, R1T, 8, wtC2, 4, c2_b, R2, 64, 128, 128, 2, 64);
    inorm_stats<<<256, blk, 0, stream>>>(R2, stats, 16384);
    // bf16 R2T only; fp32 R2 becomes dead after this (frees Z1 for CP1T)
    inorm_apply<1, false, true><<<16384, blk, 0, stream>>>(R2, stats, nullptr, 14, 6, 4194304, R2T);
    // ---- off1: concat(R2T (2 chunks), s1T (2 chunks)) -> 27ch ----
    wtrans<<<144, blk, 0, stream>>>(off1_w, wtO1, 27, 128, 9, 2, 36864);
    mconv<3, false, false, 2, 6, 2><<<dim3(128, 1, 4), blk, 40960, stream>>>(
        R2T, 2, s1T, 4, wtO1, 2, off1_b, OM1, 27, 128, 128, 2, 128);
    absmean_partial<<<512, blk, 0, stream>>>(OM1, 16384, part1);
    // ---- deform 1 (MFMA, gather from s1T) -> CP1T in freed Z1 ----
    dwtrans<64, 64><<<144, blk, 0, stream>>>(d1_w, wtD1);
    deform_mfma<64, 64, 1><<<dim3(256, 4), blk, 0, stream>>>(
        s1T, OM1, wtD1, d1_b, CP1T, 128, 128, 7);
    // ---- c3: concat(CP1T, R2T) 7x7 reflect + tanh -> 3ch via MFMA ----
    wtrans<<<392, blk, 0, stream>>>(c3_w, wtC3, 3, 128, 49, 1, 100352);
    mconv<7, false, true, 1, 4, 16, 2><<<dim3(64, 1, 4), blk, 65536, stream>>>(
        CP1T, 2, R2T, 4, wtC3, 1, c3_b, outp, 3, 128, 128, 8, 128);
    // ---- offset_sum ----
    finalize_k<<<1, blk, 0, stream>>>(part1, part2, outp + 196608);
}

// Round 10
// 571.749 us; speedup vs baseline: 7.8886x; 1.1600x over previous
//
#include <hip/hip_runtime.h>
#include <hip/hip_bf16.h>

#define DEV __device__ __forceinline__

typedef unsigned short u16;
typedef __attribute__((ext_vector_type(8))) short short8;
typedef __attribute__((ext_vector_type(4))) float float4v;

DEV u16 f2bf(float v) {
    __hip_bfloat16 h = __float2bfloat16(v);
    return *reinterpret_cast<u16*>(&h);
}
DEV float bf2f(u16 u) { return __uint_as_float(((unsigned)u) << 16); }

DEV float4v mfma16(short8 a, short8 b, float4v c) {
    return __builtin_amdgcn_mfma_f32_16x16x32_bf16(a, b, c, 0, 0, 0);
}

// async global->LDS, 16B per lane; LDS dest = wave-uniform base + lane*16.
DEV void gload_lds16(const u16* g, u16* l) {
    __builtin_amdgcn_global_load_lds(
        (const __attribute__((address_space(1))) void*)g,
        (__attribute__((address_space(3))) void*)l, 16, 0, 0);
}

// ---------------------------------------------------------------------------
// MFMA conv, 2-phase pipelined via global_load_lds (no register staging —
// round-8/9 profile showed the reg-staged version spilled rv[] to scratch:
// 148 MB of HBM writes). Input bf16 chunked [b][ch][px][32ic] (virtual
// concat X0|X1), optional fused 2x upsample, reflect or zero pad.
// Block: 256 thr = 4 waves = NWO oc-groups x NWP px-groups; wave = 16oc x 64px.
// LDS: double-buffered, icg-major [icg][t][8ch] -> conflict-free ds_read_b128.
// Zero-pad: OOB slot set is chunk-invariant -> zero both buffers once,
// then only issue loads for valid slots.
// ---------------------------------------------------------------------------
template <int K, bool UP, bool REFLECT, int NWO, int LGTW, int TH, int ACT = 0>
__global__ __launch_bounds__(256) void mconv(
    const u16* __restrict__ X0, int c0ch,
    const u16* __restrict__ X1, int nch,
    const u16* __restrict__ WT, int NOB,
    const float* __restrict__ bias, float* __restrict__ out,
    int OC, int W, int H, int tilesX, int SW)
{
    constexpr int P    = (K - 1) / 2;
    constexpr int K2   = K * K;
    constexpr int NWP  = 4 / NWO;
    constexpr int TW   = 1 << LGTW;
    constexpr int LW   = TW + K - 1;
    constexpr int ROWS = TH + K - 1;
    constexpr int IT   = ROWS * LW;          // 16B slots per icg
    constexpr int ITEMS = IT * 4;            // total 16B slots
    constexpr int CEIL = (ITEMS + 255) / 256;
    constexpr int BUF  = CEIL * 2048;        // u16 per buffer

    extern __shared__ u16 Xs[];
    const int tid = threadIdx.x;
    const int wv = tid >> 6, lane = tid & 63, lm = lane & 15, lg = lane >> 4;
    const int wo = wv / NWP, wp = wv % NWP;
    const int bx = blockIdx.x, b = blockIdx.z;
    const int ty = bx / tilesX, tx = bx - ty * tilesX;
    const int row0 = ty * TH, col0 = tx * TW;
    const int SH  = UP ? (H >> 1) : H;
    const int HWs = SW * SH;
    const int ob  = blockIdx.y * NWO + wo;
    const int wbase = tid & 192;             // wave-uniform slot base

    // ---- per-item source offsets (u16 units in channel plane), ch-invariant
    int offr[CEIL];
#pragma unroll
    for (int i = 0; i < CEIL; ++i) {
        int q = i * 256 + tid;
        bool tail = q >= ITEMS;
        if (tail) q = ITEMS - 1;
        int icg = q / IT;
        int t   = q - icg * IT;
        int tr  = t / LW, tc = t - tr * LW;
        int gy = row0 - P + tr, gx = col0 - P + tc;
        if (REFLECT) {
            gy = gy < 0 ? -gy : (gy >= H ? 2 * H - 2 - gy : gy);
            gx = gx < 0 ? -gx : (gx >= W ? 2 * W - 2 - gx : gx);
            int sy = UP ? (gy >> 1) : gy, sx = UP ? (gx >> 1) : gx;
            offr[i] = (sy * SW + sx) * 32 + icg * 8;
        } else {
            bool ok = (gy >= 0) & (gy < H) & (gx >= 0) & (gx < W) & !tail;
            int sy = UP ? (gy >> 1) : gy, sx = UP ? (gx >> 1) : gx;
            offr[i] = ok ? (sy * SW + sx) * 32 + icg * 8 : -1;
        }
    }

    // ---- per-nf bases: LDS read offset (u16) and output pixel
    int rb16[4], opx[4];
#pragma unroll
    for (int nf = 0; nf < 4; ++nf) {
        int pt = wp * 64 + nf * 16 + lm;
        int ro = pt >> LGTW, co = pt & (TW - 1);
        rb16[nf] = (lg * IT + ro * LW + co) * 8;
        opx[nf]  = (row0 + ro) * W + col0 + co;
    }

    float4v acc[4];
#pragma unroll
    for (int n = 0; n < 4; ++n) acc[n] = (float4v){0.f, 0.f, 0.f, 0.f};

    auto planeptr = [&](int ch) -> const u16* {
        return (ch < c0ch)
            ? X0 + (size_t)(b * c0ch + ch) * HWs * 32
            : X1 + (size_t)(b * (nch - c0ch) + (ch - c0ch)) * HWs * 32;
    };

    // zero both buffers once (zero-pad convs only; OOB set is chunk-invariant)
    if (!REFLECT) {
        const uint4 UZ = {0u, 0u, 0u, 0u};
        for (int i = tid; i < BUF / 4; i += 256)
            *(uint4*)(Xs + (size_t)i * 8) = UZ;
        __syncthreads();
    }

    // ---- prologue: async-load chunk 0 into buf 0 ----
    {
        const u16* src = planeptr(0);
#pragma unroll
        for (int i = 0; i < CEIL; ++i)
            if (offr[i] >= 0)
                gload_lds16(src + offr[i], &Xs[(size_t)(i * 256 + wbase) * 8]);
    }
    __syncthreads();   // vmcnt(0) drained before barrier -> buf0 ready

    int cur = 0;
    for (int ch = 0; ch < nch; ++ch) {
        // issue next-chunk async loads into the other buffer (overlap w/ MFMA)
        if (ch + 1 < nch) {
            const u16* src = planeptr(ch + 1);
            u16* dstb = Xs + (size_t)(cur ^ 1) * BUF;
#pragma unroll
            for (int i = 0; i < CEIL; ++i)
                if (offr[i] >= 0)
                    gload_lds16(src + offr[i], &dstb[(size_t)(i * 256 + wbase) * 8]);
        }
        // MFMA on current buffer
        const u16* base = Xs + (size_t)cur * BUF;
        const u16* wch  = WT + ((size_t)ch * NOB + ob) * K2 * 512 + lane * 8;
#pragma unroll
        for (int ky = 0; ky < K; ++ky) {
#pragma unroll
            for (int kx = 0; kx < K; ++kx) {
                short8 Af = *(const short8*)(wch + (size_t)(ky * K + kx) * 512);
#pragma unroll
                for (int nf = 0; nf < 4; ++nf) {
                    short8 Bf = *(const short8*)(base + rb16[nf] + (ky * LW + kx) * 8);
                    acc[nf] = mfma16(Af, Bf, acc[nf]);
                }
            }
        }
        __syncthreads();   // drains async loads -> next buffer ready
        cur ^= 1;
    }

    // ---- epilogue ----
    const size_t HWo = (size_t)H * W;
    int oc0 = ob * 16 + lg * 4;
#pragma unroll
    for (int nf = 0; nf < 4; ++nf) {
#pragma unroll
        for (int r = 0; r < 4; ++r) {
            int oc = oc0 + r;
            if (oc < OC) {
                float v = acc[nf][r] + bias[oc];
                if (ACT == 2) v = tanhf(v);
                out[(size_t)(b * OC + oc) * HWo + opx[nf]] = v;
            }
        }
    }
}

// ---------------------------------------------------------------------------
// Weight pack: w[OC][IC][K2] fp32 -> wt[ch][ob][tap][lane][8] bf16 (A-frag).
// ---------------------------------------------------------------------------
__global__ __launch_bounds__(256) void wtrans(
    const float* __restrict__ w, u16* __restrict__ wt,
    int OC, int IC, int K2, int NOB, int total)
{
    int i = blockIdx.x * 256 + threadIdx.x;
    if (i >= total) return;
    int e = i & 7;
    int l = (i >> 3) & 63;
    int rest = i >> 9;
    int tap = rest % K2;
    rest /= K2;
    int ob = rest % NOB;
    int ch = rest / NOB;
    int oc = ob * 16 + (l & 15);
    if (oc >= OC) oc = OC - 1;
    int ic = ch * 32 + (l >> 4) * 8 + e;
    wt[i] = f2bf(w[((size_t)oc * IC + ic) * K2 + tap]);
}

// Deform weight pack: w[O][C][9] fp32 -> dwt[k][ob][cc][lane][8] bf16.
template <int C, int O>
__global__ __launch_bounds__(256) void dwtrans(
    const float* __restrict__ w, u16* __restrict__ dwt)
{
    constexpr int NOB = O / 16, NCC = C / 32;
    constexpr int total = 9 * NOB * NCC * 512;
    int i = blockIdx.x * 256 + threadIdx.x;
    if (i >= total) return;
    int e = i & 7;
    int l = (i >> 3) & 63;
    int rest = i >> 9;
    int cc = rest % NCC;
    rest /= NCC;
    int ob = rest % NOB;
    int k  = rest / NOB;
    int oc = ob * 16 + (l & 15);
    int ic = cc * 32 + (l >> 4) * 8 + e;
    dwt[i] = f2bf(w[((size_t)oc * C + ic) * 9 + k]);
}

// ---------------------------------------------------------------------------
// fp32 NCHW -> bf16 [b][chunk][px][32ic]
// ---------------------------------------------------------------------------
__global__ __launch_bounds__(256) void act2t(
    const float* __restrict__ in, u16* __restrict__ out,
    int lgHW, int lgC, size_t total)
{
    size_t i = (size_t)blockIdx.x * 256 + threadIdx.x;
    if (i >= total) return;
    int px = (int)(i & (((size_t)1 << lgHW) - 1));
    int bc = (int)(i >> lgHW);
    int c = bc & ((1 << lgC) - 1);
    int b = bc >> lgC;
    size_t o = ((((size_t)(b << (lgC - 5)) + (c >> 5)) << lgHW) + px) * 32 + (c & 31);
    out[o] = f2bf(in[i]);
}

// ---------------------- instance norm -------------------------------------
__global__ __launch_bounds__(256) void inorm_stats(
    const float* __restrict__ x, float* __restrict__ stats, int HW)
{
    __shared__ float sh[8];
    const int bc = blockIdx.x;
    const float* p = x + (size_t)bc * HW;
    float s = 0.f, ss = 0.f;
    for (int i = threadIdx.x; i < HW; i += 256) {
        float v = p[i];
        s += v; ss = fmaf(v, v, ss);
    }
#pragma unroll
    for (int o = 32; o; o >>= 1) { s += __shfl_down(s, o); ss += __shfl_down(ss, o); }
    if ((threadIdx.x & 63) == 0) {
        sh[(threadIdx.x >> 6) * 2] = s;
        sh[(threadIdx.x >> 6) * 2 + 1] = ss;
    }
    __syncthreads();
    if (threadIdx.x == 0) {
        s  = sh[0] + sh[2] + sh[4] + sh[6];
        ss = sh[1] + sh[3] + sh[5] + sh[7];
        float m   = s / HW;
        float var = ss / HW - m * m;
        stats[2 * bc]     = m;
        stats[2 * bc + 1] = rsqrtf(var + 1e-5f);
    }
}

template <int MODE, bool WF32, bool WT16>
__global__ __launch_bounds__(256) void inorm_apply(
    float* __restrict__ x, const float* __restrict__ stats,
    const float* __restrict__ res, int lgHW, int lgC, size_t total,
    u16* __restrict__ tout)
{
    size_t i = (size_t)blockIdx.x * 256 + threadIdx.x;
    if (i >= total) return;
    int bc = (int)(i >> lgHW);
    float m = stats[2 * bc], r = stats[2 * bc + 1];
    float v = (x[i] - m) * r;
    if (MODE == 1) v = fmaxf(v, 0.f);
    if (MODE == 2) v += res[i];
    if (WF32) x[i] = v;
    if (WT16) {
        int px = (int)(i & (((size_t)1 << lgHW) - 1));
        int c = bc & ((1 << lgC) - 1);
        int b = bc >> lgC;
        size_t o = ((((size_t)(b << (lgC - 5)) + (c >> 5)) << lgHW) + px) * 32 + (c & 31);
        tout[o] = f2bf(v);
    }
}

// ---------------------------------------------------------------------------
// MFMA deformable conv.
// ---------------------------------------------------------------------------
template <int C, int O, int MF>
__global__ __launch_bounds__(256) void deform_mfma(
    const u16* __restrict__ featT, const float* __restrict__ om,
    const u16* __restrict__ dwt, const float* __restrict__ bias,
    u16* __restrict__ outT, int H, int W, int lgW)
{
    constexpr int NOB = O / 16, NCC = C / 32;
    constexpr int NT = 576;
    constexpr int CPT = C / 4;
    const int HW = H * W;
    const int b  = blockIdx.y;
    const int p0 = blockIdx.x * 64;
    const int tid = threadIdx.x;
    const int wv = tid >> 6, lane = tid & 63, lm = lane & 15, lg = lane >> 4;

    __shared__ int   sO[4][NT];
    __shared__ float sW[4][NT];
    __shared__ u16   val[64 * C];

    for (int t = tid; t < NT; t += 256) {
        int px = t & 63, k = t >> 6;
        int p  = p0 + px;
        int hh = p >> lgW, ww = p & (W - 1);
        float dy = om[((size_t)b * 27 + k) * HW + p];
        float dx = om[((size_t)b * 27 + 9 + k) * HW + p];
        float mk = 1.f / (1.f + __expf(-om[((size_t)b * 27 + 18 + k) * HW + p]));
        float py  = (float)(hh + k / 3 - 1) + dy;
        float pxf = (float)(ww + k % 3 - 1) + dx;
        float y0f = floorf(py), x0f = floorf(pxf);
        int y0 = (int)y0f, x0 = (int)x0f;
        float wy = py - y0f, wx = pxf - x0f;
        float vy0 = ((unsigned)y0       < (unsigned)H) ? 1.f : 0.f;
        float vy1 = ((unsigned)(y0 + 1) < (unsigned)H) ? 1.f : 0.f;
        float vx0 = ((unsigned)x0       < (unsigned)W) ? 1.f : 0.f;
        float vx1 = ((unsigned)(x0 + 1) < (unsigned)W) ? 1.f : 0.f;
        int y0c = min(max(y0, 0), H - 1), y1c = min(max(y0 + 1, 0), H - 1);
        int x0c = min(max(x0, 0), W - 1), x1c = min(max(x0 + 1, 0), W - 1);
        sO[0][t] = y0c * W + x0c;  sO[1][t] = y0c * W + x1c;
        sO[2][t] = y1c * W + x0c;  sO[3][t] = y1c * W + x1c;
        sW[0][t] = (1.f - wy) * (1.f - wx) * vy0 * vx0 * mk;
        sW[1][t] = (1.f - wy) * wx         * vy0 * vx1 * mk;
        sW[2][t] = wy         * (1.f - wx) * vy1 * vx0 * mk;
        sW[3][t] = wy         * wx         * vy1 * vx1 * mk;
    }
    __syncthreads();

    float4v acc[MF][4];
#pragma unroll
    for (int m = 0; m < MF; ++m)
#pragma unroll
        for (int n = 0; n < 4; ++n) acc[m][n] = (float4v){0.f, 0.f, 0.f, 0.f};

    const int gpx = tid >> 2, gc0 = (tid & 3) * CPT;

    for (int k = 0; k < 9; ++k) {
        if (k) __syncthreads();
        {
            int t = k * 64 + gpx;
            int o0 = sO[0][t], o1 = sO[1][t], o2 = sO[2][t], o3 = sO[3][t];
            float w0 = sW[0][t], w1 = sW[1][t], w2 = sW[2][t], w3 = sW[3][t];
#pragma unroll
            for (int c8 = 0; c8 < CPT / 8; ++c8) {
                int c = gc0 + c8 * 8;
                const u16* base = featT + ((size_t)(b * NCC + (c >> 5)) * HW) * 32 + (c & 31);
                uint4 r0 = *(const uint4*)(base + (size_t)o0 * 32);
                uint4 r1 = *(const uint4*)(base + (size_t)o1 * 32);
                uint4 r2 = *(const uint4*)(base + (size_t)o2 * 32);
                uint4 r3 = *(const uint4*)(base + (size_t)o3 * 32);
                const u16* p0_ = (const u16*)&r0;
                const u16* p1_ = (const u16*)&r1;
                const u16* p2_ = (const u16*)&r2;
                const u16* p3_ = (const u16*)&r3;
                u16 outv[8];
#pragma unroll
                for (int j = 0; j < 8; ++j) {
                    float s = w0 * bf2f(p0_[j]) + w1 * bf2f(p1_[j])
                            + w2 * bf2f(p2_[j]) + w3 * bf2f(p3_[j]);
                    outv[j] = f2bf(s);
                }
                int csw = c ^ ((gpx & 7) << 3);
                *(uint4*)(val + gpx * C + csw) = *(uint4*)outv;
            }
        }
        __syncthreads();
        const u16* wk = dwt + (size_t)k * NOB * NCC * 512;
#pragma unroll
        for (int m = 0; m < MF; ++m) {
            int ob = wv * MF + m;
#pragma unroll
            for (int cc = 0; cc < NCC; ++cc) {
                short8 Af = *(const short8*)(wk + ((size_t)ob * NCC + cc) * 512 + lane * 8);
#pragma unroll
                for (int nf = 0; nf < 4; ++nf) {
                    int row = nf * 16 + lm;
                    int csw = (cc * 32 + lg * 8) ^ ((row & 7) << 3);
                    short8 Bf = *(const short8*)(val + row * C + csw);
                    acc[m][nf] = mfma16(Af, Bf, acc[m][nf]);
                }
            }
        }
    }

#pragma unroll
    for (int m = 0; m < MF; ++m) {
        int oc0 = (wv * MF + m) * 16 + lg * 4;
#pragma unroll
        for (int nf = 0; nf < 4; ++nf) {
            int p = p0 + nf * 16 + lm;
#pragma unroll
            for (int r = 0; r < 4; ++r) {
                int oc = oc0 + r;
                outT[((size_t)(b * (O / 32) + (oc >> 5)) * HW + p) * 32 + (oc & 31)]
                    = f2bf(acc[m][nf][r] + bias[oc]);
            }
        }
    }
}

// ---------------------- offset |mean| reductions --------------------------
__global__ __launch_bounds__(256) void absmean_partial(
    const float* __restrict__ om, int HW, float* __restrict__ partial)
{
    const int n18 = 18 * HW;
    const long long total = 4LL * n18;
    float s = 0.f;
    for (long long i = (long long)blockIdx.x * 256 + threadIdx.x; i < total;
         i += (long long)gridDim.x * 256) {
        int b = (int)(i / n18);
        int r = (int)(i % n18);
        s += fabsf(om[(size_t)b * 27 * HW + r]);
    }
    __shared__ float sh[4];
#pragma unroll
    for (int o = 32; o; o >>= 1) s += __shfl_down(s, o);
    if ((threadIdx.x & 63) == 0) sh[threadIdx.x >> 6] = s;
    __syncthreads();
    if (threadIdx.x == 0) partial[blockIdx.x] = sh[0] + sh[1] + sh[2] + sh[3];
}

__global__ __launch_bounds__(256) void finalize_k(
    const float* __restrict__ p1, const float* __restrict__ p2,
    float* __restrict__ outScalar)
{
    __shared__ float sh[8];
    float a = p1[threadIdx.x] + p1[threadIdx.x + 256];
    float b = p2[threadIdx.x] + p2[threadIdx.x + 256];
#pragma unroll
    for (int o = 32; o; o >>= 1) { a += __shfl_down(a, o); b += __shfl_down(b, o); }
    if ((threadIdx.x & 63) == 0) {
        sh[(threadIdx.x >> 6) * 2]     = a;
        sh[(threadIdx.x >> 6) * 2 + 1] = b;
    }
    __syncthreads();
    if (threadIdx.x == 0) {
        a = sh[0] + sh[2] + sh[4] + sh[6];
        b = sh[1] + sh[3] + sh[5] + sh[7];
        *outScalar = 0.5f * (a / (4.f * 18.f * 16384.f) + b / (4.f * 18.f * 4096.f));
    }
}

// ---------------------------------------------------------------------------
extern "C" void kernel_launch(void* const* d_in, const int* in_sizes, int n_in,
                              void* d_out, int out_size, void* d_ws, size_t ws_size,
                              hipStream_t stream)
{
    const float* x      = (const float*)d_in[0];
    const float* skip1  = (const float*)d_in[1];
    const float* skip2  = (const float*)d_in[2];
    const float* rb1_w1 = (const float*)d_in[3];
    const float* rb1_b1 = (const float*)d_in[4];
    const float* rb1_w2 = (const float*)d_in[5];
    const float* rb1_b2 = (const float*)d_in[6];
    const float* rb2_w1 = (const float*)d_in[7];
    const float* rb2_b1 = (const float*)d_in[8];
    const float* rb2_w2 = (const float*)d_in[9];
    const float* rb2_b2 = (const float*)d_in[10];
    const float* c1_w   = (const float*)d_in[11];
    const float* c1_b   = (const float*)d_in[12];
    const float* c2_w   = (const float*)d_in[13];
    const float* c2_b   = (const float*)d_in[14];
    const float* c3_w   = (const float*)d_in[15];
    const float* c3_b   = (const float*)d_in[16];
    const float* off2_w = (const float*)d_in[17];
    const float* off2_b = (const float*)d_in[18];
    const float* d2_w   = (const float*)d_in[19];
    const float* d2_b   = (const float*)d_in[20];
    const float* off1_w = (const float*)d_in[21];
    const float* off1_b = (const float*)d_in[22];
    const float* d1_w   = (const float*)d_in[23];
    const float* d1_b   = (const float*)d_in[24];

    float* ws    = (float*)d_ws;
    float* stats = ws;
    float* part2 = ws + 2048;
    float* part1 = ws + 2560;

    // ---- weight pack arenas (words) ----
    u16* wtRB = (u16*)(ws + 4096);
    u16* wtC1 = (u16*)(ws + 299008);
    u16* wtC2 = (u16*)(ws + 708608);
    u16* wtO2 = (u16*)(ws + 913408);
    u16* wtO1 = (u16*)(ws + 950272);
    // ---- Z1: R2 fp32 (4M w) with early overlays ----
    float* R2  = ws + 968704;                  // [c2 -> inorm_apply]
    u16*  xT   = (u16*)(ws + 968704);
    u16*  A1T  = xT;
    u16*  A2T  = (u16*)(ws + 968704 + 524288);
    u16*  A3T  = A2T;
    float* A1  = ws + 968704 + 1048576;
    float* A2  = ws + 968704 + 2097152;
    float* A3  = ws + 968704 + 3145728;
    float* OM2 = ws + 968704;                  // [off2 -> deform2]
    u16*  CP1T = (u16*)(ws + 968704);          // 2M u16 [deform1 -> c3] (R2 dead)
    u16*  wtC3 = (u16*)(ws + 3065856);         // 100352 u16 [-> c3] (A2 zone, dead)
    // ---- Z2: s1T ----
    u16*  s1T  = (u16*)(ws + 5163008);         // [-> deform1]
    // ---- Z3: R1 / wtD2+CP2T / R2T overlays ----
    float* R1  = ws + 7260160;                 // [c1 -> apply]
    u16*  wtD2 = (u16*)(ws + 7260160);         // [-> deform2]
    u16*  CP2T = (u16*)(ws + 7333888);         // [deform2 -> c2]
    u16*  R2T  = (u16*)(ws + 7260160);         // [apply(after c2) -> off1, c3]
    // ---- Z4: R1T then OM1 ----
    u16*  R1T  = (u16*)(ws + 9357312);         // [-> c2]
    float* OM1 = ws + 9357312;                 // [off1 -> deform1]
    // ---- Z5: s2T; tail holds wtD1 ----
    u16*  s2T  = (u16*)(ws + 10405888);        // [-> deform2]
    u16*  wtD1 = (u16*)(ws + 11126784);        // [-> deform1]

    float* outp = (float*)d_out;
    dim3 blk(256);

    // ---- input transforms ----
    act2t<<<4096, blk, 0, stream>>>(x, xT, 10, 8, 1048576);
    act2t<<<16384, blk, 0, stream>>>(skip1, s1T, 14, 6, 4194304);
    act2t<<<8192, blk, 0, stream>>>(skip2, s2T, 12, 7, 2097152);

    // ---- resblock 1 conv 1 ----
    wtrans<<<2304, blk, 0, stream>>>(rb1_w1, wtRB, 256, 256, 9, 16, 589824);
    mconv<3, false, true, 2, 5, 4><<<dim3(8, 8, 4), blk, 32768, stream>>>(
        xT, 8, nullptr, 8, wtRB, 16, rb1_b1, A1, 256, 32, 32, 1, 32);
    inorm_stats<<<1024, blk, 0, stream>>>(A1, stats, 1024);
    inorm_apply<1, false, true><<<4096, blk, 0, stream>>>(A1, stats, nullptr, 10, 8, 1048576, A1T);
    // ---- resblock 1 conv 2 ----
    wtrans<<<2304, blk, 0, stream>>>(rb1_w2, wtRB, 256, 256, 9, 16, 589824);
    mconv<3, false, true, 2, 5, 4><<<dim3(8, 8, 4), blk, 32768, stream>>>(
        A1T, 8, nullptr, 8, wtRB, 16, rb1_b2, A2, 256, 32, 32, 1, 32);
    inorm_stats<<<1024, blk, 0, stream>>>(A2, stats, 1024);
    inorm_apply<2, true, true><<<4096, blk, 0, stream>>>(A2, stats, x, 10, 8, 1048576, A2T);
    // ---- resblock 2 conv 1 ----
    wtrans<<<2304, blk, 0, stream>>>(rb2_w1, wtRB, 256, 256, 9, 16, 589824);
    mconv<3, false, true, 2, 5, 4><<<dim3(8, 8, 4), blk, 32768, stream>>>(
        A2T, 8, nullptr, 8, wtRB, 16, rb2_b1, A1, 256, 32, 32, 1, 32);
    inorm_stats<<<1024, blk, 0, stream>>>(A1, stats, 1024);
    inorm_apply<1, false, true><<<4096, blk, 0, stream>>>(A1, stats, nullptr, 10, 8, 1048576, A1T);
    // ---- resblock 2 conv 2 ----
    wtrans<<<2304, blk, 0, stream>>>(rb2_w2, wtRB, 256, 256, 9, 16, 589824);
    mconv<3, false, true, 2, 5, 4><<<dim3(8, 8, 4), blk, 32768, stream>>>(
        A1T, 8, nullptr, 8, wtRB, 16, rb2_b2, A3, 256, 32, 32, 1, 32);
    inorm_stats<<<1024, blk, 0, stream>>>(A3, stats, 1024);
    inorm_apply<2, false, true><<<4096, blk, 0, stream>>>(A3, stats, A2, 10, 8, 1048576, A3T);
    // ---- c1: up2 + 5x5 reflect, 256->128 @64 ----
    wtrans<<<3200, blk, 0, stream>>>(c1_w, wtC1, 128, 256, 25, 8, 819200);
    mconv<5, true, true, 2, 6, 2><<<dim3(32, 4, 4), blk, 57344, stream>>>(
        A3T, 8, nullptr, 8, wtC1, 8, c1_b, R1, 128, 64, 64, 1, 32);
    inorm_stats<<<512, blk, 0, stream>>>(R1, stats, 4096);
    inorm_apply<1, false, true><<<8192, blk, 0, stream>>>(R1, stats, nullptr, 12, 7, 2097152, R1T);
    // ---- off2: concat(R1T, s2T) 3x3 zero-pad -> 27ch ----
    wtrans<<<288, blk, 0, stream>>>(off2_w, wtO2, 27, 256, 9, 2, 73728);
    mconv<3, false, false, 2, 6, 2><<<dim3(32, 1, 4), blk, 40960, stream>>>(
        R1T, 4, s2T, 8, wtO2, 2, off2_b, OM2, 27, 64, 64, 1, 64);
    absmean_partial<<<512, blk, 0, stream>>>(OM2, 4096, part2);
    // ---- deform 2 (MFMA, gather from s2T) ----
    dwtrans<128, 128><<<576, blk, 0, stream>>>(d2_w, wtD2);
    deform_mfma<128, 128, 2><<<dim3(64, 4), blk, 0, stream>>>(
        s2T, OM2, wtD2, d2_b, CP2T, 64, 64, 6);
    // ---- c2: up2(concat(CP2T, R1T)) + 5x5 reflect, 256->64 @128 ----
    wtrans<<<1600, blk, 0, stream>>>(c2_w, wtC2, 64, 256, 25, 4, 409600);
    mconv<5, true, true, 4, 6, 1><<<dim3(256, 1, 4), blk, 49152, stream>>>(
        CP2T, 4, R1T, 8, wtC2, 4, c2_b, R2, 64, 128, 128, 2, 64);
    inorm_stats<<<256, blk, 0, stream>>>(R2, stats, 16384);
    // bf16 R2T only; fp32 R2 becomes dead after this (frees Z1 for CP1T)
    inorm_apply<1, false, true><<<16384, blk, 0, stream>>>(R2, stats, nullptr, 14, 6, 4194304, R2T);
    // ---- off1: concat(R2T (2 chunks), s1T (2 chunks)) -> 27ch ----
    wtrans<<<144, blk, 0, stream>>>(off1_w, wtO1, 27, 128, 9, 2, 36864);
    mconv<3, false, false, 2, 6, 2><<<dim3(128, 1, 4), blk, 40960, stream>>>(
        R2T, 2, s1T, 4, wtO1, 2, off1_b, OM1, 27, 128, 128, 2, 128);
    absmean_partial<<<512, blk, 0, stream>>>(OM1, 16384, part1);
    // ---- deform 1 (MFMA, gather from s1T) -> CP1T in freed Z1 ----
    dwtrans<64, 64><<<144, blk, 0, stream>>>(d1_w, wtD1);
    deform_mfma<64, 64, 1><<<dim3(256, 4), blk, 0, stream>>>(
        s1T, OM1, wtD1, d1_b, CP1T, 128, 128, 7);
    // ---- c3: concat(CP1T, R2T) 7x7 reflect + tanh -> 3ch via MFMA ----
    wtrans<<<392, blk, 0, stream>>>(c3_w, wtC3, 3, 128, 49, 1, 100352);
    mconv<7, false, true, 1, 4, 16, 2><<<dim3(64, 1, 4), blk, 65536, stream>>>(
        CP1T, 2, R2T, 4, wtC3, 1, c3_b, outp, 3, 128, 128, 8, 128);
    // ---- offset_sum ----
    finalize_k<<<1, blk, 0, stream>>>(part1, part2, outp + 196608);
}